// Round 6
// baseline (634.266 us; speedup 1.0000x reference)
//
#include <hip/hip_runtime.h>

__device__ __forceinline__ float lrelu(float x){ return x >= 0.f ? x : 0.2f*x; }

// ---------------- zero degree counters ----------------
__global__ __launch_bounds__(256) void k_zero(int* __restrict__ p, int n)
{
  int i = blockIdx.x*256 + threadIdx.x;
  if (i < n) p[i] = 0;
}

// ---------------- count in-degree per destination ----------------
__global__ __launch_bounds__(256) void k_count(const int* __restrict__ ei,
                                               int E, int N, int* __restrict__ deg)
{
  const int e = blockIdx.x*256 + threadIdx.x;
  if (e >= E + N) return;
  const int d = (e < E) ? ei[E + e] : (e - E);
  atomicAdd(&deg[d], 1);
}

// ---------------- exclusive prefix scan (single block) ----------------
__global__ __launch_bounds__(256) void k_scan(const int* __restrict__ deg,
                                              int* __restrict__ rowptr,
                                              int* __restrict__ cursor, int N)
{
  __shared__ int sums[256];
  const int t = threadIdx.x;
  const int chunk = (N + 255) / 256;
  const int lo = t * chunk;
  const int hi = min(lo + chunk, N);
  int s = 0;
  for (int i = lo; i < hi; i++) s += deg[i];
  sums[t] = s;
  __syncthreads();
  if (t == 0){
    int acc = 0;
    for (int i = 0; i < 256; i++){ int v = sums[i]; sums[i] = acc; acc += v; }
  }
  __syncthreads();
  int acc = sums[t];
  for (int i = lo; i < hi; i++){
    rowptr[i] = acc; cursor[i] = acc; acc += deg[i];
  }
  if (hi == N) rowptr[N] = acc;
}

// ---------------- fill CSR src lists (+ dst per position) ----------------
__global__ __launch_bounds__(256) void k_fill(const int* __restrict__ ei,
                                              int E, int N, int* __restrict__ cursor,
                                              int* __restrict__ csr,
                                              int* __restrict__ dstE)
{
  const int e = blockIdx.x*256 + threadIdx.x;
  if (e >= E + N) return;
  int s, d;
  if (e < E){ s = ei[e]; d = ei[E + e]; } else { s = d = e - E; }
  const int pos = atomicAdd(&cursor[d], 1);
  csr[pos] = s;
  dstE[pos] = d;
}

// ---------------- register-tiled GEMM [N,K]@[K,256] + fused attention dots --
template<int K>
__global__ __launch_bounds__(256) void k_gemm_att(
    const float* __restrict__ in,     // [N,K]
    const float* __restrict__ W,      // [K,256]
    const float* __restrict__ att_s,  // [4,64]
    const float* __restrict__ att_d,  // [4,64]
    float* __restrict__ h,            // [N,256]
    float* __restrict__ asrc,         // [N,4]
    float* __restrict__ adst,         // [N,4]
    int N)
{
  constexpr int KC = 32;
  __shared__ float Ast[KC][68];
  __shared__ float Bs[KC][132];
  const int t  = threadIdx.x;
  const int tx = t & 15, ty = t >> 4;
  const int m0 = (blockIdx.x >> 1) * 64;
  const int cb = blockIdx.x & 1;           // col block: heads {2cb, 2cb+1}

  float acc[4][8];
  #pragma unroll
  for (int i=0;i<4;i++)
    #pragma unroll
    for (int j=0;j<8;j++) acc[i][j] = 0.f;

  for (int k0 = 0; k0 < K; k0 += KC){
    __syncthreads();
    #pragma unroll
    for (int i = 0; i < 2; i++){
      const int idx = t + i*256;
      const int r = idx >> 3;
      const int c4 = (idx & 7) * 4;
      const int rg = min(m0 + r, N-1);
      const float4 v = *(const float4*)(in + (size_t)rg*K + k0 + c4);
      Ast[c4+0][r] = v.x; Ast[c4+1][r] = v.y;
      Ast[c4+2][r] = v.z; Ast[c4+3][r] = v.w;
    }
    #pragma unroll
    for (int i = 0; i < 4; i++){
      const int idx = t + i*256;
      const int kr = idx >> 5;
      const int cc = (idx & 31) * 4;
      *(float4*)(&Bs[kr][cc]) = *(const float4*)(W + (size_t)(k0+kr)*256 + cb*128 + cc);
    }
    __syncthreads();
    #pragma unroll 8
    for (int kk = 0; kk < KC; kk++){
      const float4 a  = *(const float4*)(&Ast[kk][ty*4]);
      const float4 b0 = *(const float4*)(&Bs[kk][tx*4]);
      const float4 b1 = *(const float4*)(&Bs[kk][64 + tx*4]);
      const float av[4] = {a.x, a.y, a.z, a.w};
      const float bv[8] = {b0.x,b0.y,b0.z,b0.w, b1.x,b1.y,b1.z,b1.w};
      #pragma unroll
      for (int i=0;i<4;i++)
        #pragma unroll
        for (int j=0;j<8;j++) acc[i][j] += av[i] * bv[j];
    }
  }

  const int h0 = cb*2, h1 = cb*2 + 1;
  float as0[4], ad0[4], as1[4], ad1[4];
  #pragma unroll
  for (int j=0;j<4;j++){
    as0[j] = att_s[h0*64 + tx*4 + j];
    ad0[j] = att_d[h0*64 + tx*4 + j];
    as1[j] = att_s[h1*64 + tx*4 + j];
    ad1[j] = att_d[h1*64 + tx*4 + j];
  }
  #pragma unroll
  for (int i=0;i<4;i++){
    const int row = m0 + ty*4 + i;
    const bool ok = row < N;
    if (ok){
      float4 o0 = make_float4(acc[i][0],acc[i][1],acc[i][2],acc[i][3]);
      float4 o1 = make_float4(acc[i][4],acc[i][5],acc[i][6],acc[i][7]);
      *(float4*)(h + (size_t)row*256 + cb*128 + tx*4)      = o0;
      *(float4*)(h + (size_t)row*256 + cb*128 + 64 + tx*4) = o1;
    }
    float vs0 = acc[i][0]*as0[0] + acc[i][1]*as0[1] + acc[i][2]*as0[2] + acc[i][3]*as0[3];
    float vd0 = acc[i][0]*ad0[0] + acc[i][1]*ad0[1] + acc[i][2]*ad0[2] + acc[i][3]*ad0[3];
    float vs1 = acc[i][4]*as1[0] + acc[i][5]*as1[1] + acc[i][6]*as1[2] + acc[i][7]*as1[3];
    float vd1 = acc[i][4]*ad1[0] + acc[i][5]*ad1[1] + acc[i][6]*ad1[2] + acc[i][7]*ad1[3];
    #pragma unroll
    for (int off=1; off<16; off<<=1){
      vs0 += __shfl_xor(vs0, off, 16);
      vd0 += __shfl_xor(vd0, off, 16);
      vs1 += __shfl_xor(vs1, off, 16);
      vd1 += __shfl_xor(vd1, off, 16);
    }
    if (tx == 0 && ok){
      asrc[(size_t)row*4 + h0] = vs0;
      adst[(size_t)row*4 + h0] = vd0;
      asrc[(size_t)row*4 + h1] = vs1;
      adst[(size_t)row*4 + h1] = vd1;
    }
  }
}

// ---------------- per-edge unnormalized weights (CSR order, no max) ---------
__global__ __launch_bounds__(256) void k_weights(
    const int* __restrict__ csr, const int* __restrict__ dstE,
    const float* __restrict__ asrc, const float* __restrict__ adst,
    float* __restrict__ w, int tot)
{
  const int p = blockIdx.x*256 + threadIdx.x;
  if (p >= tot) return;
  const int s = csr[p];
  const int d = dstE[p];
  const float4 as = *(const float4*)(asrc + (size_t)s*4);
  const float4 ad = *(const float4*)(adst + (size_t)d*4);
  float4 o;
  o.x = __expf(lrelu(as.x + ad.x));
  o.y = __expf(lrelu(as.y + ad.y));
  o.z = __expf(lrelu(as.z + ad.z));
  o.w = __expf(lrelu(as.w + ad.w));
  *(float4*)(w + (size_t)p*4) = o;
}

// ---------------- layer-1 aggregation: wave per dst node, 4x unrolled -------
// 4 independent csr loads -> 4 weight loads -> 4 h-row gathers in flight.
__global__ __launch_bounds__(256) void k_node_agg1(
    const int* __restrict__ rowptr, const int* __restrict__ csr,
    const float* __restrict__ w,
    const float* __restrict__ h, const float* __restrict__ bias,
    float* __restrict__ outp, int N)
{
  const int n = blockIdx.x*4 + (threadIdx.x >> 6);
  const int l = threadIdx.x & 63;
  if (n >= N) return;
  const int start = rowptr[n];
  const int deg = rowptr[n+1] - start;
  const int hd = l >> 4;

  float4 acc = make_float4(0.f,0.f,0.f,0.f);
  float dsum = 0.f;
  int j = 0;
  for (; j + 4 <= deg; j += 4){
    const int p0 = start + j;
    const int s0 = csr[p0+0], s1 = csr[p0+1], s2 = csr[p0+2], s3 = csr[p0+3];
    const float w0 = w[(size_t)(p0+0)*4 + hd];
    const float w1 = w[(size_t)(p0+1)*4 + hd];
    const float w2 = w[(size_t)(p0+2)*4 + hd];
    const float w3 = w[(size_t)(p0+3)*4 + hd];
    const float4 v0 = *(const float4*)(h + (size_t)s0*256 + 4*l);
    const float4 v1 = *(const float4*)(h + (size_t)s1*256 + 4*l);
    const float4 v2 = *(const float4*)(h + (size_t)s2*256 + 4*l);
    const float4 v3 = *(const float4*)(h + (size_t)s3*256 + 4*l);
    acc.x += v0.x*w0 + v1.x*w1 + v2.x*w2 + v3.x*w3;
    acc.y += v0.y*w0 + v1.y*w1 + v2.y*w2 + v3.y*w3;
    acc.z += v0.z*w0 + v1.z*w1 + v2.z*w2 + v3.z*w3;
    acc.w += v0.w*w0 + v1.w*w1 + v2.w*w2 + v3.w*w3;
    dsum  += w0 + w1 + w2 + w3;
  }
  for (; j < deg; j++){
    const int s = csr[start + j];
    const float ww = w[(size_t)(start + j)*4 + hd];
    const float4 v = *(const float4*)(h + (size_t)s*256 + 4*l);
    acc.x += v.x*ww; acc.y += v.y*ww; acc.z += v.z*ww; acc.w += v.w*ww;
    dsum  += ww;
  }
  const float dih = 1.f / dsum;
  const float4 b = *(const float4*)(bias + 4*l);
  float4 o;
  o.x = fmaxf(acc.x*dih + b.x, 0.f);
  o.y = fmaxf(acc.y*dih + b.y, 0.f);
  o.z = fmaxf(acc.z*dih + b.z, 0.f);
  o.w = fmaxf(acc.w*dih + b.w, 0.f);
  *(float4*)(outp + (size_t)n*256 + 4*l) = o;
}

// ---------------- layer-2 aggregation: wave per dst node, head-mean, 4x -----
__global__ __launch_bounds__(256) void k_node_agg2(
    const int* __restrict__ rowptr, const int* __restrict__ csr,
    const float* __restrict__ w,
    const float* __restrict__ h, const float* __restrict__ bias,
    float* __restrict__ outp, int N)
{
  const int n = blockIdx.x*4 + (threadIdx.x >> 6);
  const int l = threadIdx.x & 63;              // output channel
  if (n >= N) return;
  const int start = rowptr[n];
  const int deg = rowptr[n+1] - start;

  float a0=0.f, a1=0.f, a2=0.f, a3=0.f;
  float d0=0.f, d1=0.f, d2=0.f, d3=0.f;
  int j = 0;
  for (; j + 4 <= deg; j += 4){
    const int p0 = start + j;
    const int s0 = csr[p0+0], s1 = csr[p0+1], s2 = csr[p0+2], s3 = csr[p0+3];
    const float4 wa = *(const float4*)(w + (size_t)(p0+0)*4);
    const float4 wb = *(const float4*)(w + (size_t)(p0+1)*4);
    const float4 wc = *(const float4*)(w + (size_t)(p0+2)*4);
    const float4 wd = *(const float4*)(w + (size_t)(p0+3)*4);
    const float* h0 = h + (size_t)s0*256;
    const float* h1 = h + (size_t)s1*256;
    const float* h2 = h + (size_t)s2*256;
    const float* h3 = h + (size_t)s3*256;
    a0 += wa.x*h0[l]     + wb.x*h1[l]     + wc.x*h2[l]     + wd.x*h3[l];
    a1 += wa.y*h0[64+l]  + wb.y*h1[64+l]  + wc.y*h2[64+l]  + wd.y*h3[64+l];
    a2 += wa.z*h0[128+l] + wb.z*h1[128+l] + wc.z*h2[128+l] + wd.z*h3[128+l];
    a3 += wa.w*h0[192+l] + wb.w*h1[192+l] + wc.w*h2[192+l] + wd.w*h3[192+l];
    d0 += wa.x + wb.x + wc.x + wd.x;
    d1 += wa.y + wb.y + wc.y + wd.y;
    d2 += wa.z + wb.z + wc.z + wd.z;
    d3 += wa.w + wb.w + wc.w + wd.w;
  }
  for (; j < deg; j++){
    const int s = csr[start + j];
    const float4 w4 = *(const float4*)(w + (size_t)(start + j)*4);
    const float* hs = h + (size_t)s*256;
    a0 += w4.x*hs[l]; a1 += w4.y*hs[64+l]; a2 += w4.z*hs[128+l]; a3 += w4.w*hs[192+l];
    d0 += w4.x; d1 += w4.y; d2 += w4.z; d3 += w4.w;
  }
  const float val = 0.25f*(a0/d0 + a1/d1 + a2/d2 + a3/d3) + bias[l];
  outp[(size_t)n*64 + l] = fmaxf(val, 0.f);
}

// ---------------- FF head: agg2 -> relu(@ff1) -> @ff2 -------
__global__ __launch_bounds__(256) void k_ff(
    const float* __restrict__ agg2,
    const float* __restrict__ w1, const float* __restrict__ b1,
    const float* __restrict__ w2, const float* __restrict__ b2f,
    float* __restrict__ out, int N)
{
  __shared__ float W1s[64*32];
  __shared__ float B1s[32];
  __shared__ float W2s[64];
  __shared__ float B2s[2];
  const int t = threadIdx.x;
  for (int i=t; i<64*32; i+=256) W1s[i] = w1[i];
  if (t < 32) B1s[t] = b1[t];
  if (t < 64) W2s[t] = w2[t];
  if (t < 2)  B2s[t] = b2f[t];
  __syncthreads();

  const int n = blockIdx.x*256 + t;
  if (n >= N) return;

  float t1[32];
  #pragma unroll
  for (int j=0;j<32;j++) t1[j] = B1s[j];
  #pragma unroll
  for (int c=0;c<64;c++){
    const float fc = agg2[(long)n*64 + c];
    #pragma unroll
    for (int j=0;j<32;j++) t1[j] += fc * W1s[c*32 + j];
  }
  float o0 = B2s[0], o1 = B2s[1];
  #pragma unroll
  for (int j=0;j<32;j++){
    const float v = t1[j] > 0.f ? t1[j] : 0.f;
    o0 += v * W2s[j*2 + 0];
    o1 += v * W2s[j*2 + 1];
  }
  out[(long)n*2 + 0] = o0;
  out[(long)n*2 + 1] = o1;
}

extern "C" void kernel_launch(void* const* d_in, const int* in_sizes, int n_in,
                              void* d_out, int out_size, void* d_ws, size_t ws_size,
                              hipStream_t stream)
{
  const float* x      = (const float*)d_in[0];
  const int*   ei     = (const int*)  d_in[1];
  const float* W1     = (const float*)d_in[3];
  const float* att_s1 = (const float*)d_in[4];
  const float* att_d1 = (const float*)d_in[5];
  const float* b1     = (const float*)d_in[6];
  const float* W2     = (const float*)d_in[7];
  const float* att_s2 = (const float*)d_in[8];
  const float* att_d2 = (const float*)d_in[9];
  const float* b2     = (const float*)d_in[10];
  const float* ff1w   = (const float*)d_in[11];
  const float* ff1b   = (const float*)d_in[12];
  const float* ff2w   = (const float*)d_in[13];
  const float* ff2b   = (const float*)d_in[14];
  float* out = (float*)d_out;

  const int N = in_sizes[0] / 128;
  const int E = in_sizes[1] / 2;
  const int tot = E + N;

  char* p = (char*)d_ws;
  float* h    = (float*)p;  p += (size_t)N*256*4;   // [N,256]
  float* agg1 = (float*)p;  p += (size_t)N*256*4;   // [N,256]
  float* agg2 = (float*)p;  p += (size_t)N*64*4;    // [N,64]
  float* w    = (float*)p;  p += (size_t)tot*4*4;   // [tot,4] edge weights
  float* asrc = (float*)p;  p += (size_t)N*4*4;     // [N,4]
  float* adst = (float*)p;  p += (size_t)N*4*4;     // [N,4]
  int* deg    = (int*)p;    p += (size_t)N*4;
  int* rowptr = (int*)p;    p += (size_t)(N+1)*4;
  int* cursor = (int*)p;    p += (size_t)N*4;
  int* csr    = (int*)p;    p += (size_t)tot*4;
  int* dstE   = (int*)p;    p += (size_t)tot*4;

  const int gE = (tot + 255) / 256;
  const int gN4 = (N + 3) / 4;
  const int gG = ((N + 63) / 64) * 2;

  // ---- CSR build (shared by both layers) ----
  k_zero <<<(N+255)/256,256,0,stream>>>(deg, N);
  k_count<<<gE,256,0,stream>>>(ei, E, N, deg);
  k_scan <<<1,256,0,stream>>>(deg, rowptr, cursor, N);
  k_fill <<<gE,256,0,stream>>>(ei, E, N, cursor, csr, dstE);

  // ---- layer 1 (concat heads) ----
  k_gemm_att<128><<<gG,256,0,stream>>>(x, W1, att_s1, att_d1, h, asrc, adst, N);
  k_weights<<<gE,256,0,stream>>>(csr, dstE, asrc, adst, w, tot);
  k_node_agg1<<<gN4,256,0,stream>>>(rowptr, csr, w, h, b1, agg1, N);

  // ---- layer 2 (head mean) ----
  k_gemm_att<256><<<gG,256,0,stream>>>(agg1, W2, att_s2, att_d2, h, asrc, adst, N);
  k_weights<<<gE,256,0,stream>>>(csr, dstE, asrc, adst, w, tot);
  k_node_agg2<<<gN4,256,0,stream>>>(rowptr, csr, w, h, b2, agg2, N);

  // ---- feed-forward head ----
  k_ff<<<(N+255)/256,256,0,stream>>>(agg2, ff1w, ff1b, ff2w, ff2b, out, N);
}

// Round 7
// 633.183 us; speedup vs baseline: 1.0017x; 1.0017x over previous
//
#include <hip/hip_runtime.h>
#include <hip/hip_fp16.h>

__device__ __forceinline__ float lrelu(float x){ return x >= 0.f ? x : 0.2f*x; }

// ---------------- zero degree counters ----------------
__global__ __launch_bounds__(256) void k_zero(int* __restrict__ p, int n)
{
  int i = blockIdx.x*256 + threadIdx.x;
  if (i < n) p[i] = 0;
}

// ---------------- count in-degree per destination ----------------
__global__ __launch_bounds__(256) void k_count(const int* __restrict__ ei,
                                               int E, int N, int* __restrict__ deg)
{
  const int e = blockIdx.x*256 + threadIdx.x;
  if (e >= E + N) return;
  const int d = (e < E) ? ei[E + e] : (e - E);
  atomicAdd(&deg[d], 1);
}

// ---------------- exclusive prefix scan (single block) ----------------
__global__ __launch_bounds__(256) void k_scan(const int* __restrict__ deg,
                                              int* __restrict__ rowptr,
                                              int* __restrict__ cursor, int N)
{
  __shared__ int sums[256];
  const int t = threadIdx.x;
  const int chunk = (N + 255) / 256;
  const int lo = t * chunk;
  const int hi = min(lo + chunk, N);
  int s = 0;
  for (int i = lo; i < hi; i++) s += deg[i];
  sums[t] = s;
  __syncthreads();
  if (t == 0){
    int acc = 0;
    for (int i = 0; i < 256; i++){ int v = sums[i]; sums[i] = acc; acc += v; }
  }
  __syncthreads();
  int acc = sums[t];
  for (int i = lo; i < hi; i++){
    rowptr[i] = acc; cursor[i] = acc; acc += deg[i];
  }
  if (hi == N) rowptr[N] = acc;
}

// ---------------- fill CSR src lists (+ dst per position) ----------------
__global__ __launch_bounds__(256) void k_fill(const int* __restrict__ ei,
                                              int E, int N, int* __restrict__ cursor,
                                              int* __restrict__ csr,
                                              int* __restrict__ dstE)
{
  const int e = blockIdx.x*256 + threadIdx.x;
  if (e >= E + N) return;
  int s, d;
  if (e < E){ s = ei[e]; d = ei[E + e]; } else { s = d = e - E; }
  const int pos = atomicAdd(&cursor[d], 1);
  csr[pos] = s;
  dstE[pos] = d;
}

// ---------------- Ps/Pd = per-head W1 @ att vectors: [128,4] ----------------
__global__ __launch_bounds__(256) void k_prep(
    const float* __restrict__ W1, const float* __restrict__ as1,
    const float* __restrict__ ad1, float* __restrict__ Ps, float* __restrict__ Pd)
{
  const int t = threadIdx.x;
  for (int idx = t; idx < 512; idx += 256){
    const int k = idx >> 2, h = idx & 3;
    float ss = 0.f, dd = 0.f;
    for (int c = 0; c < 64; c++){
      const float wv = W1[k*256 + h*64 + c];
      ss += wv * as1[h*64 + c];
      dd += wv * ad1[h*64 + c];
    }
    Ps[k*4 + h] = ss;
    Pd[k*4 + h] = dd;
  }
}

// ---------------- layer-1 logits: asrc/adst = x @ Ps/Pd  [N,4] --------------
// block=256 (4 waves) covers 64 nodes; wave g handles k in [32g,32g+32).
__global__ __launch_bounds__(256) void k_att1(
    const float* __restrict__ x, const float* __restrict__ Ps,
    const float* __restrict__ Pd, float* __restrict__ asrc,
    float* __restrict__ adst, int N)
{
  __shared__ float PsL[512], PdL[512];
  __shared__ float red[4][64][8];
  const int t = threadIdx.x;
  PsL[t] = Ps[t]; PsL[t+256] = Ps[t+256];
  PdL[t] = Pd[t]; PdL[t+256] = Pd[t+256];
  __syncthreads();
  const int r = t & 63, g = t >> 6;
  const int row = blockIdx.x*64 + r;
  const int rg = min(row, N-1);
  const float* xr = x + (size_t)rg*128;
  float4 pa = make_float4(0.f,0.f,0.f,0.f);
  float4 pb = make_float4(0.f,0.f,0.f,0.f);
  for (int kk = g*32; kk < g*32 + 32; kk++){
    const float xv = xr[kk];
    const float4 s4 = *(const float4*)(PsL + kk*4);   // wave-broadcast
    const float4 d4 = *(const float4*)(PdL + kk*4);
    pa.x += xv*s4.x; pa.y += xv*s4.y; pa.z += xv*s4.z; pa.w += xv*s4.w;
    pb.x += xv*d4.x; pb.y += xv*d4.y; pb.z += xv*d4.z; pb.w += xv*d4.w;
  }
  *(float4*)(&red[g][r][0]) = pa;
  *(float4*)(&red[g][r][4]) = pb;
  __syncthreads();
  if (t < 64 && blockIdx.x*64 + t < N){
    float4 sa = make_float4(0.f,0.f,0.f,0.f);
    float4 sb = make_float4(0.f,0.f,0.f,0.f);
    #pragma unroll
    for (int gg = 0; gg < 4; gg++){
      const float4 qa = *(const float4*)(&red[gg][t][0]);
      const float4 qb = *(const float4*)(&red[gg][t][4]);
      sa.x += qa.x; sa.y += qa.y; sa.z += qa.z; sa.w += qa.w;
      sb.x += qb.x; sb.y += qb.y; sb.z += qb.z; sb.w += qb.w;
    }
    *(float4*)(asrc + (size_t)(blockIdx.x*64 + t)*4) = sa;
    *(float4*)(adst + (size_t)(blockIdx.x*64 + t)*4) = sb;
  }
}

// ---------------- per-edge unnormalized weights (CSR order, no max) ---------
__global__ __launch_bounds__(256) void k_weights(
    const int* __restrict__ csr, const int* __restrict__ dstE,
    const float* __restrict__ asrc, const float* __restrict__ adst,
    float* __restrict__ w, int tot)
{
  const int p = blockIdx.x*256 + threadIdx.x;
  if (p >= tot) return;
  const int s = csr[p];
  const int d = dstE[p];
  const float4 as = *(const float4*)(asrc + (size_t)s*4);
  const float4 ad = *(const float4*)(adst + (size_t)d*4);
  float4 o;
  o.x = __expf(lrelu(as.x + ad.x));
  o.y = __expf(lrelu(as.y + ad.y));
  o.z = __expf(lrelu(as.z + ad.z));
  o.w = __expf(lrelu(as.w + ad.w));
  *(float4*)(w + (size_t)p*4) = o;
}

// ---------------- layer-1 aggregate-then-transform: gather x (512B/edge) ----
// wave per dst node; lane l holds x elems {2l,2l+1}; 4 per-head accumulators;
// normalized by the in-register denominator; stored fp16 [N,4,128].
__global__ __launch_bounds__(256) void k_agg_x(
    const int* __restrict__ rowptr, const int* __restrict__ csr,
    const float* __restrict__ w, const float* __restrict__ x,
    __half* __restrict__ aggX, int N)
{
  const int n = blockIdx.x*4 + (threadIdx.x >> 6);
  const int l = threadIdx.x & 63;
  if (n >= N) return;
  const int start = rowptr[n];
  const int deg = rowptr[n+1] - start;

  float a0x=0.f,a0y=0.f, a1x=0.f,a1y=0.f, a2x=0.f,a2y=0.f, a3x=0.f,a3y=0.f;
  float4 ds = make_float4(0.f,0.f,0.f,0.f);
  for (int j = 0; j < deg; j++){
    const int p = start + j;
    const int s = csr[p];                                   // broadcast
    const float4 w4 = *(const float4*)(w + (size_t)p*4);    // broadcast
    const float2 xv = *(const float2*)(x + (size_t)s*128 + 2*l);
    a0x += w4.x*xv.x; a0y += w4.x*xv.y;
    a1x += w4.y*xv.x; a1y += w4.y*xv.y;
    a2x += w4.z*xv.x; a2y += w4.z*xv.y;
    a3x += w4.w*xv.x; a3y += w4.w*xv.y;
    ds.x += w4.x; ds.y += w4.y; ds.z += w4.z; ds.w += w4.w;
  }
  const float i0 = 1.f/ds.x, i1 = 1.f/ds.y, i2 = 1.f/ds.z, i3 = 1.f/ds.w;
  __half* base = aggX + (size_t)n*512 + 2*l;
  *(__half2*)(base +   0) = __floats2half2_rn(a0x*i0, a0y*i0);
  *(__half2*)(base + 128) = __floats2half2_rn(a1x*i1, a1y*i1);
  *(__half2*)(base + 256) = __floats2half2_rn(a2x*i2, a2y*i2);
  *(__half2*)(base + 384) = __floats2half2_rn(a3x*i3, a3y*i3);
}

// ---------------- layer-1 post-GEMM: agg1 = relu(blockdiag(aggX @ W1) + b) --
// block: 64 rows x 128 cols (head pair 2cb, 2cb+1); block-diagonal: cols of
// head h consume aggX[:,h,:]. Two A tiles (one per head), shared B tile.
__global__ __launch_bounds__(256) void k_gemm_post1(
    const __half* __restrict__ aggX,  // [N,4,128] normalized
    const float* __restrict__ W1,     // [128,256]
    const float* __restrict__ bias,   // [256]
    float* __restrict__ agg1, int N)
{
  __shared__ float AstA[32][68];
  __shared__ float AstB[32][68];
  __shared__ float Bs[32][132];
  const int t  = threadIdx.x;
  const int tx = t & 15, ty = t >> 4;
  const int m0 = (blockIdx.x >> 1) * 64;
  const int cb = blockIdx.x & 1;
  const int hA = 2*cb, hB = 2*cb + 1;

  float acc[4][8];
  #pragma unroll
  for (int i=0;i<4;i++)
    #pragma unroll
    for (int j=0;j<8;j++) acc[i][j] = 0.f;

  for (int k0 = 0; k0 < 128; k0 += 32){
    __syncthreads();
    #pragma unroll
    for (int i = 0; i < 2; i++){
      const int idx = t + i*256;
      const int r = idx >> 3;
      const int c4 = (idx & 7) * 4;
      const int rg = min(m0 + r, N-1);
      const __half2* pA = (const __half2*)(aggX + (size_t)rg*512 + hA*128 + k0 + c4);
      float2 lo = __half22float2(pA[0]);
      float2 hi = __half22float2(pA[1]);
      AstA[c4+0][r] = lo.x; AstA[c4+1][r] = lo.y;
      AstA[c4+2][r] = hi.x; AstA[c4+3][r] = hi.y;
      const __half2* pB = (const __half2*)(aggX + (size_t)rg*512 + hB*128 + k0 + c4);
      lo = __half22float2(pB[0]);
      hi = __half22float2(pB[1]);
      AstB[c4+0][r] = lo.x; AstB[c4+1][r] = lo.y;
      AstB[c4+2][r] = hi.x; AstB[c4+3][r] = hi.y;
    }
    #pragma unroll
    for (int i = 0; i < 4; i++){
      const int idx = t + i*256;
      const int kr = idx >> 5;
      const int cc = (idx & 31) * 4;
      *(float4*)(&Bs[kr][cc]) = *(const float4*)(W1 + (size_t)(k0+kr)*256 + cb*128 + cc);
    }
    __syncthreads();
    #pragma unroll 8
    for (int kk = 0; kk < 32; kk++){
      const float4 aA = *(const float4*)(&AstA[kk][ty*4]);
      const float4 aB = *(const float4*)(&AstB[kk][ty*4]);
      const float4 b0 = *(const float4*)(&Bs[kk][tx*4]);
      const float4 b1 = *(const float4*)(&Bs[kk][64 + tx*4]);
      const float avA[4] = {aA.x, aA.y, aA.z, aA.w};
      const float avB[4] = {aB.x, aB.y, aB.z, aB.w};
      const float bv0[4] = {b0.x, b0.y, b0.z, b0.w};
      const float bv1[4] = {b1.x, b1.y, b1.z, b1.w};
      #pragma unroll
      for (int i=0;i<4;i++)
        #pragma unroll
        for (int j=0;j<4;j++){
          acc[i][j]   += avA[i] * bv0[j];
          acc[i][4+j] += avB[i] * bv1[j];
        }
    }
  }

  float b0v[4], b1v[4];
  #pragma unroll
  for (int j=0;j<4;j++){
    b0v[j] = bias[cb*128 + tx*4 + j];
    b1v[j] = bias[cb*128 + 64 + tx*4 + j];
  }
  #pragma unroll
  for (int i=0;i<4;i++){
    const int row = m0 + ty*4 + i;
    if (row < N){
      float4 o0, o1;
      o0.x = fmaxf(acc[i][0] + b0v[0], 0.f);
      o0.y = fmaxf(acc[i][1] + b0v[1], 0.f);
      o0.z = fmaxf(acc[i][2] + b0v[2], 0.f);
      o0.w = fmaxf(acc[i][3] + b0v[3], 0.f);
      o1.x = fmaxf(acc[i][4] + b1v[0], 0.f);
      o1.y = fmaxf(acc[i][5] + b1v[1], 0.f);
      o1.z = fmaxf(acc[i][6] + b1v[2], 0.f);
      o1.w = fmaxf(acc[i][7] + b1v[3], 0.f);
      *(float4*)(agg1 + (size_t)row*256 + cb*128 + tx*4)      = o0;
      *(float4*)(agg1 + (size_t)row*256 + cb*128 + 64 + tx*4) = o1;
    }
  }
}

// ---------------- register-tiled GEMM [N,K]@[K,256] + fused attention dots --
template<int K>
__global__ __launch_bounds__(256) void k_gemm_att(
    const float* __restrict__ in,     // [N,K]
    const float* __restrict__ W,      // [K,256]
    const float* __restrict__ att_s,  // [4,64]
    const float* __restrict__ att_d,  // [4,64]
    float* __restrict__ h,            // [N,256]
    float* __restrict__ asrc,         // [N,4]
    float* __restrict__ adst,         // [N,4]
    int N)
{
  constexpr int KC = 32;
  __shared__ float Ast[KC][68];
  __shared__ float Bs[KC][132];
  const int t  = threadIdx.x;
  const int tx = t & 15, ty = t >> 4;
  const int m0 = (blockIdx.x >> 1) * 64;
  const int cb = blockIdx.x & 1;           // col block: heads {2cb, 2cb+1}

  float acc[4][8];
  #pragma unroll
  for (int i=0;i<4;i++)
    #pragma unroll
    for (int j=0;j<8;j++) acc[i][j] = 0.f;

  for (int k0 = 0; k0 < K; k0 += KC){
    __syncthreads();
    #pragma unroll
    for (int i = 0; i < 2; i++){
      const int idx = t + i*256;
      const int r = idx >> 3;
      const int c4 = (idx & 7) * 4;
      const int rg = min(m0 + r, N-1);
      const float4 v = *(const float4*)(in + (size_t)rg*K + k0 + c4);
      Ast[c4+0][r] = v.x; Ast[c4+1][r] = v.y;
      Ast[c4+2][r] = v.z; Ast[c4+3][r] = v.w;
    }
    #pragma unroll
    for (int i = 0; i < 4; i++){
      const int idx = t + i*256;
      const int kr = idx >> 5;
      const int cc = (idx & 31) * 4;
      *(float4*)(&Bs[kr][cc]) = *(const float4*)(W + (size_t)(k0+kr)*256 + cb*128 + cc);
    }
    __syncthreads();
    #pragma unroll 8
    for (int kk = 0; kk < KC; kk++){
      const float4 a  = *(const float4*)(&Ast[kk][ty*4]);
      const float4 b0 = *(const float4*)(&Bs[kk][tx*4]);
      const float4 b1 = *(const float4*)(&Bs[kk][64 + tx*4]);
      const float av[4] = {a.x, a.y, a.z, a.w};
      const float bv[8] = {b0.x,b0.y,b0.z,b0.w, b1.x,b1.y,b1.z,b1.w};
      #pragma unroll
      for (int i=0;i<4;i++)
        #pragma unroll
        for (int j=0;j<8;j++) acc[i][j] += av[i] * bv[j];
    }
  }

  const int h0 = cb*2, h1 = cb*2 + 1;
  float as0[4], ad0[4], as1[4], ad1[4];
  #pragma unroll
  for (int j=0;j<4;j++){
    as0[j] = att_s[h0*64 + tx*4 + j];
    ad0[j] = att_d[h0*64 + tx*4 + j];
    as1[j] = att_s[h1*64 + tx*4 + j];
    ad1[j] = att_d[h1*64 + tx*4 + j];
  }
  #pragma unroll
  for (int i=0;i<4;i++){
    const int row = m0 + ty*4 + i;
    const bool ok = row < N;
    if (ok){
      float4 o0 = make_float4(acc[i][0],acc[i][1],acc[i][2],acc[i][3]);
      float4 o1 = make_float4(acc[i][4],acc[i][5],acc[i][6],acc[i][7]);
      *(float4*)(h + (size_t)row*256 + cb*128 + tx*4)      = o0;
      *(float4*)(h + (size_t)row*256 + cb*128 + 64 + tx*4) = o1;
    }
    float vs0 = acc[i][0]*as0[0] + acc[i][1]*as0[1] + acc[i][2]*as0[2] + acc[i][3]*as0[3];
    float vd0 = acc[i][0]*ad0[0] + acc[i][1]*ad0[1] + acc[i][2]*ad0[2] + acc[i][3]*ad0[3];
    float vs1 = acc[i][4]*as1[0] + acc[i][5]*as1[1] + acc[i][6]*as1[2] + acc[i][7]*as1[3];
    float vd1 = acc[i][4]*ad1[0] + acc[i][5]*ad1[1] + acc[i][6]*ad1[2] + acc[i][7]*ad1[3];
    #pragma unroll
    for (int off=1; off<16; off<<=1){
      vs0 += __shfl_xor(vs0, off, 16);
      vd0 += __shfl_xor(vd0, off, 16);
      vs1 += __shfl_xor(vs1, off, 16);
      vd1 += __shfl_xor(vd1, off, 16);
    }
    if (tx == 0 && ok){
      asrc[(size_t)row*4 + h0] = vs0;
      adst[(size_t)row*4 + h0] = vd0;
      asrc[(size_t)row*4 + h1] = vs1;
      adst[(size_t)row*4 + h1] = vd1;
    }
  }
}

// ---------------- layer-2 aggregation: wave per dst node, head-mean ---------
__global__ __launch_bounds__(256) void k_node_agg2(
    const int* __restrict__ rowptr, const int* __restrict__ csr,
    const float* __restrict__ w,
    const float* __restrict__ h, const float* __restrict__ bias,
    float* __restrict__ outp, int N)
{
  const int n = blockIdx.x*4 + (threadIdx.x >> 6);
  const int l = threadIdx.x & 63;              // output channel
  if (n >= N) return;
  const int start = rowptr[n];
  const int deg = rowptr[n+1] - start;

  float a0=0.f, a1=0.f, a2=0.f, a3=0.f;
  float d0=0.f, d1=0.f, d2=0.f, d3=0.f;
  for (int j = 0; j < deg; j++){
    const int p = start + j;
    const int s = csr[p];
    const float4 w4 = *(const float4*)(w + (size_t)p*4);
    const float* hs = h + (size_t)s*256;
    a0 += w4.x*hs[l]; a1 += w4.y*hs[64+l]; a2 += w4.z*hs[128+l]; a3 += w4.w*hs[192+l];
    d0 += w4.x; d1 += w4.y; d2 += w4.z; d3 += w4.w;
  }
  const float val = 0.25f*(a0/d0 + a1/d1 + a2/d2 + a3/d3) + bias[l];
  outp[(size_t)n*64 + l] = fmaxf(val, 0.f);
}

// ---------------- FF head: agg2 -> relu(@ff1) -> @ff2 -------
__global__ __launch_bounds__(256) void k_ff(
    const float* __restrict__ agg2,
    const float* __restrict__ w1, const float* __restrict__ b1,
    const float* __restrict__ w2, const float* __restrict__ b2f,
    float* __restrict__ out, int N)
{
  __shared__ float W1s[64*32];
  __shared__ float B1s[32];
  __shared__ float W2s[64];
  __shared__ float B2s[2];
  const int t = threadIdx.x;
  for (int i=t; i<64*32; i+=256) W1s[i] = w1[i];
  if (t < 32) B1s[t] = b1[t];
  if (t < 64) W2s[t] = w2[t];
  if (t < 2)  B2s[t] = b2f[t];
  __syncthreads();

  const int n = blockIdx.x*256 + t;
  if (n >= N) return;

  float t1[32];
  #pragma unroll
  for (int j=0;j<32;j++) t1[j] = B1s[j];
  #pragma unroll
  for (int c=0;c<64;c++){
    const float fc = agg2[(long)n*64 + c];
    #pragma unroll
    for (int j=0;j<32;j++) t1[j] += fc * W1s[c*32 + j];
  }
  float o0 = B2s[0], o1 = B2s[1];
  #pragma unroll
  for (int j=0;j<32;j++){
    const float v = t1[j] > 0.f ? t1[j] : 0.f;
    o0 += v * W2s[j*2 + 0];
    o1 += v * W2s[j*2 + 1];
  }
  out[(long)n*2 + 0] = o0;
  out[(long)n*2 + 1] = o1;
}

extern "C" void kernel_launch(void* const* d_in, const int* in_sizes, int n_in,
                              void* d_out, int out_size, void* d_ws, size_t ws_size,
                              hipStream_t stream)
{
  const float* x      = (const float*)d_in[0];
  const int*   ei     = (const int*)  d_in[1];
  const float* W1     = (const float*)d_in[3];
  const float* att_s1 = (const float*)d_in[4];
  const float* att_d1 = (const float*)d_in[5];
  const float* b1     = (const float*)d_in[6];
  const float* W2     = (const float*)d_in[7];
  const float* att_s2 = (const float*)d_in[8];
  const float* att_d2 = (const float*)d_in[9];
  const float* b2     = (const float*)d_in[10];
  const float* ff1w   = (const float*)d_in[11];
  const float* ff1b   = (const float*)d_in[12];
  const float* ff2w   = (const float*)d_in[13];
  const float* ff2b   = (const float*)d_in[14];
  float* out = (float*)d_out;

  const int N = in_sizes[0] / 128;
  const int E = in_sizes[1] / 2;
  const int tot = E + N;

  // ---- workspace (region R0 time-shared: aggX in layer-1; h2+agg2 after) ---
  char* p = (char*)d_ws;
  __half* aggX = (__half*)p;                      // [N,512] fp16 (layer-1 only)
  float*  h2   = (float*)p;                       // [N,256] f32  (layer-2)
  float*  agg2 = (float*)(p + (size_t)N*256*4);   // [N,64]  f32  (layer-2)
  p += (size_t)N*256*4 + (size_t)N*64*4;          // 64MB >= aggX's 51.2MB
  float* agg1 = (float*)p;  p += (size_t)N*256*4; // [N,256]
  float* w    = (float*)p;  p += (size_t)tot*4*4; // [tot,4] edge weights
  float* asrc = (float*)p;  p += (size_t)N*4*4;   // [N,4]
  float* adst = (float*)p;  p += (size_t)N*4*4;   // [N,4]
  float* Ps   = (float*)p;  p += 512*4;           // [128,4]
  float* Pd   = (float*)p;  p += 512*4;           // [128,4]
  int* deg    = (int*)p;    p += (size_t)N*4;
  int* rowptr = (int*)p;    p += (size_t)(N+1)*4;
  int* cursor = (int*)p;    p += (size_t)N*4;
  int* csr    = (int*)p;    p += (size_t)tot*4;
  int* dstE   = (int*)p;    p += (size_t)tot*4;

  const int gE  = (tot + 255) / 256;
  const int gN4 = (N + 3) / 4;
  const int g64 = (N + 63) / 64;

  // ---- CSR build (shared by both layers) ----
  k_zero <<<(N+255)/256,256,0,stream>>>(deg, N);
  k_count<<<gE,256,0,stream>>>(ei, E, N, deg);
  k_scan <<<1,256,0,stream>>>(deg, rowptr, cursor, N);
  k_fill <<<gE,256,0,stream>>>(ei, E, N, cursor, csr, dstE);

  // ---- layer 1: aggregate-then-transform ----
  k_prep<<<1,256,0,stream>>>(W1, att_s1, att_d1, Ps, Pd);
  k_att1<<<g64,256,0,stream>>>(x, Ps, Pd, asrc, adst, N);
  k_weights<<<gE,256,0,stream>>>(csr, dstE, asrc, adst, w, tot);
  k_agg_x<<<gN4,256,0,stream>>>(rowptr, csr, w, x, aggX, N);
  k_gemm_post1<<<g64*2,256,0,stream>>>(aggX, W1, b1, agg1, N);

  // ---- layer 2 (head mean) ----
  k_gemm_att<256><<<g64*2,256,0,stream>>>(agg1, W2, att_s2, att_d2, h2, asrc, adst, N);
  k_weights<<<gE,256,0,stream>>>(csr, dstE, asrc, adst, w, tot);
  k_node_agg2<<<gN4,256,0,stream>>>(rowptr, csr, w, h2, b2, agg2, N);

  // ---- feed-forward head ----
  k_ff<<<(N+255)/256,256,0,stream>>>(agg2, ff1w, ff1b, ff2w, ff2b, out, N);
}

// Round 8
// 612.979 us; speedup vs baseline: 1.0347x; 1.0330x over previous
//
#include <hip/hip_runtime.h>
#include <hip/hip_fp16.h>

__device__ __forceinline__ float lrelu(float x){ return x >= 0.f ? x : 0.2f*x; }

// ---------------- zero degree counters ----------------
__global__ __launch_bounds__(256) void k_zero(int* __restrict__ p, int n)
{
  int i = blockIdx.x*256 + threadIdx.x;
  if (i < n) p[i] = 0;
}

// ---------------- count in-degree per destination ----------------
__global__ __launch_bounds__(256) void k_count(const int* __restrict__ ei,
                                               int E, int N, int* __restrict__ deg)
{
  const int e = blockIdx.x*256 + threadIdx.x;
  if (e >= E + N) return;
  const int d = (e < E) ? ei[E + e] : (e - E);
  atomicAdd(&deg[d], 1);
}

// ---------------- exclusive prefix scan (single block) ----------------
__global__ __launch_bounds__(256) void k_scan(const int* __restrict__ deg,
                                              int* __restrict__ rowptr,
                                              int* __restrict__ cursor, int N)
{
  __shared__ int sums[256];
  const int t = threadIdx.x;
  const int chunk = (N + 255) / 256;
  const int lo = t * chunk;
  const int hi = min(lo + chunk, N);
  int s = 0;
  for (int i = lo; i < hi; i++) s += deg[i];
  sums[t] = s;
  __syncthreads();
  if (t == 0){
    int acc = 0;
    for (int i = 0; i < 256; i++){ int v = sums[i]; sums[i] = acc; acc += v; }
  }
  __syncthreads();
  int acc = sums[t];
  for (int i = lo; i < hi; i++){
    rowptr[i] = acc; cursor[i] = acc; acc += deg[i];
  }
  if (hi == N) rowptr[N] = acc;
}

// ---------------- fill CSR src lists (+ dst per position) ----------------
__global__ __launch_bounds__(256) void k_fill(const int* __restrict__ ei,
                                              int E, int N, int* __restrict__ cursor,
                                              int* __restrict__ csr,
                                              int* __restrict__ dstE)
{
  const int e = blockIdx.x*256 + threadIdx.x;
  if (e >= E + N) return;
  int s, d;
  if (e < E){ s = ei[e]; d = ei[E + e]; } else { s = d = e - E; }
  const int pos = atomicAdd(&cursor[d], 1);
  csr[pos] = s;
  dstE[pos] = d;
}

// ---------------- x -> fp16 copy (gather payload shrink) ----------------
__global__ __launch_bounds__(256) void k_cvt_x(const float* __restrict__ x,
                                               __half* __restrict__ xh, long n2)
{
  long i  = (long)blockIdx.x*256 + threadIdx.x;
  long st = (long)gridDim.x*256;
  for (; i < n2; i += st){
    const float2 v = *(const float2*)(x + 2*i);
    *(__half2*)(xh + 2*i) = __floats2half2_rn(v.x, v.y);
  }
}

// ---------------- Ps/Pd = per-head W1 @ att vectors: [128,4] ----------------
__global__ __launch_bounds__(256) void k_prep(
    const float* __restrict__ W1, const float* __restrict__ as1,
    const float* __restrict__ ad1, float* __restrict__ Ps, float* __restrict__ Pd)
{
  const int t = threadIdx.x;
  for (int idx = t; idx < 512; idx += 256){
    const int k = idx >> 2, h = idx & 3;
    float ss = 0.f, dd = 0.f;
    for (int c = 0; c < 64; c++){
      const float wv = W1[k*256 + h*64 + c];
      ss += wv * as1[h*64 + c];
      dd += wv * ad1[h*64 + c];
    }
    Ps[k*4 + h] = ss;
    Pd[k*4 + h] = dd;
  }
}

// ---------------- layer-1 logits: asrc/adst = x @ Ps/Pd  [N,4] --------------
__global__ __launch_bounds__(256) void k_att1(
    const float* __restrict__ x, const float* __restrict__ Ps,
    const float* __restrict__ Pd, float* __restrict__ asrc,
    float* __restrict__ adst, int N)
{
  __shared__ float PsL[512], PdL[512];
  __shared__ float red[4][64][8];
  const int t = threadIdx.x;
  PsL[t] = Ps[t]; PsL[t+256] = Ps[t+256];
  PdL[t] = Pd[t]; PdL[t+256] = Pd[t+256];
  __syncthreads();
  const int r = t & 63, g = t >> 6;
  const int row = blockIdx.x*64 + r;
  const int rg = min(row, N-1);
  const float* xr = x + (size_t)rg*128;
  float4 pa = make_float4(0.f,0.f,0.f,0.f);
  float4 pb = make_float4(0.f,0.f,0.f,0.f);
  for (int kk = g*32; kk < g*32 + 32; kk++){
    const float xv = xr[kk];
    const float4 s4 = *(const float4*)(PsL + kk*4);
    const float4 d4 = *(const float4*)(PdL + kk*4);
    pa.x += xv*s4.x; pa.y += xv*s4.y; pa.z += xv*s4.z; pa.w += xv*s4.w;
    pb.x += xv*d4.x; pb.y += xv*d4.y; pb.z += xv*d4.z; pb.w += xv*d4.w;
  }
  *(float4*)(&red[g][r][0]) = pa;
  *(float4*)(&red[g][r][4]) = pb;
  __syncthreads();
  if (t < 64 && blockIdx.x*64 + t < N){
    float4 sa = make_float4(0.f,0.f,0.f,0.f);
    float4 sb = make_float4(0.f,0.f,0.f,0.f);
    #pragma unroll
    for (int gg = 0; gg < 4; gg++){
      const float4 qa = *(const float4*)(&red[gg][t][0]);
      const float4 qb = *(const float4*)(&red[gg][t][4]);
      sa.x += qa.x; sa.y += qa.y; sa.z += qa.z; sa.w += qa.w;
      sb.x += qb.x; sb.y += qb.y; sb.z += qb.z; sb.w += qb.w;
    }
    *(float4*)(asrc + (size_t)(blockIdx.x*64 + t)*4) = sa;
    *(float4*)(adst + (size_t)(blockIdx.x*64 + t)*4) = sb;
  }
}

// ---------------- per-edge unnormalized weights (CSR order, no max) ---------
__global__ __launch_bounds__(256) void k_weights(
    const int* __restrict__ csr, const int* __restrict__ dstE,
    const float* __restrict__ asrc, const float* __restrict__ adst,
    float* __restrict__ w, int tot)
{
  const int p = blockIdx.x*256 + threadIdx.x;
  if (p >= tot) return;
  const int s = csr[p];
  const int d = dstE[p];
  const float4 as = *(const float4*)(asrc + (size_t)s*4);
  const float4 ad = *(const float4*)(adst + (size_t)d*4);
  float4 o;
  o.x = __expf(lrelu(as.x + ad.x));
  o.y = __expf(lrelu(as.y + ad.y));
  o.z = __expf(lrelu(as.z + ad.z));
  o.w = __expf(lrelu(as.w + ad.w));
  *(float4*)(w + (size_t)p*4) = o;
}

// ---------------- layer-1 aggregate: gather fp16 x (256B/edge) --------------
// wave per dst node; lane l holds x elems {2l,2l+1}; normalized; fp16 out.
__global__ __launch_bounds__(256) void k_agg_x(
    const int* __restrict__ rowptr, const int* __restrict__ csr,
    const float* __restrict__ w, const __half* __restrict__ xh,
    __half* __restrict__ aggX, int N)
{
  const int n = blockIdx.x*4 + (threadIdx.x >> 6);
  const int l = threadIdx.x & 63;
  if (n >= N) return;
  const int start = rowptr[n];
  const int deg = rowptr[n+1] - start;

  float a0x=0.f,a0y=0.f, a1x=0.f,a1y=0.f, a2x=0.f,a2y=0.f, a3x=0.f,a3y=0.f;
  float4 ds = make_float4(0.f,0.f,0.f,0.f);
  for (int j = 0; j < deg; j++){
    const int p = start + j;
    const int s = csr[p];                                   // broadcast
    const float4 w4 = *(const float4*)(w + (size_t)p*4);    // broadcast
    const float2 xv = __half22float2(*(const __half2*)(xh + (size_t)s*128 + 2*l));
    a0x += w4.x*xv.x; a0y += w4.x*xv.y;
    a1x += w4.y*xv.x; a1y += w4.y*xv.y;
    a2x += w4.z*xv.x; a2y += w4.z*xv.y;
    a3x += w4.w*xv.x; a3y += w4.w*xv.y;
    ds.x += w4.x; ds.y += w4.y; ds.z += w4.z; ds.w += w4.w;
  }
  const float i0 = 1.f/ds.x, i1 = 1.f/ds.y, i2 = 1.f/ds.z, i3 = 1.f/ds.w;
  __half* base = aggX + (size_t)n*512 + 2*l;
  *(__half2*)(base +   0) = __floats2half2_rn(a0x*i0, a0y*i0);
  *(__half2*)(base + 128) = __floats2half2_rn(a1x*i1, a1y*i1);
  *(__half2*)(base + 256) = __floats2half2_rn(a2x*i2, a2y*i2);
  *(__half2*)(base + 384) = __floats2half2_rn(a3x*i3, a3y*i3);
}

// ---------------- layer-1 post-GEMM: agg1 = relu(blockdiag(aggX @ W1) + b) --
__global__ __launch_bounds__(256) void k_gemm_post1(
    const __half* __restrict__ aggX,  // [N,4,128] normalized
    const float* __restrict__ W1,     // [128,256]
    const float* __restrict__ bias,   // [256]
    float* __restrict__ agg1, int N)
{
  __shared__ float AstA[32][68];
  __shared__ float AstB[32][68];
  __shared__ float Bs[32][132];
  const int t  = threadIdx.x;
  const int tx = t & 15, ty = t >> 4;
  const int m0 = (blockIdx.x >> 1) * 64;
  const int cb = blockIdx.x & 1;
  const int hA = 2*cb, hB = 2*cb + 1;

  float acc[4][8];
  #pragma unroll
  for (int i=0;i<4;i++)
    #pragma unroll
    for (int j=0;j<8;j++) acc[i][j] = 0.f;

  for (int k0 = 0; k0 < 128; k0 += 32){
    __syncthreads();
    #pragma unroll
    for (int i = 0; i < 2; i++){
      const int idx = t + i*256;
      const int r = idx >> 3;
      const int c4 = (idx & 7) * 4;
      const int rg = min(m0 + r, N-1);
      const __half2* pA = (const __half2*)(aggX + (size_t)rg*512 + hA*128 + k0 + c4);
      float2 lo = __half22float2(pA[0]);
      float2 hi = __half22float2(pA[1]);
      AstA[c4+0][r] = lo.x; AstA[c4+1][r] = lo.y;
      AstA[c4+2][r] = hi.x; AstA[c4+3][r] = hi.y;
      const __half2* pB = (const __half2*)(aggX + (size_t)rg*512 + hB*128 + k0 + c4);
      lo = __half22float2(pB[0]);
      hi = __half22float2(pB[1]);
      AstB[c4+0][r] = lo.x; AstB[c4+1][r] = lo.y;
      AstB[c4+2][r] = hi.x; AstB[c4+3][r] = hi.y;
    }
    #pragma unroll
    for (int i = 0; i < 4; i++){
      const int idx = t + i*256;
      const int kr = idx >> 5;
      const int cc = (idx & 31) * 4;
      *(float4*)(&Bs[kr][cc]) = *(const float4*)(W1 + (size_t)(k0+kr)*256 + cb*128 + cc);
    }
    __syncthreads();
    #pragma unroll 8
    for (int kk = 0; kk < 32; kk++){
      const float4 aA = *(const float4*)(&AstA[kk][ty*4]);
      const float4 aB = *(const float4*)(&AstB[kk][ty*4]);
      const float4 b0 = *(const float4*)(&Bs[kk][tx*4]);
      const float4 b1 = *(const float4*)(&Bs[kk][64 + tx*4]);
      const float avA[4] = {aA.x, aA.y, aA.z, aA.w};
      const float avB[4] = {aB.x, aB.y, aB.z, aB.w};
      const float bv0[4] = {b0.x, b0.y, b0.z, b0.w};
      const float bv1[4] = {b1.x, b1.y, b1.z, b1.w};
      #pragma unroll
      for (int i=0;i<4;i++)
        #pragma unroll
        for (int j=0;j<4;j++){
          acc[i][j]   += avA[i] * bv0[j];
          acc[i][4+j] += avB[i] * bv1[j];
        }
    }
  }

  float b0v[4], b1v[4];
  #pragma unroll
  for (int j=0;j<4;j++){
    b0v[j] = bias[cb*128 + tx*4 + j];
    b1v[j] = bias[cb*128 + 64 + tx*4 + j];
  }
  #pragma unroll
  for (int i=0;i<4;i++){
    const int row = m0 + ty*4 + i;
    if (row < N){
      float4 o0, o1;
      o0.x = fmaxf(acc[i][0] + b0v[0], 0.f);
      o0.y = fmaxf(acc[i][1] + b0v[1], 0.f);
      o0.z = fmaxf(acc[i][2] + b0v[2], 0.f);
      o0.w = fmaxf(acc[i][3] + b0v[3], 0.f);
      o1.x = fmaxf(acc[i][4] + b1v[0], 0.f);
      o1.y = fmaxf(acc[i][5] + b1v[1], 0.f);
      o1.z = fmaxf(acc[i][6] + b1v[2], 0.f);
      o1.w = fmaxf(acc[i][7] + b1v[3], 0.f);
      *(float4*)(agg1 + (size_t)row*256 + cb*128 + tx*4)      = o0;
      *(float4*)(agg1 + (size_t)row*256 + cb*128 + 64 + tx*4) = o1;
    }
  }
}

// ---------------- layer-2 GEMM: h2t = agg1 @ W2 in TRANSPOSED fp16 layout ---
// h2t halves layout: [row][ch(64)][head(4)] -> one 8B load per lane in agg2.
// epilogue also emits layer-2 attention logits.
__global__ __launch_bounds__(256) void k_gemm_att2(
    const float* __restrict__ in,     // [N,256] = agg1
    const float* __restrict__ W,      // [256,256]
    const float* __restrict__ att_s,  // [4,64]
    const float* __restrict__ att_d,  // [4,64]
    __half* __restrict__ h2t,         // [N,64,4] halves
    float* __restrict__ asrc,         // [N,4]
    float* __restrict__ adst,         // [N,4]
    int N)
{
  constexpr int K = 256, KC = 32;
  __shared__ float Ast[KC][68];
  __shared__ float Bs[KC][132];
  const int t  = threadIdx.x;
  const int tx = t & 15, ty = t >> 4;
  const int m0 = (blockIdx.x >> 1) * 64;
  const int cb = blockIdx.x & 1;           // col block: heads {2cb, 2cb+1}

  float acc[4][8];
  #pragma unroll
  for (int i=0;i<4;i++)
    #pragma unroll
    for (int j=0;j<8;j++) acc[i][j] = 0.f;

  for (int k0 = 0; k0 < K; k0 += KC){
    __syncthreads();
    #pragma unroll
    for (int i = 0; i < 2; i++){
      const int idx = t + i*256;
      const int r = idx >> 3;
      const int c4 = (idx & 7) * 4;
      const int rg = min(m0 + r, N-1);
      const float4 v = *(const float4*)(in + (size_t)rg*K + k0 + c4);
      Ast[c4+0][r] = v.x; Ast[c4+1][r] = v.y;
      Ast[c4+2][r] = v.z; Ast[c4+3][r] = v.w;
    }
    #pragma unroll
    for (int i = 0; i < 4; i++){
      const int idx = t + i*256;
      const int kr = idx >> 5;
      const int cc = (idx & 31) * 4;
      *(float4*)(&Bs[kr][cc]) = *(const float4*)(W + (size_t)(k0+kr)*256 + cb*128 + cc);
    }
    __syncthreads();
    #pragma unroll 8
    for (int kk = 0; kk < KC; kk++){
      const float4 a  = *(const float4*)(&Ast[kk][ty*4]);
      const float4 b0 = *(const float4*)(&Bs[kk][tx*4]);
      const float4 b1 = *(const float4*)(&Bs[kk][64 + tx*4]);
      const float av[4] = {a.x, a.y, a.z, a.w};
      const float bv[8] = {b0.x,b0.y,b0.z,b0.w, b1.x,b1.y,b1.z,b1.w};
      #pragma unroll
      for (int i=0;i<4;i++)
        #pragma unroll
        for (int j=0;j<8;j++) acc[i][j] += av[i] * bv[j];
    }
  }

  const int h0 = cb*2, h1 = cb*2 + 1;
  float as0[4], ad0[4], as1[4], ad1[4];
  #pragma unroll
  for (int j=0;j<4;j++){
    as0[j] = att_s[h0*64 + tx*4 + j];
    ad0[j] = att_d[h0*64 + tx*4 + j];
    as1[j] = att_s[h1*64 + tx*4 + j];
    ad1[j] = att_d[h1*64 + tx*4 + j];
  }
  #pragma unroll
  for (int i=0;i<4;i++){
    const int row = m0 + ty*4 + i;
    const bool ok = row < N;
    if (ok){
      // transposed fp16 store: half index = row*256 + ch*4 + head
      #pragma unroll
      for (int j=0;j<4;j++){
        const int ch = tx*4 + j;
        *(__half2*)(h2t + (size_t)row*256 + ch*4 + 2*cb) =
            __floats2half2_rn(acc[i][j], acc[i][4+j]);
      }
    }
    float vs0 = acc[i][0]*as0[0] + acc[i][1]*as0[1] + acc[i][2]*as0[2] + acc[i][3]*as0[3];
    float vd0 = acc[i][0]*ad0[0] + acc[i][1]*ad0[1] + acc[i][2]*ad0[2] + acc[i][3]*ad0[3];
    float vs1 = acc[i][4]*as1[0] + acc[i][5]*as1[1] + acc[i][6]*as1[2] + acc[i][7]*as1[3];
    float vd1 = acc[i][4]*ad1[0] + acc[i][5]*ad1[1] + acc[i][6]*ad1[2] + acc[i][7]*ad1[3];
    #pragma unroll
    for (int off=1; off<16; off<<=1){
      vs0 += __shfl_xor(vs0, off, 16);
      vd0 += __shfl_xor(vd0, off, 16);
      vs1 += __shfl_xor(vs1, off, 16);
      vd1 += __shfl_xor(vd1, off, 16);
    }
    if (tx == 0 && ok){
      asrc[(size_t)row*4 + h0] = vs0;
      adst[(size_t)row*4 + h0] = vd0;
      asrc[(size_t)row*4 + h1] = vs1;
      adst[(size_t)row*4 + h1] = vd1;
    }
  }
}

// ---------------- layer-2 aggregation: gather fp16 h2t (512B/edge) ----------
__global__ __launch_bounds__(256) void k_node_agg2(
    const int* __restrict__ rowptr, const int* __restrict__ csr,
    const float* __restrict__ w,
    const __half* __restrict__ h2t, const float* __restrict__ bias,
    float* __restrict__ outp, int N)
{
  const int n = blockIdx.x*4 + (threadIdx.x >> 6);
  const int l = threadIdx.x & 63;              // output channel
  if (n >= N) return;
  const int start = rowptr[n];
  const int deg = rowptr[n+1] - start;

  float a0=0.f, a1=0.f, a2=0.f, a3=0.f;
  float d0=0.f, d1=0.f, d2=0.f, d3=0.f;
  for (int j = 0; j < deg; j++){
    const int p = start + j;
    const int s = csr[p];                                 // broadcast
    const float4 w4 = *(const float4*)(w + (size_t)p*4);  // broadcast
    const uint2 u = *(const uint2*)(h2t + (size_t)s*256 + l*4);  // 8B/lane
    const float2 f01 = __half22float2(*reinterpret_cast<const __half2*>(&u.x));
    const float2 f23 = __half22float2(*reinterpret_cast<const __half2*>(&u.y));
    a0 += w4.x*f01.x; a1 += w4.y*f01.y; a2 += w4.z*f23.x; a3 += w4.w*f23.y;
    d0 += w4.x; d1 += w4.y; d2 += w4.z; d3 += w4.w;
  }
  const float val = 0.25f*(a0/d0 + a1/d1 + a2/d2 + a3/d3) + bias[l];
  outp[(size_t)n*64 + l] = fmaxf(val, 0.f);
}

// ---------------- FF head: agg2 -> relu(@ff1) -> @ff2 -------
__global__ __launch_bounds__(256) void k_ff(
    const float* __restrict__ agg2,
    const float* __restrict__ w1, const float* __restrict__ b1,
    const float* __restrict__ w2, const float* __restrict__ b2f,
    float* __restrict__ out, int N)
{
  __shared__ float W1s[64*32];
  __shared__ float B1s[32];
  __shared__ float W2s[64];
  __shared__ float B2s[2];
  const int t = threadIdx.x;
  for (int i=t; i<64*32; i+=256) W1s[i] = w1[i];
  if (t < 32) B1s[t] = b1[t];
  if (t < 64) W2s[t] = w2[t];
  if (t < 2)  B2s[t] = b2f[t];
  __syncthreads();

  const int n = blockIdx.x*256 + t;
  if (n >= N) return;

  float t1[32];
  #pragma unroll
  for (int j=0;j<32;j++) t1[j] = B1s[j];
  #pragma unroll
  for (int c=0;c<64;c++){
    const float fc = agg2[(long)n*64 + c];
    #pragma unroll
    for (int j=0;j<32;j++) t1[j] += fc * W1s[c*32 + j];
  }
  float o0 = B2s[0], o1 = B2s[1];
  #pragma unroll
  for (int j=0;j<32;j++){
    const float v = t1[j] > 0.f ? t1[j] : 0.f;
    o0 += v * W2s[j*2 + 0];
    o1 += v * W2s[j*2 + 1];
  }
  out[(long)n*2 + 0] = o0;
  out[(long)n*2 + 1] = o1;
}

extern "C" void kernel_launch(void* const* d_in, const int* in_sizes, int n_in,
                              void* d_out, int out_size, void* d_ws, size_t ws_size,
                              hipStream_t stream)
{
  const float* x      = (const float*)d_in[0];
  const int*   ei     = (const int*)  d_in[1];
  const float* W1     = (const float*)d_in[3];
  const float* att_s1 = (const float*)d_in[4];
  const float* att_d1 = (const float*)d_in[5];
  const float* b1     = (const float*)d_in[6];
  const float* W2     = (const float*)d_in[7];
  const float* att_s2 = (const float*)d_in[8];
  const float* att_d2 = (const float*)d_in[9];
  const float* b2     = (const float*)d_in[10];
  const float* ff1w   = (const float*)d_in[11];
  const float* ff1b   = (const float*)d_in[12];
  const float* ff2w   = (const float*)d_in[13];
  const float* ff2b   = (const float*)d_in[14];
  float* out = (float*)d_out;

  const int N = in_sizes[0] / 128;
  const int E = in_sizes[1] / 2;
  const int tot = E + N;

  // ---- workspace (R0 time-shared: aggX layer-1; h2t+agg2 layer-2) ----
  char* p = (char*)d_ws;
  __half* aggX = (__half*)p;                         // [N,512] fp16 (layer-1)
  __half* h2t  = (__half*)p;                         // [N,256] fp16 (layer-2)
  float*  agg2 = (float*)(p + (size_t)N*256*2);      // [N,64]  f32  (layer-2)
  p += (size_t)N*256*4 + (size_t)N*64*4;             // region >= all phases
  float* agg1 = (float*)p;                           // [N,256] f32
  __half* xh  = (__half*)p;                          // [N,128] fp16, aliased:
  p += (size_t)N*256*4;                              //   dead before agg1 write
  float* w    = (float*)p;  p += (size_t)tot*4*4;    // [tot,4] edge weights
  float* asrc = (float*)p;  p += (size_t)N*4*4;      // [N,4]
  float* adst = (float*)p;  p += (size_t)N*4*4;      // [N,4]
  float* Ps   = (float*)p;  p += 512*4;              // [128,4]
  float* Pd   = (float*)p;  p += 512*4;              // [128,4]
  int* deg    = (int*)p;    p += (size_t)N*4;
  int* rowptr = (int*)p;    p += (size_t)(N+1)*4;
  int* cursor = (int*)p;    p += (size_t)N*4;
  int* csr    = (int*)p;    p += (size_t)tot*4;
  int* dstE   = (int*)p;    p += (size_t)tot*4;

  const int gE  = (tot + 255) / 256;
  const int gN4 = (N + 3) / 4;
  const int g64 = (N + 63) / 64;

  // ---- CSR build (shared by both layers) ----
  k_zero <<<(N+255)/256,256,0,stream>>>(deg, N);
  k_count<<<gE,256,0,stream>>>(ei, E, N, deg);
  k_scan <<<1,256,0,stream>>>(deg, rowptr, cursor, N);
  k_fill <<<gE,256,0,stream>>>(ei, E, N, cursor, csr, dstE);

  // ---- layer 1: aggregate-then-transform (fp16 gather payload) ----
  k_cvt_x<<<1024,256,0,stream>>>(x, xh, (long)N*64);
  k_prep<<<1,256,0,stream>>>(W1, att_s1, att_d1, Ps, Pd);
  k_att1<<<g64,256,0,stream>>>(x, Ps, Pd, asrc, adst, N);
  k_weights<<<gE,256,0,stream>>>(csr, dstE, asrc, adst, w, tot);
  k_agg_x<<<gN4,256,0,stream>>>(rowptr, csr, w, xh, aggX, N);
  k_gemm_post1<<<g64*2,256,0,stream>>>(aggX, W1, b1, agg1, N);

  // ---- layer 2 (head mean; fp16 transposed gather payload) ----
  k_gemm_att2<<<g64*2,256,0,stream>>>(agg1, W2, att_s2, att_d2, h2t, asrc, adst, N);
  k_weights<<<gE,256,0,stream>>>(csr, dstE, asrc, adst, w, tot);
  k_node_agg2<<<gN4,256,0,stream>>>(rowptr, csr, w, h2t, b2, agg2, N);

  // ---- feed-forward head ----
  k_ff<<<(N+255)/256,256,0,stream>>>(agg2, ff1w, ff1b, ff2w, ff2b, out, N);
}

// Round 9
// 506.965 us; speedup vs baseline: 1.2511x; 1.2091x over previous
//
#include <hip/hip_runtime.h>
#include <hip/hip_fp16.h>

__device__ __forceinline__ float lrelu(float x){ return x >= 0.f ? x : 0.2f*x; }

#define SB 256  // scan blocks

// ---------------- zero degree counters ----------------
__global__ __launch_bounds__(256) void k_zero(int* __restrict__ p, int n)
{
  int i = blockIdx.x*256 + threadIdx.x;
  if (i < n) p[i] = 0;
}

// ---------------- count in-degree per destination ----------------
__global__ __launch_bounds__(256) void k_count(const int* __restrict__ ei,
                                               int E, int N, int* __restrict__ deg)
{
  const int e = blockIdx.x*256 + threadIdx.x;
  if (e >= E + N) return;
  const int d = (e < E) ? ei[E + e] : (e - E);
  atomicAdd(&deg[d], 1);
}

// ---------------- parallel scan phase 1: per-block chunk sums ----------------
__global__ __launch_bounds__(256) void k_scan1(const int* __restrict__ deg,
                                               int* __restrict__ bsum, int N)
{
  __shared__ int sh[256];
  const int chunk = (N + SB - 1) / SB;
  const int lo = blockIdx.x * chunk;
  const int hi = min(lo + chunk, N);
  int s = 0;
  for (int i = lo + threadIdx.x; i < hi; i += 256) s += deg[i];
  sh[threadIdx.x] = s;
  __syncthreads();
  #pragma unroll
  for (int off = 128; off; off >>= 1){
    if (threadIdx.x < off) sh[threadIdx.x] += sh[threadIdx.x + off];
    __syncthreads();
  }
  if (threadIdx.x == 0) bsum[blockIdx.x] = sh[0];
}

// ---------------- parallel scan phase 2: exclusive scan of 256 partials -----
__global__ __launch_bounds__(256) void k_scan2(int* __restrict__ bsum)
{
  __shared__ int sh[256];
  const int v = bsum[threadIdx.x];
  sh[threadIdx.x] = v;
  __syncthreads();
  for (int off = 1; off < 256; off <<= 1){
    int t = 0;
    if (threadIdx.x >= off) t = sh[threadIdx.x - off];
    __syncthreads();
    sh[threadIdx.x] += t;
    __syncthreads();
  }
  bsum[threadIdx.x] = sh[threadIdx.x] - v;  // exclusive
}

// ---------------- parallel scan phase 3: chunk-local scan + base -------------
__global__ __launch_bounds__(256) void k_scan3(const int* __restrict__ deg,
                                               const int* __restrict__ bsum,
                                               int* __restrict__ rowptr,
                                               int* __restrict__ cursor, int N)
{
  __shared__ int sh[256];
  const int chunk = (N + SB - 1) / SB;
  const int lo = blockIdx.x * chunk;
  const int hi = min(lo + chunk, N);
  int base = bsum[blockIdx.x];
  for (int start = lo; start < hi; start += 256){
    const int i = start + threadIdx.x;
    const int v = (i < hi) ? deg[i] : 0;
    sh[threadIdx.x] = v;
    __syncthreads();
    for (int off = 1; off < 256; off <<= 1){
      int t = 0;
      if (threadIdx.x >= off) t = sh[threadIdx.x - off];
      __syncthreads();
      sh[threadIdx.x] += t;
      __syncthreads();
    }
    if (i < hi){
      const int excl = base + sh[threadIdx.x] - v;
      rowptr[i] = excl;
      cursor[i] = excl;
    }
    base += sh[255];
    __syncthreads();
  }
  if (blockIdx.x == SB-1 && threadIdx.x == 0) rowptr[N] = base;
}

// ---------------- fill CSR src lists (+ dst per position) ----------------
__global__ __launch_bounds__(256) void k_fill(const int* __restrict__ ei,
                                              int E, int N, int* __restrict__ cursor,
                                              int* __restrict__ csr,
                                              int* __restrict__ dstE)
{
  const int e = blockIdx.x*256 + threadIdx.x;
  if (e >= E + N) return;
  int s, d;
  if (e < E){ s = ei[e]; d = ei[E + e]; } else { s = d = e - E; }
  const int pos = atomicAdd(&cursor[d], 1);
  csr[pos] = s;
  dstE[pos] = d;
}

// ---------------- x -> fp16 copy (gather payload shrink) ----------------
__global__ __launch_bounds__(256) void k_cvt_x(const float* __restrict__ x,
                                               __half* __restrict__ xh, long n2)
{
  long i  = (long)blockIdx.x*256 + threadIdx.x;
  long st = (long)gridDim.x*256;
  for (; i < n2; i += st){
    const float2 v = *(const float2*)(x + 2*i);
    *(__half2*)(xh + 2*i) = __floats2half2_rn(v.x, v.y);
  }
}

// ---------------- Ps/Pd = per-head W1 @ att vectors: [128,4] ----------------
__global__ __launch_bounds__(256) void k_prep(
    const float* __restrict__ W1, const float* __restrict__ as1,
    const float* __restrict__ ad1, float* __restrict__ Ps, float* __restrict__ Pd)
{
  const int t = threadIdx.x;
  for (int idx = t; idx < 512; idx += 256){
    const int k = idx >> 2, h = idx & 3;
    float ss = 0.f, dd = 0.f;
    for (int c = 0; c < 64; c++){
      const float wv = W1[k*256 + h*64 + c];
      ss += wv * as1[h*64 + c];
      dd += wv * ad1[h*64 + c];
    }
    Ps[k*4 + h] = ss;
    Pd[k*4 + h] = dd;
  }
}

// ---------------- layer-1 logits: asrc/adst = x @ Ps/Pd  [N,4] --------------
__global__ __launch_bounds__(256) void k_att1(
    const float* __restrict__ x, const float* __restrict__ Ps,
    const float* __restrict__ Pd, float* __restrict__ asrc,
    float* __restrict__ adst, int N)
{
  __shared__ float PsL[512], PdL[512];
  __shared__ float red[4][64][8];
  const int t = threadIdx.x;
  PsL[t] = Ps[t]; PsL[t+256] = Ps[t+256];
  PdL[t] = Pd[t]; PdL[t+256] = Pd[t+256];
  __syncthreads();
  const int r = t & 63, g = t >> 6;
  const int row = blockIdx.x*64 + r;
  const int rg = min(row, N-1);
  const float* xr = x + (size_t)rg*128;
  float4 pa = make_float4(0.f,0.f,0.f,0.f);
  float4 pb = make_float4(0.f,0.f,0.f,0.f);
  for (int kk = g*32; kk < g*32 + 32; kk++){
    const float xv = xr[kk];
    const float4 s4 = *(const float4*)(PsL + kk*4);
    const float4 d4 = *(const float4*)(PdL + kk*4);
    pa.x += xv*s4.x; pa.y += xv*s4.y; pa.z += xv*s4.z; pa.w += xv*s4.w;
    pb.x += xv*d4.x; pb.y += xv*d4.y; pb.z += xv*d4.z; pb.w += xv*d4.w;
  }
  *(float4*)(&red[g][r][0]) = pa;
  *(float4*)(&red[g][r][4]) = pb;
  __syncthreads();
  if (t < 64 && blockIdx.x*64 + t < N){
    float4 sa = make_float4(0.f,0.f,0.f,0.f);
    float4 sb = make_float4(0.f,0.f,0.f,0.f);
    #pragma unroll
    for (int gg = 0; gg < 4; gg++){
      const float4 qa = *(const float4*)(&red[gg][t][0]);
      const float4 qb = *(const float4*)(&red[gg][t][4]);
      sa.x += qa.x; sa.y += qa.y; sa.z += qa.z; sa.w += qa.w;
      sb.x += qb.x; sb.y += qb.y; sb.z += qb.z; sb.w += qb.w;
    }
    *(float4*)(asrc + (size_t)(blockIdx.x*64 + t)*4) = sa;
    *(float4*)(adst + (size_t)(blockIdx.x*64 + t)*4) = sb;
  }
}

// ---------------- per-edge unnormalized weights (CSR order, no max) ---------
__global__ __launch_bounds__(256) void k_weights(
    const int* __restrict__ csr, const int* __restrict__ dstE,
    const float* __restrict__ asrc, const float* __restrict__ adst,
    float* __restrict__ w, int tot)
{
  const int p = blockIdx.x*256 + threadIdx.x;
  if (p >= tot) return;
  const int s = csr[p];
  const int d = dstE[p];
  const float4 as = *(const float4*)(asrc + (size_t)s*4);
  const float4 ad = *(const float4*)(adst + (size_t)d*4);
  float4 o;
  o.x = __expf(lrelu(as.x + ad.x));
  o.y = __expf(lrelu(as.y + ad.y));
  o.z = __expf(lrelu(as.z + ad.z));
  o.w = __expf(lrelu(as.w + ad.w));
  *(float4*)(w + (size_t)p*4) = o;
}

// ---------------- layer-1 aggregate: gather fp16 x (256B/edge) --------------
__global__ __launch_bounds__(256) void k_agg_x(
    const int* __restrict__ rowptr, const int* __restrict__ csr,
    const float* __restrict__ w, const __half* __restrict__ xh,
    __half* __restrict__ aggX, int N)
{
  const int n = blockIdx.x*4 + (threadIdx.x >> 6);
  const int l = threadIdx.x & 63;
  if (n >= N) return;
  const int start = rowptr[n];
  const int deg = rowptr[n+1] - start;

  float a0x=0.f,a0y=0.f, a1x=0.f,a1y=0.f, a2x=0.f,a2y=0.f, a3x=0.f,a3y=0.f;
  float4 ds = make_float4(0.f,0.f,0.f,0.f);
  for (int j = 0; j < deg; j++){
    const int p = start + j;
    const int s = csr[p];                                   // broadcast
    const float4 w4 = *(const float4*)(w + (size_t)p*4);    // broadcast
    const float2 xv = __half22float2(*(const __half2*)(xh + (size_t)s*128 + 2*l));
    a0x += w4.x*xv.x; a0y += w4.x*xv.y;
    a1x += w4.y*xv.x; a1y += w4.y*xv.y;
    a2x += w4.z*xv.x; a2y += w4.z*xv.y;
    a3x += w4.w*xv.x; a3y += w4.w*xv.y;
    ds.x += w4.x; ds.y += w4.y; ds.z += w4.z; ds.w += w4.w;
  }
  const float i0 = 1.f/ds.x, i1 = 1.f/ds.y, i2 = 1.f/ds.z, i3 = 1.f/ds.w;
  __half* base = aggX + (size_t)n*512 + 2*l;
  *(__half2*)(base +   0) = __floats2half2_rn(a0x*i0, a0y*i0);
  *(__half2*)(base + 128) = __floats2half2_rn(a1x*i1, a1y*i1);
  *(__half2*)(base + 256) = __floats2half2_rn(a2x*i2, a2y*i2);
  *(__half2*)(base + 384) = __floats2half2_rn(a3x*i3, a3y*i3);
}

// ---------------- layer-1 post-GEMM: agg1 = relu(blockdiag(aggX @ W1) + b) --
__global__ __launch_bounds__(256) void k_gemm_post1(
    const __half* __restrict__ aggX,  // [N,4,128] normalized
    const float* __restrict__ W1,     // [128,256]
    const float* __restrict__ bias,   // [256]
    float* __restrict__ agg1, int N)
{
  __shared__ float AstA[32][68];
  __shared__ float AstB[32][68];
  __shared__ float Bs[32][132];
  const int t  = threadIdx.x;
  const int tx = t & 15, ty = t >> 4;
  const int m0 = (blockIdx.x >> 1) * 64;
  const int cb = blockIdx.x & 1;
  const int hA = 2*cb, hB = 2*cb + 1;

  float acc[4][8];
  #pragma unroll
  for (int i=0;i<4;i++)
    #pragma unroll
    for (int j=0;j<8;j++) acc[i][j] = 0.f;

  for (int k0 = 0; k0 < 128; k0 += 32){
    __syncthreads();
    #pragma unroll
    for (int i = 0; i < 2; i++){
      const int idx = t + i*256;
      const int r = idx >> 3;
      const int c4 = (idx & 7) * 4;
      const int rg = min(m0 + r, N-1);
      const __half2* pA = (const __half2*)(aggX + (size_t)rg*512 + hA*128 + k0 + c4);
      float2 lo = __half22float2(pA[0]);
      float2 hi = __half22float2(pA[1]);
      AstA[c4+0][r] = lo.x; AstA[c4+1][r] = lo.y;
      AstA[c4+2][r] = hi.x; AstA[c4+3][r] = hi.y;
      const __half2* pB = (const __half2*)(aggX + (size_t)rg*512 + hB*128 + k0 + c4);
      lo = __half22float2(pB[0]);
      hi = __half22float2(pB[1]);
      AstB[c4+0][r] = lo.x; AstB[c4+1][r] = lo.y;
      AstB[c4+2][r] = hi.x; AstB[c4+3][r] = hi.y;
    }
    #pragma unroll
    for (int i = 0; i < 4; i++){
      const int idx = t + i*256;
      const int kr = idx >> 5;
      const int cc = (idx & 31) * 4;
      *(float4*)(&Bs[kr][cc]) = *(const float4*)(W1 + (size_t)(k0+kr)*256 + cb*128 + cc);
    }
    __syncthreads();
    #pragma unroll 8
    for (int kk = 0; kk < 32; kk++){
      const float4 aA = *(const float4*)(&AstA[kk][ty*4]);
      const float4 aB = *(const float4*)(&AstB[kk][ty*4]);
      const float4 b0 = *(const float4*)(&Bs[kk][tx*4]);
      const float4 b1 = *(const float4*)(&Bs[kk][64 + tx*4]);
      const float avA[4] = {aA.x, aA.y, aA.z, aA.w};
      const float avB[4] = {aB.x, aB.y, aB.z, aB.w};
      const float bv0[4] = {b0.x, b0.y, b0.z, b0.w};
      const float bv1[4] = {b1.x, b1.y, b1.z, b1.w};
      #pragma unroll
      for (int i=0;i<4;i++)
        #pragma unroll
        for (int j=0;j<4;j++){
          acc[i][j]   += avA[i] * bv0[j];
          acc[i][4+j] += avB[i] * bv1[j];
        }
    }
  }

  float b0v[4], b1v[4];
  #pragma unroll
  for (int j=0;j<4;j++){
    b0v[j] = bias[cb*128 + tx*4 + j];
    b1v[j] = bias[cb*128 + 64 + tx*4 + j];
  }
  #pragma unroll
  for (int i=0;i<4;i++){
    const int row = m0 + ty*4 + i;
    if (row < N){
      float4 o0, o1;
      o0.x = fmaxf(acc[i][0] + b0v[0], 0.f);
      o0.y = fmaxf(acc[i][1] + b0v[1], 0.f);
      o0.z = fmaxf(acc[i][2] + b0v[2], 0.f);
      o0.w = fmaxf(acc[i][3] + b0v[3], 0.f);
      o1.x = fmaxf(acc[i][4] + b1v[0], 0.f);
      o1.y = fmaxf(acc[i][5] + b1v[1], 0.f);
      o1.z = fmaxf(acc[i][6] + b1v[2], 0.f);
      o1.w = fmaxf(acc[i][7] + b1v[3], 0.f);
      *(float4*)(agg1 + (size_t)row*256 + cb*128 + tx*4)      = o0;
      *(float4*)(agg1 + (size_t)row*256 + cb*128 + 64 + tx*4) = o1;
    }
  }
}

// ---------------- layer-2 GEMM: h2t = agg1 @ W2 in TRANSPOSED fp16 layout ---
__global__ __launch_bounds__(256) void k_gemm_att2(
    const float* __restrict__ in,     // [N,256] = agg1
    const float* __restrict__ W,      // [256,256]
    const float* __restrict__ att_s,  // [4,64]
    const float* __restrict__ att_d,  // [4,64]
    __half* __restrict__ h2t,         // [N,64,4] halves
    float* __restrict__ asrc,         // [N,4]
    float* __restrict__ adst,         // [N,4]
    int N)
{
  constexpr int K = 256, KC = 32;
  __shared__ float Ast[KC][68];
  __shared__ float Bs[KC][132];
  const int t  = threadIdx.x;
  const int tx = t & 15, ty = t >> 4;
  const int m0 = (blockIdx.x >> 1) * 64;
  const int cb = blockIdx.x & 1;           // col block: heads {2cb, 2cb+1}

  float acc[4][8];
  #pragma unroll
  for (int i=0;i<4;i++)
    #pragma unroll
    for (int j=0;j<8;j++) acc[i][j] = 0.f;

  for (int k0 = 0; k0 < K; k0 += KC){
    __syncthreads();
    #pragma unroll
    for (int i = 0; i < 2; i++){
      const int idx = t + i*256;
      const int r = idx >> 3;
      const int c4 = (idx & 7) * 4;
      const int rg = min(m0 + r, N-1);
      const float4 v = *(const float4*)(in + (size_t)rg*K + k0 + c4);
      Ast[c4+0][r] = v.x; Ast[c4+1][r] = v.y;
      Ast[c4+2][r] = v.z; Ast[c4+3][r] = v.w;
    }
    #pragma unroll
    for (int i = 0; i < 4; i++){
      const int idx = t + i*256;
      const int kr = idx >> 5;
      const int cc = (idx & 31) * 4;
      *(float4*)(&Bs[kr][cc]) = *(const float4*)(W + (size_t)(k0+kr)*256 + cb*128 + cc);
    }
    __syncthreads();
    #pragma unroll 8
    for (int kk = 0; kk < KC; kk++){
      const float4 a  = *(const float4*)(&Ast[kk][ty*4]);
      const float4 b0 = *(const float4*)(&Bs[kk][tx*4]);
      const float4 b1 = *(const float4*)(&Bs[kk][64 + tx*4]);
      const float av[4] = {a.x, a.y, a.z, a.w};
      const float bv[8] = {b0.x,b0.y,b0.z,b0.w, b1.x,b1.y,b1.z,b1.w};
      #pragma unroll
      for (int i=0;i<4;i++)
        #pragma unroll
        for (int j=0;j<8;j++) acc[i][j] += av[i] * bv[j];
    }
  }

  const int h0 = cb*2, h1 = cb*2 + 1;
  float as0[4], ad0[4], as1[4], ad1[4];
  #pragma unroll
  for (int j=0;j<4;j++){
    as0[j] = att_s[h0*64 + tx*4 + j];
    ad0[j] = att_d[h0*64 + tx*4 + j];
    as1[j] = att_s[h1*64 + tx*4 + j];
    ad1[j] = att_d[h1*64 + tx*4 + j];
  }
  #pragma unroll
  for (int i=0;i<4;i++){
    const int row = m0 + ty*4 + i;
    const bool ok = row < N;
    if (ok){
      #pragma unroll
      for (int j=0;j<4;j++){
        const int ch = tx*4 + j;
        *(__half2*)(h2t + (size_t)row*256 + ch*4 + 2*cb) =
            __floats2half2_rn(acc[i][j], acc[i][4+j]);
      }
    }
    float vs0 = acc[i][0]*as0[0] + acc[i][1]*as0[1] + acc[i][2]*as0[2] + acc[i][3]*as0[3];
    float vd0 = acc[i][0]*ad0[0] + acc[i][1]*ad0[1] + acc[i][2]*ad0[2] + acc[i][3]*ad0[3];
    float vs1 = acc[i][4]*as1[0] + acc[i][5]*as1[1] + acc[i][6]*as1[2] + acc[i][7]*as1[3];
    float vd1 = acc[i][4]*ad1[0] + acc[i][5]*ad1[1] + acc[i][6]*ad1[2] + acc[i][7]*ad1[3];
    #pragma unroll
    for (int off=1; off<16; off<<=1){
      vs0 += __shfl_xor(vs0, off, 16);
      vd0 += __shfl_xor(vd0, off, 16);
      vs1 += __shfl_xor(vs1, off, 16);
      vd1 += __shfl_xor(vd1, off, 16);
    }
    if (tx == 0 && ok){
      asrc[(size_t)row*4 + h0] = vs0;
      adst[(size_t)row*4 + h0] = vd0;
      asrc[(size_t)row*4 + h1] = vs1;
      adst[(size_t)row*4 + h1] = vd1;
    }
  }
}

// ---------------- layer-2 aggregation: gather fp16 h2t (512B/edge) ----------
__global__ __launch_bounds__(256) void k_node_agg2(
    const int* __restrict__ rowptr, const int* __restrict__ csr,
    const float* __restrict__ w,
    const __half* __restrict__ h2t, const float* __restrict__ bias,
    float* __restrict__ outp, int N)
{
  const int n = blockIdx.x*4 + (threadIdx.x >> 6);
  const int l = threadIdx.x & 63;              // output channel
  if (n >= N) return;
  const int start = rowptr[n];
  const int deg = rowptr[n+1] - start;

  float a0=0.f, a1=0.f, a2=0.f, a3=0.f;
  float d0=0.f, d1=0.f, d2=0.f, d3=0.f;
  for (int j = 0; j < deg; j++){
    const int p = start + j;
    const int s = csr[p];                                 // broadcast
    const float4 w4 = *(const float4*)(w + (size_t)p*4);  // broadcast
    const uint2 u = *(const uint2*)(h2t + (size_t)s*256 + l*4);  // 8B/lane
    const float2 f01 = __half22float2(*reinterpret_cast<const __half2*>(&u.x));
    const float2 f23 = __half22float2(*reinterpret_cast<const __half2*>(&u.y));
    a0 += w4.x*f01.x; a1 += w4.y*f01.y; a2 += w4.z*f23.x; a3 += w4.w*f23.y;
    d0 += w4.x; d1 += w4.y; d2 += w4.z; d3 += w4.w;
  }
  const float val = 0.25f*(a0/d0 + a1/d1 + a2/d2 + a3/d3) + bias[l];
  outp[(size_t)n*64 + l] = fmaxf(val, 0.f);
}

// ---------------- FF head: agg2 -> relu(@ff1) -> @ff2 -------
__global__ __launch_bounds__(256) void k_ff(
    const float* __restrict__ agg2,
    const float* __restrict__ w1, const float* __restrict__ b1,
    const float* __restrict__ w2, const float* __restrict__ b2f,
    float* __restrict__ out, int N)
{
  __shared__ float W1s[64*32];
  __shared__ float B1s[32];
  __shared__ float W2s[64];
  __shared__ float B2s[2];
  const int t = threadIdx.x;
  for (int i=t; i<64*32; i+=256) W1s[i] = w1[i];
  if (t < 32) B1s[t] = b1[t];
  if (t < 64) W2s[t] = w2[t];
  if (t < 2)  B2s[t] = b2f[t];
  __syncthreads();

  const int n = blockIdx.x*256 + t;
  if (n >= N) return;

  float t1[32];
  #pragma unroll
  for (int j=0;j<32;j++) t1[j] = B1s[j];
  #pragma unroll
  for (int c=0;c<64;c++){
    const float fc = agg2[(long)n*64 + c];
    #pragma unroll
    for (int j=0;j<32;j++) t1[j] += fc * W1s[c*32 + j];
  }
  float o0 = B2s[0], o1 = B2s[1];
  #pragma unroll
  for (int j=0;j<32;j++){
    const float v = t1[j] > 0.f ? t1[j] : 0.f;
    o0 += v * W2s[j*2 + 0];
    o1 += v * W2s[j*2 + 1];
  }
  out[(long)n*2 + 0] = o0;
  out[(long)n*2 + 1] = o1;
}

extern "C" void kernel_launch(void* const* d_in, const int* in_sizes, int n_in,
                              void* d_out, int out_size, void* d_ws, size_t ws_size,
                              hipStream_t stream)
{
  const float* x      = (const float*)d_in[0];
  const int*   ei     = (const int*)  d_in[1];
  const float* W1     = (const float*)d_in[3];
  const float* att_s1 = (const float*)d_in[4];
  const float* att_d1 = (const float*)d_in[5];
  const float* b1     = (const float*)d_in[6];
  const float* W2     = (const float*)d_in[7];
  const float* att_s2 = (const float*)d_in[8];
  const float* att_d2 = (const float*)d_in[9];
  const float* b2     = (const float*)d_in[10];
  const float* ff1w   = (const float*)d_in[11];
  const float* ff1b   = (const float*)d_in[12];
  const float* ff2w   = (const float*)d_in[13];
  const float* ff2b   = (const float*)d_in[14];
  float* out = (float*)d_out;

  const int N = in_sizes[0] / 128;
  const int E = in_sizes[1] / 2;
  const int tot = E + N;

  // ---- workspace (R0 time-shared: aggX layer-1; h2t+agg2 layer-2) ----
  char* p = (char*)d_ws;
  __half* aggX = (__half*)p;                         // [N,512] fp16 (layer-1)
  __half* h2t  = (__half*)p;                         // [N,256] fp16 (layer-2)
  float*  agg2 = (float*)(p + (size_t)N*256*2);      // [N,64]  f32  (layer-2)
  p += (size_t)N*256*4 + (size_t)N*64*4;             // region >= all phases
  float* agg1 = (float*)p;                           // [N,256] f32
  __half* xh  = (__half*)p;                          // [N,128] fp16, aliased:
  p += (size_t)N*256*4;                              //   dead before agg1 write
  float* w    = (float*)p;  p += (size_t)tot*4*4;    // [tot,4] edge weights
  float* asrc = (float*)p;  p += (size_t)N*4*4;      // [N,4]
  float* adst = (float*)p;  p += (size_t)N*4*4;      // [N,4]
  float* Ps   = (float*)p;  p += 512*4;              // [128,4]
  float* Pd   = (float*)p;  p += 512*4;              // [128,4]
  int* deg    = (int*)p;    p += (size_t)N*4;
  int* rowptr = (int*)p;    p += (size_t)(N+1)*4;
  int* cursor = (int*)p;    p += (size_t)N*4;
  int* bsum   = (int*)p;    p += SB*4;
  int* csr    = (int*)p;    p += (size_t)tot*4;
  int* dstE   = (int*)p;    p += (size_t)tot*4;

  const int gE  = (tot + 255) / 256;
  const int gN4 = (N + 3) / 4;
  const int g64 = (N + 63) / 64;

  // ---- CSR build (shared by both layers) ----
  k_zero <<<(N+255)/256,256,0,stream>>>(deg, N);
  k_count<<<gE,256,0,stream>>>(ei, E, N, deg);
  k_scan1<<<SB,256,0,stream>>>(deg, bsum, N);
  k_scan2<<<1,256,0,stream>>>(bsum);
  k_scan3<<<SB,256,0,stream>>>(deg, bsum, rowptr, cursor, N);
  k_fill <<<gE,256,0,stream>>>(ei, E, N, cursor, csr, dstE);

  // ---- layer 1: aggregate-then-transform (fp16 gather payload) ----
  k_cvt_x<<<1024,256,0,stream>>>(x, xh, (long)N*64);
  k_prep<<<1,256,0,stream>>>(W1, att_s1, att_d1, Ps, Pd);
  k_att1<<<g64,256,0,stream>>>(x, Ps, Pd, asrc, adst, N);
  k_weights<<<gE,256,0,stream>>>(csr, dstE, asrc, adst, w, tot);
  k_agg_x<<<gN4,256,0,stream>>>(rowptr, csr, w, xh, aggX, N);
  k_gemm_post1<<<g64*2,256,0,stream>>>(aggX, W1, b1, agg1, N);

  // ---- layer 2 (head mean; fp16 transposed gather payload) ----
  k_gemm_att2<<<g64*2,256,0,stream>>>(agg1, W2, att_s2, att_d2, h2t, asrc, adst, N);
  k_weights<<<gE,256,0,stream>>>(csr, dstE, asrc, adst, w, tot);
  k_node_agg2<<<gN4,256,0,stream>>>(rowptr, csr, w, h2t, b2, agg2, N);

  // ---- feed-forward head ----
  k_ff<<<(N+255)/256,256,0,stream>>>(agg2, ff1w, ff1b, ff2w, ff2b, out, N);
}

// Round 10
// 485.987 us; speedup vs baseline: 1.3051x; 1.0432x over previous
//
#include <hip/hip_runtime.h>
#include <hip/hip_fp16.h>

typedef _Float16 v8h __attribute__((ext_vector_type(8)));
typedef float    v4f __attribute__((ext_vector_type(4)));

__device__ __forceinline__ float lrelu(float x){ return x >= 0.f ? x : 0.2f*x; }

#define SB 256  // scan blocks

// ---------------- zero degree counters ----------------
__global__ __launch_bounds__(256) void k_zero(int* __restrict__ p, int n)
{
  int i = blockIdx.x*256 + threadIdx.x;
  if (i < n) p[i] = 0;
}

// ---------------- count in-degree per destination ----------------
__global__ __launch_bounds__(256) void k_count(const int* __restrict__ ei,
                                               int E, int N, int* __restrict__ deg)
{
  const int e = blockIdx.x*256 + threadIdx.x;
  if (e >= E + N) return;
  const int d = (e < E) ? ei[E + e] : (e - E);
  atomicAdd(&deg[d], 1);
}

// ---------------- parallel scan phase 1: per-block chunk sums ----------------
__global__ __launch_bounds__(256) void k_scan1(const int* __restrict__ deg,
                                               int* __restrict__ bsum, int N)
{
  __shared__ int sh[256];
  const int chunk = (N + SB - 1) / SB;
  const int lo = blockIdx.x * chunk;
  const int hi = min(lo + chunk, N);
  int s = 0;
  for (int i = lo + threadIdx.x; i < hi; i += 256) s += deg[i];
  sh[threadIdx.x] = s;
  __syncthreads();
  #pragma unroll
  for (int off = 128; off; off >>= 1){
    if (threadIdx.x < off) sh[threadIdx.x] += sh[threadIdx.x + off];
    __syncthreads();
  }
  if (threadIdx.x == 0) bsum[blockIdx.x] = sh[0];
}

// ---------------- parallel scan phase 2: exclusive scan of 256 partials -----
__global__ __launch_bounds__(256) void k_scan2(int* __restrict__ bsum)
{
  __shared__ int sh[256];
  const int v = bsum[threadIdx.x];
  sh[threadIdx.x] = v;
  __syncthreads();
  for (int off = 1; off < 256; off <<= 1){
    int t = 0;
    if (threadIdx.x >= off) t = sh[threadIdx.x - off];
    __syncthreads();
    sh[threadIdx.x] += t;
    __syncthreads();
  }
  bsum[threadIdx.x] = sh[threadIdx.x] - v;  // exclusive
}

// ---------------- parallel scan phase 3: chunk-local scan + base -------------
__global__ __launch_bounds__(256) void k_scan3(const int* __restrict__ deg,
                                               const int* __restrict__ bsum,
                                               int* __restrict__ rowptr,
                                               int* __restrict__ cursor, int N)
{
  __shared__ int sh[256];
  const int chunk = (N + SB - 1) / SB;
  const int lo = blockIdx.x * chunk;
  const int hi = min(lo + chunk, N);
  int base = bsum[blockIdx.x];
  for (int start = lo; start < hi; start += 256){
    const int i = start + threadIdx.x;
    const int v = (i < hi) ? deg[i] : 0;
    sh[threadIdx.x] = v;
    __syncthreads();
    for (int off = 1; off < 256; off <<= 1){
      int t = 0;
      if (threadIdx.x >= off) t = sh[threadIdx.x - off];
      __syncthreads();
      sh[threadIdx.x] += t;
      __syncthreads();
    }
    if (i < hi){
      const int excl = base + sh[threadIdx.x] - v;
      rowptr[i] = excl;
      cursor[i] = excl;
    }
    base += sh[255];
    __syncthreads();
  }
  if (blockIdx.x == SB-1 && threadIdx.x == 0) rowptr[N] = base;
}

// ---------------- fill CSR src lists (+ dst per position) ----------------
__global__ __launch_bounds__(256) void k_fill(const int* __restrict__ ei,
                                              int E, int N, int* __restrict__ cursor,
                                              int* __restrict__ csr,
                                              int* __restrict__ dstE)
{
  const int e = blockIdx.x*256 + threadIdx.x;
  if (e >= E + N) return;
  int s, d;
  if (e < E){ s = ei[e]; d = ei[E + e]; } else { s = d = e - E; }
  const int pos = atomicAdd(&cursor[d], 1);
  csr[pos] = s;
  dstE[pos] = d;
}

// ---------------- x -> fp16 copy (gather payload shrink) ----------------
__global__ __launch_bounds__(256) void k_cvt_x(const float* __restrict__ x,
                                               __half* __restrict__ xh, long n2)
{
  long i  = (long)blockIdx.x*256 + threadIdx.x;
  long st = (long)gridDim.x*256;
  for (; i < n2; i += st){
    const float2 v = *(const float2*)(x + 2*i);
    *(__half2*)(xh + 2*i) = __floats2half2_rn(v.x, v.y);
  }
}

// ---------------- W [K,C] f32 -> Wt [C,K] fp16 (transpose + convert) --------
__global__ __launch_bounds__(256) void k_cvt_wt(const float* __restrict__ W,
                                                _Float16* __restrict__ Wt,
                                                int K, int C)
{
  const int idx = blockIdx.x*256 + threadIdx.x;
  if (idx >= K*C) return;
  const int c = idx / K, k = idx % K;     // writes coalesced along k
  Wt[(size_t)c*K + k] = (_Float16)W[(size_t)k*C + c];
}

// ---------------- Ps/Pd = per-head W1 @ att vectors: [128,4] ----------------
__global__ __launch_bounds__(256) void k_prep(
    const float* __restrict__ W1, const float* __restrict__ as1,
    const float* __restrict__ ad1, float* __restrict__ Ps, float* __restrict__ Pd)
{
  const int t = threadIdx.x;
  for (int idx = t; idx < 512; idx += 256){
    const int k = idx >> 2, h = idx & 3;
    float ss = 0.f, dd = 0.f;
    for (int c = 0; c < 64; c++){
      const float wv = W1[k*256 + h*64 + c];
      ss += wv * as1[h*64 + c];
      dd += wv * ad1[h*64 + c];
    }
    Ps[k*4 + h] = ss;
    Pd[k*4 + h] = dd;
  }
}

// ---------------- layer-1 logits: asrc/adst = x @ Ps/Pd  [N,4] --------------
__global__ __launch_bounds__(256) void k_att1(
    const float* __restrict__ x, const float* __restrict__ Ps,
    const float* __restrict__ Pd, float* __restrict__ asrc,
    float* __restrict__ adst, int N)
{
  __shared__ float PsL[512], PdL[512];
  __shared__ float red[4][64][8];
  const int t = threadIdx.x;
  PsL[t] = Ps[t]; PsL[t+256] = Ps[t+256];
  PdL[t] = Pd[t]; PdL[t+256] = Pd[t+256];
  __syncthreads();
  const int r = t & 63, g = t >> 6;
  const int row = blockIdx.x*64 + r;
  const int rg = min(row, N-1);
  const float* xr = x + (size_t)rg*128;
  float4 pa = make_float4(0.f,0.f,0.f,0.f);
  float4 pb = make_float4(0.f,0.f,0.f,0.f);
  for (int kk = g*32; kk < g*32 + 32; kk++){
    const float xv = xr[kk];
    const float4 s4 = *(const float4*)(PsL + kk*4);
    const float4 d4 = *(const float4*)(PdL + kk*4);
    pa.x += xv*s4.x; pa.y += xv*s4.y; pa.z += xv*s4.z; pa.w += xv*s4.w;
    pb.x += xv*d4.x; pb.y += xv*d4.y; pb.z += xv*d4.z; pb.w += xv*d4.w;
  }
  *(float4*)(&red[g][r][0]) = pa;
  *(float4*)(&red[g][r][4]) = pb;
  __syncthreads();
  if (t < 64 && blockIdx.x*64 + t < N){
    float4 sa = make_float4(0.f,0.f,0.f,0.f);
    float4 sb = make_float4(0.f,0.f,0.f,0.f);
    #pragma unroll
    for (int gg = 0; gg < 4; gg++){
      const float4 qa = *(const float4*)(&red[gg][t][0]);
      const float4 qb = *(const float4*)(&red[gg][t][4]);
      sa.x += qa.x; sa.y += qa.y; sa.z += qa.z; sa.w += qa.w;
      sb.x += qb.x; sb.y += qb.y; sb.z += qb.z; sb.w += qb.w;
    }
    *(float4*)(asrc + (size_t)(blockIdx.x*64 + t)*4) = sa;
    *(float4*)(adst + (size_t)(blockIdx.x*64 + t)*4) = sb;
  }
}

// ---------------- per-edge unnormalized weights (CSR order, no max) ---------
__global__ __launch_bounds__(256) void k_weights(
    const int* __restrict__ csr, const int* __restrict__ dstE,
    const float* __restrict__ asrc, const float* __restrict__ adst,
    float* __restrict__ w, int tot)
{
  const int p = blockIdx.x*256 + threadIdx.x;
  if (p >= tot) return;
  const int s = csr[p];
  const int d = dstE[p];
  const float4 as = *(const float4*)(asrc + (size_t)s*4);
  const float4 ad = *(const float4*)(adst + (size_t)d*4);
  float4 o;
  o.x = __expf(lrelu(as.x + ad.x));
  o.y = __expf(lrelu(as.y + ad.y));
  o.z = __expf(lrelu(as.z + ad.z));
  o.w = __expf(lrelu(as.w + ad.w));
  *(float4*)(w + (size_t)p*4) = o;
}

// ---------------- layer-1 aggregate: gather fp16 x (256B/edge) --------------
__global__ __launch_bounds__(256) void k_agg_x(
    const int* __restrict__ rowptr, const int* __restrict__ csr,
    const float* __restrict__ w, const __half* __restrict__ xh,
    __half* __restrict__ aggX, int N)
{
  const int n = blockIdx.x*4 + (threadIdx.x >> 6);
  const int l = threadIdx.x & 63;
  if (n >= N) return;
  const int start = rowptr[n];
  const int deg = rowptr[n+1] - start;

  float a0x=0.f,a0y=0.f, a1x=0.f,a1y=0.f, a2x=0.f,a2y=0.f, a3x=0.f,a3y=0.f;
  float4 ds = make_float4(0.f,0.f,0.f,0.f);
  for (int j = 0; j < deg; j++){
    const int p = start + j;
    const int s = csr[p];                                   // broadcast
    const float4 w4 = *(const float4*)(w + (size_t)p*4);    // broadcast
    const float2 xv = __half22float2(*(const __half2*)(xh + (size_t)s*128 + 2*l));
    a0x += w4.x*xv.x; a0y += w4.x*xv.y;
    a1x += w4.y*xv.x; a1y += w4.y*xv.y;
    a2x += w4.z*xv.x; a2y += w4.z*xv.y;
    a3x += w4.w*xv.x; a3y += w4.w*xv.y;
    ds.x += w4.x; ds.y += w4.y; ds.z += w4.z; ds.w += w4.w;
  }
  const float i0 = 1.f/ds.x, i1 = 1.f/ds.y, i2 = 1.f/ds.z, i3 = 1.f/ds.w;
  __half* base = aggX + (size_t)n*512 + 2*l;
  *(__half2*)(base +   0) = __floats2half2_rn(a0x*i0, a0y*i0);
  *(__half2*)(base + 128) = __floats2half2_rn(a1x*i1, a1y*i1);
  *(__half2*)(base + 256) = __floats2half2_rn(a2x*i2, a2y*i2);
  *(__half2*)(base + 384) = __floats2half2_rn(a3x*i3, a3y*i3);
}

// ---------------- layer-1 post-GEMM (MFMA, block-diagonal) ------------------
// agg1[n, h*64+ch] = relu( sum_k aggX[n,h,k]*W1[k,h*64+ch] + b ), f32 out.
// wave w: rows [row0+16w, +16) x cols [0,256). col-tile ct -> head ct>>2.
__global__ __launch_bounds__(256) void k_gemm1_mfma(
    const _Float16* __restrict__ aggX,  // [N,4,128]
    const _Float16* __restrict__ W1t,   // [256,128]  (Wt[c][k])
    const float* __restrict__ bias,     // [256]
    float* __restrict__ agg1, int N)
{
  const int w = threadIdx.x >> 6, l = threadIdx.x & 63;
  const int lr = l & 15, lk = l >> 4;
  const int row0 = blockIdx.x*64 + w*16;
  const int rowa = min(row0 + lr, N-1);
  v4f acc[16] = {};
  for (int ks = 0; ks < 4; ks++){
    const int k = ks*32 + lk*8;
    v8h a[4];
    #pragma unroll
    for (int h = 0; h < 4; h++)
      a[h] = *(const v8h*)(aggX + (size_t)rowa*512 + h*128 + k);
    #pragma unroll
    for (int ct = 0; ct < 16; ct++){
      const int col = ct*16 + lr;
      const v8h b = *(const v8h*)(W1t + (size_t)col*128 + k);
      acc[ct] = __builtin_amdgcn_mfma_f32_16x16x32_f16(a[ct>>2], b, acc[ct], 0,0,0);
    }
  }
  #pragma unroll
  for (int ct = 0; ct < 16; ct++){
    const int col = ct*16 + lr;
    const float bv = bias[col];
    #pragma unroll
    for (int j = 0; j < 4; j++){
      const int row = row0 + lk*4 + j;
      if (row < N)
        agg1[(size_t)row*256 + col] = fmaxf(acc[ct][j] + bv, 0.f);
    }
  }
}

// ---------------- layer-2 GEMM (MFMA) + logits + transposed fp16 store ------
// h2 = agg1 @ W2 ; h2t[row][ch*4+head] fp16 ; asrc/adst logits fused.
__global__ __launch_bounds__(256) void k_gemm2_mfma(
    const float* __restrict__ agg1,     // [N,256] f32
    const _Float16* __restrict__ W2t,   // [256,256] (Wt[c][k])
    const float* __restrict__ att_s, const float* __restrict__ att_d,
    __half* __restrict__ h2t,           // [N,64,4] halves
    float* __restrict__ asrc, float* __restrict__ adst, int N)
{
  const int w = threadIdx.x >> 6, l = threadIdx.x & 63;
  const int lr = l & 15, lk = l >> 4;
  const int row0 = blockIdx.x*64 + w*16;
  const int rowa = min(row0 + lr, N-1);
  v4f acc[16] = {};
  for (int ks = 0; ks < 8; ks++){
    const int k = ks*32 + lk*8;
    const float4 a0 = *(const float4*)(agg1 + (size_t)rowa*256 + k);
    const float4 a1 = *(const float4*)(agg1 + (size_t)rowa*256 + k + 4);
    v8h a;
    a[0]=(_Float16)a0.x; a[1]=(_Float16)a0.y; a[2]=(_Float16)a0.z; a[3]=(_Float16)a0.w;
    a[4]=(_Float16)a1.x; a[5]=(_Float16)a1.y; a[6]=(_Float16)a1.z; a[7]=(_Float16)a1.w;
    #pragma unroll
    for (int ct = 0; ct < 16; ct++){
      const int col = ct*16 + lr;
      const v8h b = *(const v8h*)(W2t + (size_t)col*256 + k);
      acc[ct] = __builtin_amdgcn_mfma_f32_16x16x32_f16(a, b, acc[ct], 0,0,0);
    }
  }
  // per-lane attention coefficients: coltile ct -> head ct>>2, idx (ct&3)*16+lr
  float AS[16], AD[16];
  #pragma unroll
  for (int ct = 0; ct < 16; ct++){
    const int h = ct >> 2, idx = (ct & 3)*16 + lr;
    AS[ct] = att_s[h*64 + idx];
    AD[ct] = att_d[h*64 + idx];
  }
  #pragma unroll
  for (int j = 0; j < 4; j++){
    const int row = row0 + lk*4 + j;
    const bool ok = row < N;
    float vs[4] = {0.f,0.f,0.f,0.f}, vd[4] = {0.f,0.f,0.f,0.f};
    #pragma unroll
    for (int ct = 0; ct < 16; ct++){
      const float v = acc[ct][j];
      const int col = ct*16 + lr;
      if (ok)
        h2t[(size_t)row*256 + (col & 63)*4 + (col >> 6)] = __float2half(v);
      vs[ct>>2] += v * AS[ct];
      vd[ct>>2] += v * AD[ct];
    }
    #pragma unroll
    for (int h = 0; h < 4; h++){
      float s = vs[h], d = vd[h];
      #pragma unroll
      for (int off = 1; off < 16; off <<= 1){
        s += __shfl_xor(s, off, 16);
        d += __shfl_xor(d, off, 16);
      }
      if (lr == 0 && ok){
        asrc[(size_t)row*4 + h] = s;
        adst[(size_t)row*4 + h] = d;
      }
    }
  }
}

// ---------------- layer-2 aggregation: gather fp16 h2t (512B/edge) ----------
__global__ __launch_bounds__(256) void k_node_agg2(
    const int* __restrict__ rowptr, const int* __restrict__ csr,
    const float* __restrict__ w,
    const __half* __restrict__ h2t, const float* __restrict__ bias,
    float* __restrict__ outp, int N)
{
  const int n = blockIdx.x*4 + (threadIdx.x >> 6);
  const int l = threadIdx.x & 63;              // output channel
  if (n >= N) return;
  const int start = rowptr[n];
  const int deg = rowptr[n+1] - start;

  float a0=0.f, a1=0.f, a2=0.f, a3=0.f;
  float d0=0.f, d1=0.f, d2=0.f, d3=0.f;
  for (int j = 0; j < deg; j++){
    const int p = start + j;
    const int s = csr[p];                                 // broadcast
    const float4 w4 = *(const float4*)(w + (size_t)p*4);  // broadcast
    const uint2 u = *(const uint2*)(h2t + (size_t)s*256 + l*4);  // 8B/lane
    const float2 f01 = __half22float2(*reinterpret_cast<const __half2*>(&u.x));
    const float2 f23 = __half22float2(*reinterpret_cast<const __half2*>(&u.y));
    a0 += w4.x*f01.x; a1 += w4.y*f01.y; a2 += w4.z*f23.x; a3 += w4.w*f23.y;
    d0 += w4.x; d1 += w4.y; d2 += w4.z; d3 += w4.w;
  }
  const float val = 0.25f*(a0/d0 + a1/d1 + a2/d2 + a3/d3) + bias[l];
  outp[(size_t)n*64 + l] = fmaxf(val, 0.f);
}

// ---------------- FF head: agg2 -> relu(@ff1) -> @ff2 -------
__global__ __launch_bounds__(256) void k_ff(
    const float* __restrict__ agg2,
    const float* __restrict__ w1, const float* __restrict__ b1,
    const float* __restrict__ w2, const float* __restrict__ b2f,
    float* __restrict__ out, int N)
{
  __shared__ float W1s[64*32];
  __shared__ float B1s[32];
  __shared__ float W2s[64];
  __shared__ float B2s[2];
  const int t = threadIdx.x;
  for (int i=t; i<64*32; i+=256) W1s[i] = w1[i];
  if (t < 32) B1s[t] = b1[t];
  if (t < 64) W2s[t] = w2[t];
  if (t < 2)  B2s[t] = b2f[t];
  __syncthreads();

  const int n = blockIdx.x*256 + t;
  if (n >= N) return;

  float t1[32];
  #pragma unroll
  for (int j=0;j<32;j++) t1[j] = B1s[j];
  #pragma unroll
  for (int c=0;c<64;c++){
    const float fc = agg2[(long)n*64 + c];
    #pragma unroll
    for (int j=0;j<32;j++) t1[j] += fc * W1s[c*32 + j];
  }
  float o0 = B2s[0], o1 = B2s[1];
  #pragma unroll
  for (int j=0;j<32;j++){
    const float v = t1[j] > 0.f ? t1[j] : 0.f;
    o0 += v * W2s[j*2 + 0];
    o1 += v * W2s[j*2 + 1];
  }
  out[(long)n*2 + 0] = o0;
  out[(long)n*2 + 1] = o1;
}

extern "C" void kernel_launch(void* const* d_in, const int* in_sizes, int n_in,
                              void* d_out, int out_size, void* d_ws, size_t ws_size,
                              hipStream_t stream)
{
  const float* x      = (const float*)d_in[0];
  const int*   ei     = (const int*)  d_in[1];
  const float* W1     = (const float*)d_in[3];
  const float* att_s1 = (const float*)d_in[4];
  const float* att_d1 = (const float*)d_in[5];
  const float* b1     = (const float*)d_in[6];
  const float* W2     = (const float*)d_in[7];
  const float* att_s2 = (const float*)d_in[8];
  const float* att_d2 = (const float*)d_in[9];
  const float* b2     = (const float*)d_in[10];
  const float* ff1w   = (const float*)d_in[11];
  const float* ff1b   = (const float*)d_in[12];
  const float* ff2w   = (const float*)d_in[13];
  const float* ff2b   = (const float*)d_in[14];
  float* out = (float*)d_out;

  const int N = in_sizes[0] / 128;
  const int E = in_sizes[1] / 2;
  const int tot = E + N;

  // ---- workspace (R0 time-shared: aggX layer-1; h2t+agg2 layer-2) ----
  char* p = (char*)d_ws;
  __half* aggX = (__half*)p;                         // [N,512] fp16 (layer-1)
  __half* h2t  = (__half*)p;                         // [N,256] fp16 (layer-2)
  float*  agg2 = (float*)(p + (size_t)N*256*2);      // [N,64]  f32  (layer-2)
  p += (size_t)N*256*4 + (size_t)N*64*4;             // region >= all phases
  float* agg1 = (float*)p;                           // [N,256] f32
  __half* xh  = (__half*)p;                          // [N,128] fp16, aliased:
  p += (size_t)N*256*4;                              //   dead before agg1 write
  float* w    = (float*)p;  p += (size_t)tot*4*4;    // [tot,4] edge weights
  float* asrc = (float*)p;  p += (size_t)N*4*4;      // [N,4]
  float* adst = (float*)p;  p += (size_t)N*4*4;      // [N,4]
  float* Ps   = (float*)p;  p += 512*4;              // [128,4]
  float* Pd   = (float*)p;  p += 512*4;              // [128,4]
  _Float16* W1t = (_Float16*)p; p += 256*128*2;      // [256,128] fp16
  _Float16* W2t = (_Float16*)p; p += 256*256*2;      // [256,256] fp16
  int* deg    = (int*)p;    p += (size_t)N*4;
  int* rowptr = (int*)p;    p += (size_t)(N+1)*4;
  int* cursor = (int*)p;    p += (size_t)N*4;
  int* bsum   = (int*)p;    p += SB*4;
  int* csr    = (int*)p;    p += (size_t)tot*4;
  int* dstE   = (int*)p;    p += (size_t)tot*4;

  const int gE  = (tot + 255) / 256;
  const int gN4 = (N + 3) / 4;
  const int g64 = (N + 63) / 64;

  // ---- CSR build (shared by both layers) ----
  k_zero <<<(N+255)/256,256,0,stream>>>(deg, N);
  k_count<<<gE,256,0,stream>>>(ei, E, N, deg);
  k_scan1<<<SB,256,0,stream>>>(deg, bsum, N);
  k_scan2<<<1,256,0,stream>>>(bsum);
  k_scan3<<<SB,256,0,stream>>>(deg, bsum, rowptr, cursor, N);
  k_fill <<<gE,256,0,stream>>>(ei, E, N, cursor, csr, dstE);

  // ---- weight prep (fp16 transposed copies) ----
  k_cvt_wt<<<128,256,0,stream>>>(W1, W1t, 128, 256);
  k_cvt_wt<<<256,256,0,stream>>>(W2, W2t, 256, 256);

  // ---- layer 1: aggregate-then-transform ----
  k_cvt_x<<<1024,256,0,stream>>>(x, xh, (long)N*64);
  k_prep<<<1,256,0,stream>>>(W1, att_s1, att_d1, Ps, Pd);
  k_att1<<<g64,256,0,stream>>>(x, Ps, Pd, asrc, adst, N);
  k_weights<<<gE,256,0,stream>>>(csr, dstE, asrc, adst, w, tot);
  k_agg_x<<<gN4,256,0,stream>>>(rowptr, csr, w, xh, (__half*)aggX, N);
  k_gemm1_mfma<<<g64,256,0,stream>>>((const _Float16*)aggX, W1t, b1, agg1, N);

  // ---- layer 2 (head mean; MFMA GEMM + fp16 transposed gather payload) ----
  k_gemm2_mfma<<<g64,256,0,stream>>>(agg1, W2t, att_s2, att_d2, h2t, asrc, adst, N);
  k_weights<<<gE,256,0,stream>>>(csr, dstE, asrc, adst, w, tot);
  k_node_agg2<<<gN4,256,0,stream>>>(rowptr, csr, w, h2t, b2, agg2, N);

  // ---- feed-forward head ----
  k_ff<<<(N+255)/256,256,0,stream>>>(agg2, ff1w, ff1b, ff2w, ff2b, out, N);
}

// Round 11
// 428.098 us; speedup vs baseline: 1.4816x; 1.1352x over previous
//
#include <hip/hip_runtime.h>
#include <hip/hip_fp16.h>

typedef _Float16 v8h __attribute__((ext_vector_type(8)));
typedef float    v4f __attribute__((ext_vector_type(4)));

__device__ __forceinline__ float lrelu(float x){ return x >= 0.f ? x : 0.2f*x; }

#define SB 256  // scan blocks

// ---------------- zero degree counters ----------------
__global__ __launch_bounds__(256) void k_zero(int* __restrict__ p, int n)
{
  int i = blockIdx.x*256 + threadIdx.x;
  if (i < n) p[i] = 0;
}

// ---------------- count in-degree per destination ----------------
__global__ __launch_bounds__(256) void k_count(const int* __restrict__ ei,
                                               int E, int N, int* __restrict__ deg)
{
  const int e = blockIdx.x*256 + threadIdx.x;
  if (e >= E + N) return;
  const int d = (e < E) ? ei[E + e] : (e - E);
  atomicAdd(&deg[d], 1);
}

// ---------------- parallel scan phase 1: per-block chunk sums ----------------
__global__ __launch_bounds__(256) void k_scan1(const int* __restrict__ deg,
                                               int* __restrict__ bsum, int N)
{
  __shared__ int sh[256];
  const int chunk = (N + SB - 1) / SB;
  const int lo = blockIdx.x * chunk;
  const int hi = min(lo + chunk, N);
  int s = 0;
  for (int i = lo + threadIdx.x; i < hi; i += 256) s += deg[i];
  sh[threadIdx.x] = s;
  __syncthreads();
  #pragma unroll
  for (int off = 128; off; off >>= 1){
    if (threadIdx.x < off) sh[threadIdx.x] += sh[threadIdx.x + off];
    __syncthreads();
  }
  if (threadIdx.x == 0) bsum[blockIdx.x] = sh[0];
}

// ---------------- parallel scan phase 2: exclusive scan of 256 partials -----
__global__ __launch_bounds__(256) void k_scan2(int* __restrict__ bsum)
{
  __shared__ int sh[256];
  const int v = bsum[threadIdx.x];
  sh[threadIdx.x] = v;
  __syncthreads();
  for (int off = 1; off < 256; off <<= 1){
    int t = 0;
    if (threadIdx.x >= off) t = sh[threadIdx.x - off];
    __syncthreads();
    sh[threadIdx.x] += t;
    __syncthreads();
  }
  bsum[threadIdx.x] = sh[threadIdx.x] - v;  // exclusive
}

// ---------------- parallel scan phase 3: chunk-local scan + base -------------
__global__ __launch_bounds__(256) void k_scan3(const int* __restrict__ deg,
                                               const int* __restrict__ bsum,
                                               int* __restrict__ rowptr,
                                               int* __restrict__ cursor, int N)
{
  __shared__ int sh[256];
  const int chunk = (N + SB - 1) / SB;
  const int lo = blockIdx.x * chunk;
  const int hi = min(lo + chunk, N);
  int base = bsum[blockIdx.x];
  for (int start = lo; start < hi; start += 256){
    const int i = start + threadIdx.x;
    const int v = (i < hi) ? deg[i] : 0;
    sh[threadIdx.x] = v;
    __syncthreads();
    for (int off = 1; off < 256; off <<= 1){
      int t = 0;
      if (threadIdx.x >= off) t = sh[threadIdx.x - off];
      __syncthreads();
      sh[threadIdx.x] += t;
      __syncthreads();
    }
    if (i < hi){
      const int excl = base + sh[threadIdx.x] - v;
      rowptr[i] = excl;
      cursor[i] = excl;
    }
    base += sh[255];
    __syncthreads();
  }
  if (blockIdx.x == SB-1 && threadIdx.x == 0) rowptr[N] = base;
}

// ---------------- fill CSR src lists ----------------
__global__ __launch_bounds__(256) void k_fill(const int* __restrict__ ei,
                                              int E, int N, int* __restrict__ cursor,
                                              int* __restrict__ csr)
{
  const int e = blockIdx.x*256 + threadIdx.x;
  if (e >= E + N) return;
  int s, d;
  if (e < E){ s = ei[e]; d = ei[E + e]; } else { s = d = e - E; }
  const int pos = atomicAdd(&cursor[d], 1);
  csr[pos] = s;
}

// ---------------- x -> fp16 copy (gather payload shrink) ----------------
__global__ __launch_bounds__(256) void k_cvt_x(const float* __restrict__ x,
                                               __half* __restrict__ xh, long n2)
{
  long i  = (long)blockIdx.x*256 + threadIdx.x;
  long st = (long)gridDim.x*256;
  for (; i < n2; i += st){
    const float2 v = *(const float2*)(x + 2*i);
    *(__half2*)(xh + 2*i) = __floats2half2_rn(v.x, v.y);
  }
}

// ---------------- W [K,C] f32 -> Wt [C,K] fp16 (transpose + convert) --------
__global__ __launch_bounds__(256) void k_cvt_wt(const float* __restrict__ W,
                                                _Float16* __restrict__ Wt,
                                                int K, int C)
{
  const int idx = blockIdx.x*256 + threadIdx.x;
  if (idx >= K*C) return;
  const int c = idx / K, k = idx % K;     // writes coalesced along k
  Wt[(size_t)c*K + k] = (_Float16)W[(size_t)k*C + c];
}

// ---------------- Ps/Pd = per-head W1 @ att vectors: [128,4] ----------------
__global__ __launch_bounds__(256) void k_prep(
    const float* __restrict__ W1, const float* __restrict__ as1,
    const float* __restrict__ ad1, float* __restrict__ Ps, float* __restrict__ Pd)
{
  const int t = threadIdx.x;
  for (int idx = t; idx < 512; idx += 256){
    const int k = idx >> 2, h = idx & 3;
    float ss = 0.f, dd = 0.f;
    for (int c = 0; c < 64; c++){
      const float wv = W1[k*256 + h*64 + c];
      ss += wv * as1[h*64 + c];
      dd += wv * ad1[h*64 + c];
    }
    Ps[k*4 + h] = ss;
    Pd[k*4 + h] = dd;
  }
}

// ---------------- layer-1 logits: asrc/adst = x @ Ps/Pd  [N,4] --------------
__global__ __launch_bounds__(256) void k_att1(
    const float* __restrict__ x, const float* __restrict__ Ps,
    const float* __restrict__ Pd, float* __restrict__ asrc,
    float* __restrict__ adst, int N)
{
  __shared__ float PsL[512], PdL[512];
  __shared__ float red[4][64][8];
  const int t = threadIdx.x;
  PsL[t] = Ps[t]; PsL[t+256] = Ps[t+256];
  PdL[t] = Pd[t]; PdL[t+256] = Pd[t+256];
  __syncthreads();
  const int r = t & 63, g = t >> 6;
  const int row = blockIdx.x*64 + r;
  const int rg = min(row, N-1);
  const float* xr = x + (size_t)rg*128;
  float4 pa = make_float4(0.f,0.f,0.f,0.f);
  float4 pb = make_float4(0.f,0.f,0.f,0.f);
  for (int kk = g*32; kk < g*32 + 32; kk++){
    const float xv = xr[kk];
    const float4 s4 = *(const float4*)(PsL + kk*4);
    const float4 d4 = *(const float4*)(PdL + kk*4);
    pa.x += xv*s4.x; pa.y += xv*s4.y; pa.z += xv*s4.z; pa.w += xv*s4.w;
    pb.x += xv*d4.x; pb.y += xv*d4.y; pb.z += xv*d4.z; pb.w += xv*d4.w;
  }
  *(float4*)(&red[g][r][0]) = pa;
  *(float4*)(&red[g][r][4]) = pb;
  __syncthreads();
  if (t < 64 && blockIdx.x*64 + t < N){
    float4 sa = make_float4(0.f,0.f,0.f,0.f);
    float4 sb = make_float4(0.f,0.f,0.f,0.f);
    #pragma unroll
    for (int gg = 0; gg < 4; gg++){
      const float4 qa = *(const float4*)(&red[gg][t][0]);
      const float4 qb = *(const float4*)(&red[gg][t][4]);
      sa.x += qa.x; sa.y += qa.y; sa.z += qa.z; sa.w += qa.w;
      sb.x += qb.x; sb.y += qb.y; sb.z += qb.z; sb.w += qb.w;
    }
    *(float4*)(asrc + (size_t)(blockIdx.x*64 + t)*4) = sa;
    *(float4*)(adst + (size_t)(blockIdx.x*64 + t)*4) = sb;
  }
}

// ---------------- layer-1 aggregate: inline weights + 4x unrolled gather ----
// wave per dst node; lane l holds x elems {2l,2l+1}; asrc is L2-resident.
__global__ __launch_bounds__(256) void k_agg_x(
    const int* __restrict__ rowptr, const int* __restrict__ csr,
    const float* __restrict__ asrc, const float* __restrict__ adst,
    const __half* __restrict__ xh,
    __half* __restrict__ aggX, int N)
{
  const int n = blockIdx.x*4 + (threadIdx.x >> 6);
  const int l = threadIdx.x & 63;
  if (n >= N) return;
  const int start = rowptr[n];
  const int deg = rowptr[n+1] - start;
  const float4 ad = *(const float4*)(adst + (size_t)n*4);

  float a0x=0.f,a0y=0.f, a1x=0.f,a1y=0.f, a2x=0.f,a2y=0.f, a3x=0.f,a3y=0.f;
  float4 ds = make_float4(0.f,0.f,0.f,0.f);
  int j = 0;
  for (; j + 4 <= deg; j += 4){
    const int p0 = start + j;
    const int s0 = csr[p0+0], s1 = csr[p0+1], s2 = csr[p0+2], s3 = csr[p0+3];
    const float4 q0 = *(const float4*)(asrc + (size_t)s0*4);   // L2 hit
    const float4 q1 = *(const float4*)(asrc + (size_t)s1*4);
    const float4 q2 = *(const float4*)(asrc + (size_t)s2*4);
    const float4 q3 = *(const float4*)(asrc + (size_t)s3*4);
    const __half2 v0 = *(const __half2*)(xh + (size_t)s0*128 + 2*l);
    const __half2 v1 = *(const __half2*)(xh + (size_t)s1*128 + 2*l);
    const __half2 v2 = *(const __half2*)(xh + (size_t)s2*128 + 2*l);
    const __half2 v3 = *(const __half2*)(xh + (size_t)s3*128 + 2*l);
    float4 w0, w1, w2, w3;
    w0.x = __expf(lrelu(q0.x+ad.x)); w0.y = __expf(lrelu(q0.y+ad.y));
    w0.z = __expf(lrelu(q0.z+ad.z)); w0.w = __expf(lrelu(q0.w+ad.w));
    w1.x = __expf(lrelu(q1.x+ad.x)); w1.y = __expf(lrelu(q1.y+ad.y));
    w1.z = __expf(lrelu(q1.z+ad.z)); w1.w = __expf(lrelu(q1.w+ad.w));
    w2.x = __expf(lrelu(q2.x+ad.x)); w2.y = __expf(lrelu(q2.y+ad.y));
    w2.z = __expf(lrelu(q2.z+ad.z)); w2.w = __expf(lrelu(q2.w+ad.w));
    w3.x = __expf(lrelu(q3.x+ad.x)); w3.y = __expf(lrelu(q3.y+ad.y));
    w3.z = __expf(lrelu(q3.z+ad.z)); w3.w = __expf(lrelu(q3.w+ad.w));
    const float2 f0 = __half22float2(v0);
    const float2 f1 = __half22float2(v1);
    const float2 f2 = __half22float2(v2);
    const float2 f3 = __half22float2(v3);
    a0x += w0.x*f0.x + w1.x*f1.x + w2.x*f2.x + w3.x*f3.x;
    a0y += w0.x*f0.y + w1.x*f1.y + w2.x*f2.y + w3.x*f3.y;
    a1x += w0.y*f0.x + w1.y*f1.x + w2.y*f2.x + w3.y*f3.x;
    a1y += w0.y*f0.y + w1.y*f1.y + w2.y*f2.y + w3.y*f3.y;
    a2x += w0.z*f0.x + w1.z*f1.x + w2.z*f2.x + w3.z*f3.x;
    a2y += w0.z*f0.y + w1.z*f1.y + w2.z*f2.y + w3.z*f3.y;
    a3x += w0.w*f0.x + w1.w*f1.x + w2.w*f2.x + w3.w*f3.x;
    a3y += w0.w*f0.y + w1.w*f1.y + w2.w*f2.y + w3.w*f3.y;
    ds.x += w0.x+w1.x+w2.x+w3.x;
    ds.y += w0.y+w1.y+w2.y+w3.y;
    ds.z += w0.z+w1.z+w2.z+w3.z;
    ds.w += w0.w+w1.w+w2.w+w3.w;
  }
  for (; j < deg; j++){
    const int s = csr[start + j];
    const float4 q = *(const float4*)(asrc + (size_t)s*4);
    const float2 f = __half22float2(*(const __half2*)(xh + (size_t)s*128 + 2*l));
    float4 w4;
    w4.x = __expf(lrelu(q.x+ad.x)); w4.y = __expf(lrelu(q.y+ad.y));
    w4.z = __expf(lrelu(q.z+ad.z)); w4.w = __expf(lrelu(q.w+ad.w));
    a0x += w4.x*f.x; a0y += w4.x*f.y;
    a1x += w4.y*f.x; a1y += w4.y*f.y;
    a2x += w4.z*f.x; a2y += w4.z*f.y;
    a3x += w4.w*f.x; a3y += w4.w*f.y;
    ds.x += w4.x; ds.y += w4.y; ds.z += w4.z; ds.w += w4.w;
  }
  const float i0 = 1.f/ds.x, i1 = 1.f/ds.y, i2 = 1.f/ds.z, i3 = 1.f/ds.w;
  __half* base = aggX + (size_t)n*512 + 2*l;
  *(__half2*)(base +   0) = __floats2half2_rn(a0x*i0, a0y*i0);
  *(__half2*)(base + 128) = __floats2half2_rn(a1x*i1, a1y*i1);
  *(__half2*)(base + 256) = __floats2half2_rn(a2x*i2, a2y*i2);
  *(__half2*)(base + 384) = __floats2half2_rn(a3x*i3, a3y*i3);
}

// ---------------- layer-1 post-GEMM (MFMA, block-diagonal) ------------------
__global__ __launch_bounds__(256) void k_gemm1_mfma(
    const _Float16* __restrict__ aggX,  // [N,4,128]
    const _Float16* __restrict__ W1t,   // [256,128]  (Wt[c][k])
    const float* __restrict__ bias,     // [256]
    float* __restrict__ agg1, int N)
{
  const int w = threadIdx.x >> 6, l = threadIdx.x & 63;
  const int lr = l & 15, lk = l >> 4;
  const int row0 = blockIdx.x*64 + w*16;
  const int rowa = min(row0 + lr, N-1);
  v4f acc[16] = {};
  for (int ks = 0; ks < 4; ks++){
    const int k = ks*32 + lk*8;
    v8h a[4];
    #pragma unroll
    for (int h = 0; h < 4; h++)
      a[h] = *(const v8h*)(aggX + (size_t)rowa*512 + h*128 + k);
    #pragma unroll
    for (int ct = 0; ct < 16; ct++){
      const int col = ct*16 + lr;
      const v8h b = *(const v8h*)(W1t + (size_t)col*128 + k);
      acc[ct] = __builtin_amdgcn_mfma_f32_16x16x32_f16(a[ct>>2], b, acc[ct], 0,0,0);
    }
  }
  #pragma unroll
  for (int ct = 0; ct < 16; ct++){
    const int col = ct*16 + lr;
    const float bv = bias[col];
    #pragma unroll
    for (int j = 0; j < 4; j++){
      const int row = row0 + lk*4 + j;
      if (row < N)
        agg1[(size_t)row*256 + col] = fmaxf(acc[ct][j] + bv, 0.f);
    }
  }
}

// ---------------- layer-2 GEMM (MFMA) + logits + transposed fp16 store ------
__global__ __launch_bounds__(256) void k_gemm2_mfma(
    const float* __restrict__ agg1,     // [N,256] f32
    const _Float16* __restrict__ W2t,   // [256,256] (Wt[c][k])
    const float* __restrict__ att_s, const float* __restrict__ att_d,
    __half* __restrict__ h2t,           // [N,64,4] halves
    float* __restrict__ asrc, float* __restrict__ adst, int N)
{
  const int w = threadIdx.x >> 6, l = threadIdx.x & 63;
  const int lr = l & 15, lk = l >> 4;
  const int row0 = blockIdx.x*64 + w*16;
  const int rowa = min(row0 + lr, N-1);
  v4f acc[16] = {};
  for (int ks = 0; ks < 8; ks++){
    const int k = ks*32 + lk*8;
    const float4 a0 = *(const float4*)(agg1 + (size_t)rowa*256 + k);
    const float4 a1 = *(const float4*)(agg1 + (size_t)rowa*256 + k + 4);
    v8h a;
    a[0]=(_Float16)a0.x; a[1]=(_Float16)a0.y; a[2]=(_Float16)a0.z; a[3]=(_Float16)a0.w;
    a[4]=(_Float16)a1.x; a[5]=(_Float16)a1.y; a[6]=(_Float16)a1.z; a[7]=(_Float16)a1.w;
    #pragma unroll
    for (int ct = 0; ct < 16; ct++){
      const int col = ct*16 + lr;
      const v8h b = *(const v8h*)(W2t + (size_t)col*256 + k);
      acc[ct] = __builtin_amdgcn_mfma_f32_16x16x32_f16(a, b, acc[ct], 0,0,0);
    }
  }
  float AS[16], AD[16];
  #pragma unroll
  for (int ct = 0; ct < 16; ct++){
    const int h = ct >> 2, idx = (ct & 3)*16 + lr;
    AS[ct] = att_s[h*64 + idx];
    AD[ct] = att_d[h*64 + idx];
  }
  #pragma unroll
  for (int j = 0; j < 4; j++){
    const int row = row0 + lk*4 + j;
    const bool ok = row < N;
    float vs[4] = {0.f,0.f,0.f,0.f}, vd[4] = {0.f,0.f,0.f,0.f};
    #pragma unroll
    for (int ct = 0; ct < 16; ct++){
      const float v = acc[ct][j];
      const int col = ct*16 + lr;
      if (ok)
        h2t[(size_t)row*256 + (col & 63)*4 + (col >> 6)] = __float2half(v);
      vs[ct>>2] += v * AS[ct];
      vd[ct>>2] += v * AD[ct];
    }
    #pragma unroll
    for (int h = 0; h < 4; h++){
      float s = vs[h], d = vd[h];
      #pragma unroll
      for (int off = 1; off < 16; off <<= 1){
        s += __shfl_xor(s, off, 16);
        d += __shfl_xor(d, off, 16);
      }
      if (lr == 0 && ok){
        asrc[(size_t)row*4 + h] = s;
        adst[(size_t)row*4 + h] = d;
      }
    }
  }
}

// ---------------- layer-2 aggregation: inline weights + 4x unrolled ---------
__global__ __launch_bounds__(256) void k_node_agg2(
    const int* __restrict__ rowptr, const int* __restrict__ csr,
    const float* __restrict__ asrc, const float* __restrict__ adst,
    const __half* __restrict__ h2t, const float* __restrict__ bias,
    float* __restrict__ outp, int N)
{
  const int n = blockIdx.x*4 + (threadIdx.x >> 6);
  const int l = threadIdx.x & 63;              // output channel
  if (n >= N) return;
  const int start = rowptr[n];
  const int deg = rowptr[n+1] - start;
  const float4 ad = *(const float4*)(adst + (size_t)n*4);

  float a0=0.f, a1=0.f, a2=0.f, a3=0.f;
  float4 ds = make_float4(0.f,0.f,0.f,0.f);
  int j = 0;
  for (; j + 4 <= deg; j += 4){
    const int p0 = start + j;
    const int s0 = csr[p0+0], s1 = csr[p0+1], s2 = csr[p0+2], s3 = csr[p0+3];
    const float4 q0 = *(const float4*)(asrc + (size_t)s0*4);   // L2 hit
    const float4 q1 = *(const float4*)(asrc + (size_t)s1*4);
    const float4 q2 = *(const float4*)(asrc + (size_t)s2*4);
    const float4 q3 = *(const float4*)(asrc + (size_t)s3*4);
    const uint2 u0 = *(const uint2*)(h2t + (size_t)s0*256 + l*4);
    const uint2 u1 = *(const uint2*)(h2t + (size_t)s1*256 + l*4);
    const uint2 u2 = *(const uint2*)(h2t + (size_t)s2*256 + l*4);
    const uint2 u3 = *(const uint2*)(h2t + (size_t)s3*256 + l*4);
    float4 w0, w1, w2, w3;
    w0.x = __expf(lrelu(q0.x+ad.x)); w0.y = __expf(lrelu(q0.y+ad.y));
    w0.z = __expf(lrelu(q0.z+ad.z)); w0.w = __expf(lrelu(q0.w+ad.w));
    w1.x = __expf(lrelu(q1.x+ad.x)); w1.y = __expf(lrelu(q1.y+ad.y));
    w1.z = __expf(lrelu(q1.z+ad.z)); w1.w = __expf(lrelu(q1.w+ad.w));
    w2.x = __expf(lrelu(q2.x+ad.x)); w2.y = __expf(lrelu(q2.y+ad.y));
    w2.z = __expf(lrelu(q2.z+ad.z)); w2.w = __expf(lrelu(q2.w+ad.w));
    w3.x = __expf(lrelu(q3.x+ad.x)); w3.y = __expf(lrelu(q3.y+ad.y));
    w3.z = __expf(lrelu(q3.z+ad.z)); w3.w = __expf(lrelu(q3.w+ad.w));
    const float2 g0 = __half22float2(*reinterpret_cast<const __half2*>(&u0.x));
    const float2 g1 = __half22float2(*reinterpret_cast<const __half2*>(&u0.y));
    const float2 h0 = __half22float2(*reinterpret_cast<const __half2*>(&u1.x));
    const float2 h1 = __half22float2(*reinterpret_cast<const __half2*>(&u1.y));
    const float2 i0 = __half22float2(*reinterpret_cast<const __half2*>(&u2.x));
    const float2 i1 = __half22float2(*reinterpret_cast<const __half2*>(&u2.y));
    const float2 k0 = __half22float2(*reinterpret_cast<const __half2*>(&u3.x));
    const float2 k1 = __half22float2(*reinterpret_cast<const __half2*>(&u3.y));
    a0 += w0.x*g0.x + w1.x*h0.x + w2.x*i0.x + w3.x*k0.x;
    a1 += w0.y*g0.y + w1.y*h0.y + w2.y*i0.y + w3.y*k0.y;
    a2 += w0.z*g1.x + w1.z*h1.x + w2.z*i1.x + w3.z*k1.x;
    a3 += w0.w*g1.y + w1.w*h1.y + w2.w*i1.y + w3.w*k1.y;
    ds.x += w0.x+w1.x+w2.x+w3.x;
    ds.y += w0.y+w1.y+w2.y+w3.y;
    ds.z += w0.z+w1.z+w2.z+w3.z;
    ds.w += w0.w+w1.w+w2.w+w3.w;
  }
  for (; j < deg; j++){
    const int s = csr[start + j];
    const float4 q = *(const float4*)(asrc + (size_t)s*4);
    const uint2 u = *(const uint2*)(h2t + (size_t)s*256 + l*4);
    float4 w4;
    w4.x = __expf(lrelu(q.x+ad.x)); w4.y = __expf(lrelu(q.y+ad.y));
    w4.z = __expf(lrelu(q.z+ad.z)); w4.w = __expf(lrelu(q.w+ad.w));
    const float2 f01 = __half22float2(*reinterpret_cast<const __half2*>(&u.x));
    const float2 f23 = __half22float2(*reinterpret_cast<const __half2*>(&u.y));
    a0 += w4.x*f01.x; a1 += w4.y*f01.y; a2 += w4.z*f23.x; a3 += w4.w*f23.y;
    ds.x += w4.x; ds.y += w4.y; ds.z += w4.z; ds.w += w4.w;
  }
  const float val = 0.25f*(a0/ds.x + a1/ds.y + a2/ds.z + a3/ds.w) + bias[l];
  outp[(size_t)n*64 + l] = fmaxf(val, 0.f);
}

// ---------------- FF head: agg2 -> relu(@ff1) -> @ff2 -------
__global__ __launch_bounds__(256) void k_ff(
    const float* __restrict__ agg2,
    const float* __restrict__ w1, const float* __restrict__ b1,
    const float* __restrict__ w2, const float* __restrict__ b2f,
    float* __restrict__ out, int N)
{
  __shared__ float W1s[64*32];
  __shared__ float B1s[32];
  __shared__ float W2s[64];
  __shared__ float B2s[2];
  const int t = threadIdx.x;
  for (int i=t; i<64*32; i+=256) W1s[i] = w1[i];
  if (t < 32) B1s[t] = b1[t];
  if (t < 64) W2s[t] = w2[t];
  if (t < 2)  B2s[t] = b2f[t];
  __syncthreads();

  const int n = blockIdx.x*256 + t;
  if (n >= N) return;

  float t1[32];
  #pragma unroll
  for (int j=0;j<32;j++) t1[j] = B1s[j];
  #pragma unroll
  for (int c=0;c<64;c++){
    const float fc = agg2[(long)n*64 + c];
    #pragma unroll
    for (int j=0;j<32;j++) t1[j] += fc * W1s[c*32 + j];
  }
  float o0 = B2s[0], o1 = B2s[1];
  #pragma unroll
  for (int j=0;j<32;j++){
    const float v = t1[j] > 0.f ? t1[j] : 0.f;
    o0 += v * W2s[j*2 + 0];
    o1 += v * W2s[j*2 + 1];
  }
  out[(long)n*2 + 0] = o0;
  out[(long)n*2 + 1] = o1;
}

extern "C" void kernel_launch(void* const* d_in, const int* in_sizes, int n_in,
                              void* d_out, int out_size, void* d_ws, size_t ws_size,
                              hipStream_t stream)
{
  const float* x      = (const float*)d_in[0];
  const int*   ei     = (const int*)  d_in[1];
  const float* W1     = (const float*)d_in[3];
  const float* att_s1 = (const float*)d_in[4];
  const float* att_d1 = (const float*)d_in[5];
  const float* b1     = (const float*)d_in[6];
  const float* W2     = (const float*)d_in[7];
  const float* att_s2 = (const float*)d_in[8];
  const float* att_d2 = (const float*)d_in[9];
  const float* b2     = (const float*)d_in[10];
  const float* ff1w   = (const float*)d_in[11];
  const float* ff1b   = (const float*)d_in[12];
  const float* ff2w   = (const float*)d_in[13];
  const float* ff2b   = (const float*)d_in[14];
  float* out = (float*)d_out;

  const int N = in_sizes[0] / 128;
  const int E = in_sizes[1] / 2;
  const int tot = E + N;

  // ---- workspace (R0 time-shared: aggX layer-1; h2t+agg2 layer-2) ----
  char* p = (char*)d_ws;
  __half* aggX = (__half*)p;                         // [N,512] fp16 (layer-1)
  __half* h2t  = (__half*)p;                         // [N,256] fp16 (layer-2)
  float*  agg2 = (float*)(p + (size_t)N*256*2);      // [N,64]  f32  (layer-2)
  p += (size_t)N*256*4 + (size_t)N*64*4;             // region >= all phases
  float* agg1 = (float*)p;                           // [N,256] f32
  __half* xh  = (__half*)p;                          // [N,128] fp16, aliased:
  p += (size_t)N*256*4;                              //   dead before agg1 write
  float* asrc = (float*)p;  p += (size_t)N*4*4;      // [N,4]
  float* adst = (float*)p;  p += (size_t)N*4*4;      // [N,4]
  float* Ps   = (float*)p;  p += 512*4;              // [128,4]
  float* Pd   = (float*)p;  p += 512*4;              // [128,4]
  _Float16* W1t = (_Float16*)p; p += 256*128*2;      // [256,128] fp16
  _Float16* W2t = (_Float16*)p; p += 256*256*2;      // [256,256] fp16
  int* deg    = (int*)p;    p += (size_t)N*4;
  int* rowptr = (int*)p;    p += (size_t)(N+1)*4;
  int* cursor = (int*)p;    p += (size_t)N*4;
  int* bsum   = (int*)p;    p += SB*4;
  int* csr    = (int*)p;    p += (size_t)tot*4;

  const int gE  = (tot + 255) / 256;
  const int gN4 = (N + 3) / 4;
  const int g64 = (N + 63) / 64;

  // ---- CSR build (shared by both layers) ----
  k_zero <<<(N+255)/256,256,0,stream>>>(deg, N);
  k_count<<<gE,256,0,stream>>>(ei, E, N, deg);
  k_scan1<<<SB,256,0,stream>>>(deg, bsum, N);
  k_scan2<<<1,256,0,stream>>>(bsum);
  k_scan3<<<SB,256,0,stream>>>(deg, bsum, rowptr, cursor, N);
  k_fill <<<gE,256,0,stream>>>(ei, E, N, cursor, csr);

  // ---- weight prep (fp16 transposed copies) ----
  k_cvt_wt<<<128,256,0,stream>>>(W1, W1t, 128, 256);
  k_cvt_wt<<<256,256,0,stream>>>(W2, W2t, 256, 256);

  // ---- layer 1: aggregate-then-transform ----
  k_cvt_x<<<1024,256,0,stream>>>(x, xh, (long)N*64);
  k_prep<<<1,256,0,stream>>>(W1, att_s1, att_d1, Ps, Pd);
  k_att1<<<g64,256,0,stream>>>(x, Ps, Pd, asrc, adst, N);
  k_agg_x<<<gN4,256,0,stream>>>(rowptr, csr, asrc, adst, xh, (__half*)aggX, N);
  k_gemm1_mfma<<<g64,256,0,stream>>>((const _Float16*)aggX, W1t, b1, agg1, N);

  // ---- layer 2 (head mean; MFMA GEMM + fp16 transposed gather payload) ----
  k_gemm2_mfma<<<g64,256,0,stream>>>(agg1, W2t, att_s2, att_d2, h2t, asrc, adst, N);
  k_node_agg2<<<gN4,256,0,stream>>>(rowptr, csr, asrc, adst, h2t, b2, agg2, N);

  // ---- feed-forward head ----
  k_ff<<<(N+255)/256,256,0,stream>>>(agg2, ff1w, ff1b, ff2w, ff2b, out, N);
}

// Round 12
// 407.087 us; speedup vs baseline: 1.5581x; 1.0516x over previous
//
#include <hip/hip_runtime.h>
#include <hip/hip_fp16.h>

typedef _Float16 v8h __attribute__((ext_vector_type(8)));
typedef float    v4f __attribute__((ext_vector_type(4)));

__device__ __forceinline__ float lrelu(float x){ return x >= 0.f ? x : 0.2f*x; }

#define SB 256  // scan blocks

// ---------------- zero degree counters ----------------
__global__ __launch_bounds__(256) void k_zero(int* __restrict__ p, int n)
{
  int i = blockIdx.x*256 + threadIdx.x;
  if (i < n) p[i] = 0;
}

// ---------------- count in-degree per destination ----------------
__global__ __launch_bounds__(256) void k_count(const int* __restrict__ ei,
                                               int E, int N, int* __restrict__ deg)
{
  const int e = blockIdx.x*256 + threadIdx.x;
  if (e >= E + N) return;
  const int d = (e < E) ? ei[E + e] : (e - E);
  atomicAdd(&deg[d], 1);
}

// ---------------- parallel scan phase 1: per-block chunk sums ----------------
__global__ __launch_bounds__(256) void k_scan1(const int* __restrict__ deg,
                                               int* __restrict__ bsum, int N)
{
  __shared__ int sh[256];
  const int chunk = (N + SB - 1) / SB;
  const int lo = blockIdx.x * chunk;
  const int hi = min(lo + chunk, N);
  int s = 0;
  for (int i = lo + threadIdx.x; i < hi; i += 256) s += deg[i];
  sh[threadIdx.x] = s;
  __syncthreads();
  #pragma unroll
  for (int off = 128; off; off >>= 1){
    if (threadIdx.x < off) sh[threadIdx.x] += sh[threadIdx.x + off];
    __syncthreads();
  }
  if (threadIdx.x == 0) bsum[blockIdx.x] = sh[0];
}

// ---------------- parallel scan phase 2: exclusive scan of 256 partials -----
__global__ __launch_bounds__(256) void k_scan2(int* __restrict__ bsum)
{
  __shared__ int sh[256];
  const int v = bsum[threadIdx.x];
  sh[threadIdx.x] = v;
  __syncthreads();
  for (int off = 1; off < 256; off <<= 1){
    int t = 0;
    if (threadIdx.x >= off) t = sh[threadIdx.x - off];
    __syncthreads();
    sh[threadIdx.x] += t;
    __syncthreads();
  }
  bsum[threadIdx.x] = sh[threadIdx.x] - v;  // exclusive
}

// ---------------- parallel scan phase 3: chunk-local scan + base -------------
__global__ __launch_bounds__(256) void k_scan3(const int* __restrict__ deg,
                                               const int* __restrict__ bsum,
                                               int* __restrict__ rowptr,
                                               int* __restrict__ cursor, int N)
{
  __shared__ int sh[256];
  const int chunk = (N + SB - 1) / SB;
  const int lo = blockIdx.x * chunk;
  const int hi = min(lo + chunk, N);
  int base = bsum[blockIdx.x];
  for (int start = lo; start < hi; start += 256){
    const int i = start + threadIdx.x;
    const int v = (i < hi) ? deg[i] : 0;
    sh[threadIdx.x] = v;
    __syncthreads();
    for (int off = 1; off < 256; off <<= 1){
      int t = 0;
      if (threadIdx.x >= off) t = sh[threadIdx.x - off];
      __syncthreads();
      sh[threadIdx.x] += t;
      __syncthreads();
    }
    if (i < hi){
      const int excl = base + sh[threadIdx.x] - v;
      rowptr[i] = excl;
      cursor[i] = excl;
    }
    base += sh[255];
    __syncthreads();
  }
  if (blockIdx.x == SB-1 && threadIdx.x == 0) rowptr[N] = base;
}

// ---------------- fill CSR src lists ----------------
__global__ __launch_bounds__(256) void k_fill(const int* __restrict__ ei,
                                              int E, int N, int* __restrict__ cursor,
                                              int* __restrict__ csr)
{
  const int e = blockIdx.x*256 + threadIdx.x;
  if (e >= E + N) return;
  int s, d;
  if (e < E){ s = ei[e]; d = ei[E + e]; } else { s = d = e - E; }
  const int pos = atomicAdd(&cursor[d], 1);
  csr[pos] = s;
}

// ---------------- x -> fp16 copy (gather payload shrink) ----------------
__global__ __launch_bounds__(256) void k_cvt_x(const float* __restrict__ x,
                                               __half* __restrict__ xh, long n2)
{
  long i  = (long)blockIdx.x*256 + threadIdx.x;
  long st = (long)gridDim.x*256;
  for (; i < n2; i += st){
    const float2 v = *(const float2*)(x + 2*i);
    *(__half2*)(xh + 2*i) = __floats2half2_rn(v.x, v.y);
  }
}

// ---------------- W [K,C] f32 -> Wt [C,K] fp16 (transpose + convert) --------
__global__ __launch_bounds__(256) void k_cvt_wt(const float* __restrict__ W,
                                                _Float16* __restrict__ Wt,
                                                int K, int C)
{
  const int idx = blockIdx.x*256 + threadIdx.x;
  if (idx >= K*C) return;
  const int c = idx / K, k = idx % K;     // writes coalesced along k
  Wt[(size_t)c*K + k] = (_Float16)W[(size_t)k*C + c];
}

// ---------------- Ps/Pd = per-head W1 @ att vectors: [128,4] ----------------
__global__ __launch_bounds__(256) void k_prep(
    const float* __restrict__ W1, const float* __restrict__ as1,
    const float* __restrict__ ad1, float* __restrict__ Ps, float* __restrict__ Pd)
{
  const int t = threadIdx.x;
  for (int idx = t; idx < 512; idx += 256){
    const int k = idx >> 2, h = idx & 3;
    float ss = 0.f, dd = 0.f;
    for (int c = 0; c < 64; c++){
      const float wv = W1[k*256 + h*64 + c];
      ss += wv * as1[h*64 + c];
      dd += wv * ad1[h*64 + c];
    }
    Ps[k*4 + h] = ss;
    Pd[k*4 + h] = dd;
  }
}

// ---------------- layer-1 logits: asrc/adst = x @ Ps/Pd  [N,4] --------------
__global__ __launch_bounds__(256) void k_att1(
    const float* __restrict__ x, const float* __restrict__ Ps,
    const float* __restrict__ Pd, float* __restrict__ asrc,
    float* __restrict__ adst, int N)
{
  __shared__ float PsL[512], PdL[512];
  __shared__ float red[4][64][8];
  const int t = threadIdx.x;
  PsL[t] = Ps[t]; PsL[t+256] = Ps[t+256];
  PdL[t] = Pd[t]; PdL[t+256] = Pd[t+256];
  __syncthreads();
  const int r = t & 63, g = t >> 6;
  const int row = blockIdx.x*64 + r;
  const int rg = min(row, N-1);
  const float* xr = x + (size_t)rg*128;
  float4 pa = make_float4(0.f,0.f,0.f,0.f);
  float4 pb = make_float4(0.f,0.f,0.f,0.f);
  for (int kk = g*32; kk < g*32 + 32; kk++){
    const float xv = xr[kk];
    const float4 s4 = *(const float4*)(PsL + kk*4);
    const float4 d4 = *(const float4*)(PdL + kk*4);
    pa.x += xv*s4.x; pa.y += xv*s4.y; pa.z += xv*s4.z; pa.w += xv*s4.w;
    pb.x += xv*d4.x; pb.y += xv*d4.y; pb.z += xv*d4.z; pb.w += xv*d4.w;
  }
  *(float4*)(&red[g][r][0]) = pa;
  *(float4*)(&red[g][r][4]) = pb;
  __syncthreads();
  if (t < 64 && blockIdx.x*64 + t < N){
    float4 sa = make_float4(0.f,0.f,0.f,0.f);
    float4 sb = make_float4(0.f,0.f,0.f,0.f);
    #pragma unroll
    for (int gg = 0; gg < 4; gg++){
      const float4 qa = *(const float4*)(&red[gg][t][0]);
      const float4 qb = *(const float4*)(&red[gg][t][4]);
      sa.x += qa.x; sa.y += qa.y; sa.z += qa.z; sa.w += qa.w;
      sb.x += qb.x; sb.y += qb.y; sb.z += qb.z; sb.w += qb.w;
    }
    *(float4*)(asrc + (size_t)(blockIdx.x*64 + t)*4) = sa;
    *(float4*)(adst + (size_t)(blockIdx.x*64 + t)*4) = sb;
  }
}

// ---------------- layer-1 aggregate: inline weights + 4x unrolled gather ----
__global__ __launch_bounds__(256) void k_agg_x(
    const int* __restrict__ rowptr, const int* __restrict__ csr,
    const float* __restrict__ asrc, const float* __restrict__ adst,
    const __half* __restrict__ xh,
    __half* __restrict__ aggX, int N)
{
  const int n = blockIdx.x*4 + (threadIdx.x >> 6);
  const int l = threadIdx.x & 63;
  if (n >= N) return;
  const int start = rowptr[n];
  const int deg = rowptr[n+1] - start;
  const float4 ad = *(const float4*)(adst + (size_t)n*4);

  float a0x=0.f,a0y=0.f, a1x=0.f,a1y=0.f, a2x=0.f,a2y=0.f, a3x=0.f,a3y=0.f;
  float4 ds = make_float4(0.f,0.f,0.f,0.f);
  int j = 0;
  for (; j + 4 <= deg; j += 4){
    const int p0 = start + j;
    const int s0 = csr[p0+0], s1 = csr[p0+1], s2 = csr[p0+2], s3 = csr[p0+3];
    const float4 q0 = *(const float4*)(asrc + (size_t)s0*4);   // L2 hit
    const float4 q1 = *(const float4*)(asrc + (size_t)s1*4);
    const float4 q2 = *(const float4*)(asrc + (size_t)s2*4);
    const float4 q3 = *(const float4*)(asrc + (size_t)s3*4);
    const __half2 v0 = *(const __half2*)(xh + (size_t)s0*128 + 2*l);
    const __half2 v1 = *(const __half2*)(xh + (size_t)s1*128 + 2*l);
    const __half2 v2 = *(const __half2*)(xh + (size_t)s2*128 + 2*l);
    const __half2 v3 = *(const __half2*)(xh + (size_t)s3*128 + 2*l);
    float4 w0, w1, w2, w3;
    w0.x = __expf(lrelu(q0.x+ad.x)); w0.y = __expf(lrelu(q0.y+ad.y));
    w0.z = __expf(lrelu(q0.z+ad.z)); w0.w = __expf(lrelu(q0.w+ad.w));
    w1.x = __expf(lrelu(q1.x+ad.x)); w1.y = __expf(lrelu(q1.y+ad.y));
    w1.z = __expf(lrelu(q1.z+ad.z)); w1.w = __expf(lrelu(q1.w+ad.w));
    w2.x = __expf(lrelu(q2.x+ad.x)); w2.y = __expf(lrelu(q2.y+ad.y));
    w2.z = __expf(lrelu(q2.z+ad.z)); w2.w = __expf(lrelu(q2.w+ad.w));
    w3.x = __expf(lrelu(q3.x+ad.x)); w3.y = __expf(lrelu(q3.y+ad.y));
    w3.z = __expf(lrelu(q3.z+ad.z)); w3.w = __expf(lrelu(q3.w+ad.w));
    const float2 f0 = __half22float2(v0);
    const float2 f1 = __half22float2(v1);
    const float2 f2 = __half22float2(v2);
    const float2 f3 = __half22float2(v3);
    a0x += w0.x*f0.x + w1.x*f1.x + w2.x*f2.x + w3.x*f3.x;
    a0y += w0.x*f0.y + w1.x*f1.y + w2.x*f2.y + w3.x*f3.y;
    a1x += w0.y*f0.x + w1.y*f1.x + w2.y*f2.x + w3.y*f3.x;
    a1y += w0.y*f0.y + w1.y*f1.y + w2.y*f2.y + w3.y*f3.y;
    a2x += w0.z*f0.x + w1.z*f1.x + w2.z*f2.x + w3.z*f3.x;
    a2y += w0.z*f0.y + w1.z*f1.y + w2.z*f2.y + w3.z*f3.y;
    a3x += w0.w*f0.x + w1.w*f1.x + w2.w*f2.x + w3.w*f3.x;
    a3y += w0.w*f0.y + w1.w*f1.y + w2.w*f2.y + w3.w*f3.y;
    ds.x += w0.x+w1.x+w2.x+w3.x;
    ds.y += w0.y+w1.y+w2.y+w3.y;
    ds.z += w0.z+w1.z+w2.z+w3.z;
    ds.w += w0.w+w1.w+w2.w+w3.w;
  }
  for (; j < deg; j++){
    const int s = csr[start + j];
    const float4 q = *(const float4*)(asrc + (size_t)s*4);
    const float2 f = __half22float2(*(const __half2*)(xh + (size_t)s*128 + 2*l));
    float4 w4;
    w4.x = __expf(lrelu(q.x+ad.x)); w4.y = __expf(lrelu(q.y+ad.y));
    w4.z = __expf(lrelu(q.z+ad.z)); w4.w = __expf(lrelu(q.w+ad.w));
    a0x += w4.x*f.x; a0y += w4.x*f.y;
    a1x += w4.y*f.x; a1y += w4.y*f.y;
    a2x += w4.z*f.x; a2y += w4.z*f.y;
    a3x += w4.w*f.x; a3y += w4.w*f.y;
    ds.x += w4.x; ds.y += w4.y; ds.z += w4.z; ds.w += w4.w;
  }
  const float i0 = 1.f/ds.x, i1 = 1.f/ds.y, i2 = 1.f/ds.z, i3 = 1.f/ds.w;
  __half* base = aggX + (size_t)n*512 + 2*l;
  *(__half2*)(base +   0) = __floats2half2_rn(a0x*i0, a0y*i0);
  *(__half2*)(base + 128) = __floats2half2_rn(a1x*i1, a1y*i1);
  *(__half2*)(base + 256) = __floats2half2_rn(a2x*i2, a2y*i2);
  *(__half2*)(base + 384) = __floats2half2_rn(a3x*i3, a3y*i3);
}

// ---------------- layer-1 post-GEMM (MFMA, block-diag, col-split x2) --------
// block (rb,cb): rows rb*64..+64, cols cb*128..+128 (heads 2cb, 2cb+1).
__global__ __launch_bounds__(256) void k_gemm1_mfma(
    const _Float16* __restrict__ aggX,  // [N,4,128]
    const _Float16* __restrict__ W1t,   // [256,128]  (Wt[c][k])
    const float* __restrict__ bias,     // [256]
    float* __restrict__ agg1, int N)
{
  const int w = threadIdx.x >> 6, l = threadIdx.x & 63;
  const int lr = l & 15, lk = l >> 4;
  const int rb = blockIdx.x >> 1, cb = blockIdx.x & 1;
  const int row0 = rb*64 + w*16;
  const int rowa = min(row0 + lr, N-1);
  v4f acc[8] = {};
  for (int ks = 0; ks < 4; ks++){
    const int k = ks*32 + lk*8;
    const v8h a0 = *(const v8h*)(aggX + (size_t)rowa*512 + (2*cb  )*128 + k);
    const v8h a1 = *(const v8h*)(aggX + (size_t)rowa*512 + (2*cb+1)*128 + k);
    #pragma unroll
    for (int ct = 0; ct < 8; ct++){
      const int col = cb*128 + ct*16 + lr;
      const v8h b = *(const v8h*)(W1t + (size_t)col*128 + k);
      acc[ct] = __builtin_amdgcn_mfma_f32_16x16x32_f16(ct < 4 ? a0 : a1, b, acc[ct], 0,0,0);
    }
  }
  #pragma unroll
  for (int ct = 0; ct < 8; ct++){
    const int col = cb*128 + ct*16 + lr;
    const float bv = bias[col];
    #pragma unroll
    for (int j = 0; j < 4; j++){
      const int row = row0 + lk*4 + j;
      if (row < N)
        agg1[(size_t)row*256 + col] = fmaxf(acc[ct][j] + bv, 0.f);
    }
  }
}

// ---------------- layer-2 GEMM (MFMA, col-split x2) + logits + h2t store ----
__global__ __launch_bounds__(256) void k_gemm2_mfma(
    const float* __restrict__ agg1,     // [N,256] f32
    const _Float16* __restrict__ W2t,   // [256,256] (Wt[c][k])
    const float* __restrict__ att_s, const float* __restrict__ att_d,
    __half* __restrict__ h2t,           // [N,64,4] halves
    float* __restrict__ asrc, float* __restrict__ adst, int N)
{
  const int w = threadIdx.x >> 6, l = threadIdx.x & 63;
  const int lr = l & 15, lk = l >> 4;
  const int rb = blockIdx.x >> 1, cb = blockIdx.x & 1;
  const int row0 = rb*64 + w*16;
  const int rowa = min(row0 + lr, N-1);
  v4f acc[8] = {};
  for (int ks = 0; ks < 8; ks++){
    const int k = ks*32 + lk*8;
    const float4 a0 = *(const float4*)(agg1 + (size_t)rowa*256 + k);
    const float4 a1 = *(const float4*)(agg1 + (size_t)rowa*256 + k + 4);
    v8h a;
    a[0]=(_Float16)a0.x; a[1]=(_Float16)a0.y; a[2]=(_Float16)a0.z; a[3]=(_Float16)a0.w;
    a[4]=(_Float16)a1.x; a[5]=(_Float16)a1.y; a[6]=(_Float16)a1.z; a[7]=(_Float16)a1.w;
    #pragma unroll
    for (int ct = 0; ct < 8; ct++){
      const int col = cb*128 + ct*16 + lr;
      const v8h b = *(const v8h*)(W2t + (size_t)col*256 + k);
      acc[ct] = __builtin_amdgcn_mfma_f32_16x16x32_f16(a, b, acc[ct], 0,0,0);
    }
  }
  // per-lane attention coefficients: head = 2cb + (ct>>2), ch = (ct&3)*16+lr
  float AS[8], AD[8];
  #pragma unroll
  for (int ct = 0; ct < 8; ct++){
    const int h = 2*cb + (ct >> 2), idx = (ct & 3)*16 + lr;
    AS[ct] = att_s[h*64 + idx];
    AD[ct] = att_d[h*64 + idx];
  }
  #pragma unroll
  for (int j = 0; j < 4; j++){
    const int row = row0 + lk*4 + j;
    const bool ok = row < N;
    float vs0=0.f, vd0=0.f, vs1=0.f, vd1=0.f;
    #pragma unroll
    for (int ct = 0; ct < 8; ct++){
      const float v = acc[ct][j];
      if (ct < 4){ vs0 += v*AS[ct]; vd0 += v*AD[ct]; }
      else       { vs1 += v*AS[ct]; vd1 += v*AD[ct]; }
    }
    if (ok){
      // batched store: heads (2cb, 2cb+1) for channel ch -> one 4B __half2
      #pragma unroll
      for (int ctm = 0; ctm < 4; ctm++){
        const int ch = ctm*16 + lr;
        *(__half2*)(h2t + (size_t)row*256 + ch*4 + 2*cb) =
            __floats2half2_rn(acc[ctm][j], acc[ctm+4][j]);
      }
    }
    #pragma unroll
    for (int off = 1; off < 16; off <<= 1){
      vs0 += __shfl_xor(vs0, off, 16);
      vd0 += __shfl_xor(vd0, off, 16);
      vs1 += __shfl_xor(vs1, off, 16);
      vd1 += __shfl_xor(vd1, off, 16);
    }
    if (lr == 0 && ok){
      asrc[(size_t)row*4 + 2*cb    ] = vs0;
      adst[(size_t)row*4 + 2*cb    ] = vd0;
      asrc[(size_t)row*4 + 2*cb + 1] = vs1;
      adst[(size_t)row*4 + 2*cb + 1] = vd1;
    }
  }
}

// ---------------- layer-2 aggregation: inline weights + 4x unrolled ---------
__global__ __launch_bounds__(256) void k_node_agg2(
    const int* __restrict__ rowptr, const int* __restrict__ csr,
    const float* __restrict__ asrc, const float* __restrict__ adst,
    const __half* __restrict__ h2t, const float* __restrict__ bias,
    float* __restrict__ outp, int N)
{
  const int n = blockIdx.x*4 + (threadIdx.x >> 6);
  const int l = threadIdx.x & 63;              // output channel
  if (n >= N) return;
  const int start = rowptr[n];
  const int deg = rowptr[n+1] - start;
  const float4 ad = *(const float4*)(adst + (size_t)n*4);

  float a0=0.f, a1=0.f, a2=0.f, a3=0.f;
  float4 ds = make_float4(0.f,0.f,0.f,0.f);
  int j = 0;
  for (; j + 4 <= deg; j += 4){
    const int p0 = start + j;
    const int s0 = csr[p0+0], s1 = csr[p0+1], s2 = csr[p0+2], s3 = csr[p0+3];
    const float4 q0 = *(const float4*)(asrc + (size_t)s0*4);   // L2 hit
    const float4 q1 = *(const float4*)(asrc + (size_t)s1*4);
    const float4 q2 = *(const float4*)(asrc + (size_t)s2*4);
    const float4 q3 = *(const float4*)(asrc + (size_t)s3*4);
    const uint2 u0 = *(const uint2*)(h2t + (size_t)s0*256 + l*4);
    const uint2 u1 = *(const uint2*)(h2t + (size_t)s1*256 + l*4);
    const uint2 u2 = *(const uint2*)(h2t + (size_t)s2*256 + l*4);
    const uint2 u3 = *(const uint2*)(h2t + (size_t)s3*256 + l*4);
    float4 w0, w1, w2, w3;
    w0.x = __expf(lrelu(q0.x+ad.x)); w0.y = __expf(lrelu(q0.y+ad.y));
    w0.z = __expf(lrelu(q0.z+ad.z)); w0.w = __expf(lrelu(q0.w+ad.w));
    w1.x = __expf(lrelu(q1.x+ad.x)); w1.y = __expf(lrelu(q1.y+ad.y));
    w1.z = __expf(lrelu(q1.z+ad.z)); w1.w = __expf(lrelu(q1.w+ad.w));
    w2.x = __expf(lrelu(q2.x+ad.x)); w2.y = __expf(lrelu(q2.y+ad.y));
    w2.z = __expf(lrelu(q2.z+ad.z)); w2.w = __expf(lrelu(q2.w+ad.w));
    w3.x = __expf(lrelu(q3.x+ad.x)); w3.y = __expf(lrelu(q3.y+ad.y));
    w3.z = __expf(lrelu(q3.z+ad.z)); w3.w = __expf(lrelu(q3.w+ad.w));
    const float2 g0 = __half22float2(*reinterpret_cast<const __half2*>(&u0.x));
    const float2 g1 = __half22float2(*reinterpret_cast<const __half2*>(&u0.y));
    const float2 h0 = __half22float2(*reinterpret_cast<const __half2*>(&u1.x));
    const float2 h1 = __half22float2(*reinterpret_cast<const __half2*>(&u1.y));
    const float2 i0 = __half22float2(*reinterpret_cast<const __half2*>(&u2.x));
    const float2 i1 = __half22float2(*reinterpret_cast<const __half2*>(&u2.y));
    const float2 k0 = __half22float2(*reinterpret_cast<const __half2*>(&u3.x));
    const float2 k1 = __half22float2(*reinterpret_cast<const __half2*>(&u3.y));
    a0 += w0.x*g0.x + w1.x*h0.x + w2.x*i0.x + w3.x*k0.x;
    a1 += w0.y*g0.y + w1.y*h0.y + w2.y*i0.y + w3.y*k0.y;
    a2 += w0.z*g1.x + w1.z*h1.x + w2.z*i1.x + w3.z*k1.x;
    a3 += w0.w*g1.y + w1.w*h1.y + w2.w*i1.y + w3.w*k1.y;
    ds.x += w0.x+w1.x+w2.x+w3.x;
    ds.y += w0.y+w1.y+w2.y+w3.y;
    ds.z += w0.z+w1.z+w2.z+w3.z;
    ds.w += w0.w+w1.w+w2.w+w3.w;
  }
  for (; j < deg; j++){
    const int s = csr[start + j];
    const float4 q = *(const float4*)(asrc + (size_t)s*4);
    const uint2 u = *(const uint2*)(h2t + (size_t)s*256 + l*4);
    float4 w4;
    w4.x = __expf(lrelu(q.x+ad.x)); w4.y = __expf(lrelu(q.y+ad.y));
    w4.z = __expf(lrelu(q.z+ad.z)); w4.w = __expf(lrelu(q.w+ad.w));
    const float2 f01 = __half22float2(*reinterpret_cast<const __half2*>(&u.x));
    const float2 f23 = __half22float2(*reinterpret_cast<const __half2*>(&u.y));
    a0 += w4.x*f01.x; a1 += w4.y*f01.y; a2 += w4.z*f23.x; a3 += w4.w*f23.y;
    ds.x += w4.x; ds.y += w4.y; ds.z += w4.z; ds.w += w4.w;
  }
  const float val = 0.25f*(a0/ds.x + a1/ds.y + a2/ds.z + a3/ds.w) + bias[l];
  outp[(size_t)n*64 + l] = fmaxf(val, 0.f);
}

// ---------------- FF head: agg2 -> relu(@ff1) -> @ff2 -------
__global__ __launch_bounds__(256) void k_ff(
    const float* __restrict__ agg2,
    const float* __restrict__ w1, const float* __restrict__ b1,
    const float* __restrict__ w2, const float* __restrict__ b2f,
    float* __restrict__ out, int N)
{
  __shared__ float W1s[64*32];
  __shared__ float B1s[32];
  __shared__ float W2s[64];
  __shared__ float B2s[2];
  const int t = threadIdx.x;
  for (int i=t; i<64*32; i+=256) W1s[i] = w1[i];
  if (t < 32) B1s[t] = b1[t];
  if (t < 64) W2s[t] = w2[t];
  if (t < 2)  B2s[t] = b2f[t];
  __syncthreads();

  const int n = blockIdx.x*256 + t;
  if (n >= N) return;

  float t1[32];
  #pragma unroll
  for (int j=0;j<32;j++) t1[j] = B1s[j];
  #pragma unroll
  for (int c=0;c<64;c++){
    const float fc = agg2[(long)n*64 + c];
    #pragma unroll
    for (int j=0;j<32;j++) t1[j] += fc * W1s[c*32 + j];
  }
  float o0 = B2s[0], o1 = B2s[1];
  #pragma unroll
  for (int j=0;j<32;j++){
    const float v = t1[j] > 0.f ? t1[j] : 0.f;
    o0 += v * W2s[j*2 + 0];
    o1 += v * W2s[j*2 + 1];
  }
  out[(long)n*2 + 0] = o0;
  out[(long)n*2 + 1] = o1;
}

extern "C" void kernel_launch(void* const* d_in, const int* in_sizes, int n_in,
                              void* d_out, int out_size, void* d_ws, size_t ws_size,
                              hipStream_t stream)
{
  const float* x      = (const float*)d_in[0];
  const int*   ei     = (const int*)  d_in[1];
  const float* W1     = (const float*)d_in[3];
  const float* att_s1 = (const float*)d_in[4];
  const float* att_d1 = (const float*)d_in[5];
  const float* b1     = (const float*)d_in[6];
  const float* W2     = (const float*)d_in[7];
  const float* att_s2 = (const float*)d_in[8];
  const float* att_d2 = (const float*)d_in[9];
  const float* b2     = (const float*)d_in[10];
  const float* ff1w   = (const float*)d_in[11];
  const float* ff1b   = (const float*)d_in[12];
  const float* ff2w   = (const float*)d_in[13];
  const float* ff2b   = (const float*)d_in[14];
  float* out = (float*)d_out;

  const int N = in_sizes[0] / 128;
  const int E = in_sizes[1] / 2;
  const int tot = E + N;

  // ---- workspace (R0 time-shared: aggX layer-1; h2t+agg2 layer-2) ----
  char* p = (char*)d_ws;
  __half* aggX = (__half*)p;                         // [N,512] fp16 (layer-1)
  __half* h2t  = (__half*)p;                         // [N,256] fp16 (layer-2)
  float*  agg2 = (float*)(p + (size_t)N*256*2);      // [N,64]  f32  (layer-2)
  p += (size_t)N*256*4 + (size_t)N*64*4;             // region >= all phases
  float* agg1 = (float*)p;                           // [N,256] f32
  __half* xh  = (__half*)p;                          // [N,128] fp16, aliased:
  p += (size_t)N*256*4;                              //   dead before agg1 write
  float* asrc = (float*)p;  p += (size_t)N*4*4;      // [N,4]
  float* adst = (float*)p;  p += (size_t)N*4*4;      // [N,4]
  float* Ps   = (float*)p;  p += 512*4;              // [128,4]
  float* Pd   = (float*)p;  p += 512*4;              // [128,4]
  _Float16* W1t = (_Float16*)p; p += 256*128*2;      // [256,128] fp16
  _Float16* W2t = (_Float16*)p; p += 256*256*2;      // [256,256] fp16
  int* deg    = (int*)p;    p += (size_t)N*4;
  int* rowptr = (int*)p;    p += (size_t)(N+1)*4;
  int* cursor = (int*)p;    p += (size_t)N*4;
  int* bsum   = (int*)p;    p += SB*4;
  int* csr    = (int*)p;    p += (size_t)tot*4;

  const int gE  = (tot + 255) / 256;
  const int gN4 = (N + 3) / 4;
  const int g64 = (N + 63) / 64;

  // ---- CSR build (shared by both layers) ----
  k_zero <<<(N+255)/256,256,0,stream>>>(deg, N);
  k_count<<<gE,256,0,stream>>>(ei, E, N, deg);
  k_scan1<<<SB,256,0,stream>>>(deg, bsum, N);
  k_scan2<<<1,256,0,stream>>>(bsum);
  k_scan3<<<SB,256,0,stream>>>(deg, bsum, rowptr, cursor, N);
  k_fill <<<gE,256,0,stream>>>(ei, E, N, cursor, csr);

  // ---- weight prep (fp16 transposed copies) ----
  k_cvt_wt<<<128,256,0,stream>>>(W1, W1t, 128, 256);
  k_cvt_wt<<<256,256,0,stream>>>(W2, W2t, 256, 256);

  // ---- layer 1: aggregate-then-transform ----
  k_cvt_x<<<1024,256,0,stream>>>(x, xh, (long)N*64);
  k_prep<<<1,256,0,stream>>>(W1, att_s1, att_d1, Ps, Pd);
  k_att1<<<g64,256,0,stream>>>(x, Ps, Pd, asrc, adst, N);
  k_agg_x<<<gN4,256,0,stream>>>(rowptr, csr, asrc, adst, xh, (__half*)aggX, N);
  k_gemm1_mfma<<<g64*2,256,0,stream>>>((const _Float16*)aggX, W1t, b1, agg1, N);

  // ---- layer 2 (head mean; MFMA GEMM + fp16 transposed gather payload) ----
  k_gemm2_mfma<<<g64*2,256,0,stream>>>(agg1, W2t, att_s2, att_d2, h2t, asrc, adst, N);
  k_node_agg2<<<gN4,256,0,stream>>>(rowptr, csr, asrc, adst, h2t, b2, agg2, N);

  // ---- feed-forward head ----
  k_ff<<<(N+255)/256,256,0,stream>>>(agg2, ff1w, ff1b, ff2w, ff2b, out, N);
}

// Round 13
// 390.993 us; speedup vs baseline: 1.6222x; 1.0412x over previous
//
#include <hip/hip_runtime.h>
#include <hip/hip_fp16.h>

typedef _Float16 v8h __attribute__((ext_vector_type(8)));
typedef float    v4f __attribute__((ext_vector_type(4)));

__device__ __forceinline__ float lrelu(float x){ return x >= 0.f ? x : 0.2f*x; }

#define SB 256  // scan blocks

// ---------------- zero degree counters ----------------
__global__ __launch_bounds__(256) void k_zero(int* __restrict__ p, int n)
{
  int i = blockIdx.x*256 + threadIdx.x;
  if (i < n) p[i] = 0;
}

// ---------------- count in-degree per destination ----------------
__global__ __launch_bounds__(256) void k_count(const int* __restrict__ ei,
                                               int E, int N, int* __restrict__ deg)
{
  const int e = blockIdx.x*256 + threadIdx.x;
  if (e >= E + N) return;
  const int d = (e < E) ? ei[E + e] : (e - E);
  atomicAdd(&deg[d], 1);
}

// ---------------- parallel scan phase 1: per-block chunk sums ----------------
__global__ __launch_bounds__(256) void k_scan1(const int* __restrict__ deg,
                                               int* __restrict__ bsum, int N)
{
  __shared__ int sh[256];
  const int chunk = (N + SB - 1) / SB;
  const int lo = blockIdx.x * chunk;
  const int hi = min(lo + chunk, N);
  int s = 0;
  for (int i = lo + threadIdx.x; i < hi; i += 256) s += deg[i];
  sh[threadIdx.x] = s;
  __syncthreads();
  #pragma unroll
  for (int off = 128; off; off >>= 1){
    if (threadIdx.x < off) sh[threadIdx.x] += sh[threadIdx.x + off];
    __syncthreads();
  }
  if (threadIdx.x == 0) bsum[blockIdx.x] = sh[0];
}

// ---------------- parallel scan phase 2: exclusive scan of 256 partials -----
__global__ __launch_bounds__(256) void k_scan2(int* __restrict__ bsum)
{
  __shared__ int sh[256];
  const int v = bsum[threadIdx.x];
  sh[threadIdx.x] = v;
  __syncthreads();
  for (int off = 1; off < 256; off <<= 1){
    int t = 0;
    if (threadIdx.x >= off) t = sh[threadIdx.x - off];
    __syncthreads();
    sh[threadIdx.x] += t;
    __syncthreads();
  }
  bsum[threadIdx.x] = sh[threadIdx.x] - v;  // exclusive
}

// ---------------- parallel scan phase 3: chunk-local scan + base -------------
__global__ __launch_bounds__(256) void k_scan3(const int* __restrict__ deg,
                                               const int* __restrict__ bsum,
                                               int* __restrict__ rowptr,
                                               int* __restrict__ cursor, int N)
{
  __shared__ int sh[256];
  const int chunk = (N + SB - 1) / SB;
  const int lo = blockIdx.x * chunk;
  const int hi = min(lo + chunk, N);
  int base = bsum[blockIdx.x];
  for (int start = lo; start < hi; start += 256){
    const int i = start + threadIdx.x;
    const int v = (i < hi) ? deg[i] : 0;
    sh[threadIdx.x] = v;
    __syncthreads();
    for (int off = 1; off < 256; off <<= 1){
      int t = 0;
      if (threadIdx.x >= off) t = sh[threadIdx.x - off];
      __syncthreads();
      sh[threadIdx.x] += t;
      __syncthreads();
    }
    if (i < hi){
      const int excl = base + sh[threadIdx.x] - v;
      rowptr[i] = excl;
      cursor[i] = excl;
    }
    base += sh[255];
    __syncthreads();
  }
  if (blockIdx.x == SB-1 && threadIdx.x == 0) rowptr[N] = base;
}

// ---------------- fill CSR src lists ----------------
__global__ __launch_bounds__(256) void k_fill(const int* __restrict__ ei,
                                              int E, int N, int* __restrict__ cursor,
                                              int* __restrict__ csr)
{
  const int e = blockIdx.x*256 + threadIdx.x;
  if (e >= E + N) return;
  int s, d;
  if (e < E){ s = ei[e]; d = ei[E + e]; } else { s = d = e - E; }
  const int pos = atomicAdd(&cursor[d], 1);
  csr[pos] = s;
}

// ---------------- x -> fp16 copy (gather payload shrink) ----------------
__global__ __launch_bounds__(256) void k_cvt_x(const float* __restrict__ x,
                                               __half* __restrict__ xh, long n2)
{
  long i  = (long)blockIdx.x*256 + threadIdx.x;
  long st = (long)gridDim.x*256;
  for (; i < n2; i += st){
    const float2 v = *(const float2*)(x + 2*i);
    *(__half2*)(xh + 2*i) = __floats2half2_rn(v.x, v.y);
  }
}

// ---------------- W [K,C] f32 -> Wt [C,K] fp16 (transpose + convert) --------
__global__ __launch_bounds__(256) void k_cvt_wt(const float* __restrict__ W,
                                                _Float16* __restrict__ Wt,
                                                int K, int C)
{
  const int idx = blockIdx.x*256 + threadIdx.x;
  if (idx >= K*C) return;
  const int c = idx / K, k = idx % K;     // writes coalesced along k
  Wt[(size_t)c*K + k] = (_Float16)W[(size_t)k*C + c];
}

// ---------------- Ps/Pd = per-head W1 @ att vectors: [128,4] ----------------
__global__ __launch_bounds__(256) void k_prep(
    const float* __restrict__ W1, const float* __restrict__ as1,
    const float* __restrict__ ad1, float* __restrict__ Ps, float* __restrict__ Pd)
{
  const int t = threadIdx.x;
  for (int idx = t; idx < 512; idx += 256){
    const int k = idx >> 2, h = idx & 3;
    float ss = 0.f, dd = 0.f;
    for (int c = 0; c < 64; c++){
      const float wv = W1[k*256 + h*64 + c];
      ss += wv * as1[h*64 + c];
      dd += wv * ad1[h*64 + c];
    }
    Ps[k*4 + h] = ss;
    Pd[k*4 + h] = dd;
  }
}

// ---------------- layer-1 logits: asrc/adst = x @ Ps/Pd  [N,4] --------------
__global__ __launch_bounds__(256) void k_att1(
    const float* __restrict__ x, const float* __restrict__ Ps,
    const float* __restrict__ Pd, float* __restrict__ asrc,
    float* __restrict__ adst, int N)
{
  __shared__ float PsL[512], PdL[512];
  __shared__ float red[4][64][8];
  const int t = threadIdx.x;
  PsL[t] = Ps[t]; PsL[t+256] = Ps[t+256];
  PdL[t] = Pd[t]; PdL[t+256] = Pd[t+256];
  __syncthreads();
  const int r = t & 63, g = t >> 6;
  const int row = blockIdx.x*64 + r;
  const int rg = min(row, N-1);
  const float* xr = x + (size_t)rg*128;
  float4 pa = make_float4(0.f,0.f,0.f,0.f);
  float4 pb = make_float4(0.f,0.f,0.f,0.f);
  for (int kk = g*32; kk < g*32 + 32; kk++){
    const float xv = xr[kk];
    const float4 s4 = *(const float4*)(PsL + kk*4);
    const float4 d4 = *(const float4*)(PdL + kk*4);
    pa.x += xv*s4.x; pa.y += xv*s4.y; pa.z += xv*s4.z; pa.w += xv*s4.w;
    pb.x += xv*d4.x; pb.y += xv*d4.y; pb.z += xv*d4.z; pb.w += xv*d4.w;
  }
  *(float4*)(&red[g][r][0]) = pa;
  *(float4*)(&red[g][r][4]) = pb;
  __syncthreads();
  if (t < 64 && blockIdx.x*64 + t < N){
    float4 sa = make_float4(0.f,0.f,0.f,0.f);
    float4 sb = make_float4(0.f,0.f,0.f,0.f);
    #pragma unroll
    for (int gg = 0; gg < 4; gg++){
      const float4 qa = *(const float4*)(&red[gg][t][0]);
      const float4 qb = *(const float4*)(&red[gg][t][4]);
      sa.x += qa.x; sa.y += qa.y; sa.z += qa.z; sa.w += qa.w;
      sb.x += qb.x; sb.y += qb.y; sb.z += qb.z; sb.w += qb.w;
    }
    *(float4*)(asrc + (size_t)(blockIdx.x*64 + t)*4) = sa;
    *(float4*)(adst + (size_t)(blockIdx.x*64 + t)*4) = sb;
  }
}

// ---------------- layer-1 aggregate: inline weights + 4x unrolled gather ----
__global__ __launch_bounds__(256) void k_agg_x(
    const int* __restrict__ rowptr, const int* __restrict__ csr,
    const float* __restrict__ asrc, const float* __restrict__ adst,
    const __half* __restrict__ xh,
    __half* __restrict__ aggX, int N)
{
  const int n = blockIdx.x*4 + (threadIdx.x >> 6);
  const int l = threadIdx.x & 63;
  if (n >= N) return;
  const int start = rowptr[n];
  const int deg = rowptr[n+1] - start;
  const float4 ad = *(const float4*)(adst + (size_t)n*4);

  float a0x=0.f,a0y=0.f, a1x=0.f,a1y=0.f, a2x=0.f,a2y=0.f, a3x=0.f,a3y=0.f;
  float4 ds = make_float4(0.f,0.f,0.f,0.f);
  int j = 0;
  for (; j + 4 <= deg; j += 4){
    const int p0 = start + j;
    const int s0 = csr[p0+0], s1 = csr[p0+1], s2 = csr[p0+2], s3 = csr[p0+3];
    const float4 q0 = *(const float4*)(asrc + (size_t)s0*4);   // L2 hit
    const float4 q1 = *(const float4*)(asrc + (size_t)s1*4);
    const float4 q2 = *(const float4*)(asrc + (size_t)s2*4);
    const float4 q3 = *(const float4*)(asrc + (size_t)s3*4);
    const __half2 v0 = *(const __half2*)(xh + (size_t)s0*128 + 2*l);
    const __half2 v1 = *(const __half2*)(xh + (size_t)s1*128 + 2*l);
    const __half2 v2 = *(const __half2*)(xh + (size_t)s2*128 + 2*l);
    const __half2 v3 = *(const __half2*)(xh + (size_t)s3*128 + 2*l);
    float4 w0, w1, w2, w3;
    w0.x = __expf(lrelu(q0.x+ad.x)); w0.y = __expf(lrelu(q0.y+ad.y));
    w0.z = __expf(lrelu(q0.z+ad.z)); w0.w = __expf(lrelu(q0.w+ad.w));
    w1.x = __expf(lrelu(q1.x+ad.x)); w1.y = __expf(lrelu(q1.y+ad.y));
    w1.z = __expf(lrelu(q1.z+ad.z)); w1.w = __expf(lrelu(q1.w+ad.w));
    w2.x = __expf(lrelu(q2.x+ad.x)); w2.y = __expf(lrelu(q2.y+ad.y));
    w2.z = __expf(lrelu(q2.z+ad.z)); w2.w = __expf(lrelu(q2.w+ad.w));
    w3.x = __expf(lrelu(q3.x+ad.x)); w3.y = __expf(lrelu(q3.y+ad.y));
    w3.z = __expf(lrelu(q3.z+ad.z)); w3.w = __expf(lrelu(q3.w+ad.w));
    const float2 f0 = __half22float2(v0);
    const float2 f1 = __half22float2(v1);
    const float2 f2 = __half22float2(v2);
    const float2 f3 = __half22float2(v3);
    a0x += w0.x*f0.x + w1.x*f1.x + w2.x*f2.x + w3.x*f3.x;
    a0y += w0.x*f0.y + w1.x*f1.y + w2.x*f2.y + w3.x*f3.y;
    a1x += w0.y*f0.x + w1.y*f1.x + w2.y*f2.x + w3.y*f3.x;
    a1y += w0.y*f0.y + w1.y*f1.y + w2.y*f2.y + w3.y*f3.y;
    a2x += w0.z*f0.x + w1.z*f1.x + w2.z*f2.x + w3.z*f3.x;
    a2y += w0.z*f0.y + w1.z*f1.y + w2.z*f2.y + w3.z*f3.y;
    a3x += w0.w*f0.x + w1.w*f1.x + w2.w*f2.x + w3.w*f3.x;
    a3y += w0.w*f0.y + w1.w*f1.y + w2.w*f2.y + w3.w*f3.y;
    ds.x += w0.x+w1.x+w2.x+w3.x;
    ds.y += w0.y+w1.y+w2.y+w3.y;
    ds.z += w0.z+w1.z+w2.z+w3.z;
    ds.w += w0.w+w1.w+w2.w+w3.w;
  }
  for (; j < deg; j++){
    const int s = csr[start + j];
    const float4 q = *(const float4*)(asrc + (size_t)s*4);
    const float2 f = __half22float2(*(const __half2*)(xh + (size_t)s*128 + 2*l));
    float4 w4;
    w4.x = __expf(lrelu(q.x+ad.x)); w4.y = __expf(lrelu(q.y+ad.y));
    w4.z = __expf(lrelu(q.z+ad.z)); w4.w = __expf(lrelu(q.w+ad.w));
    a0x += w4.x*f.x; a0y += w4.x*f.y;
    a1x += w4.y*f.x; a1y += w4.y*f.y;
    a2x += w4.z*f.x; a2y += w4.z*f.y;
    a3x += w4.w*f.x; a3y += w4.w*f.y;
    ds.x += w4.x; ds.y += w4.y; ds.z += w4.z; ds.w += w4.w;
  }
  const float i0 = 1.f/ds.x, i1 = 1.f/ds.y, i2 = 1.f/ds.z, i3 = 1.f/ds.w;
  __half* base = aggX + (size_t)n*512 + 2*l;
  *(__half2*)(base +   0) = __floats2half2_rn(a0x*i0, a0y*i0);
  *(__half2*)(base + 128) = __floats2half2_rn(a1x*i1, a1y*i1);
  *(__half2*)(base + 256) = __floats2half2_rn(a2x*i2, a2y*i2);
  *(__half2*)(base + 384) = __floats2half2_rn(a3x*i3, a3y*i3);
}

// ---------------- FUSED MFMA: aggX -> (gemm1+relu, LDS) -> gemm2 -> h2t -----
// block = 64 rows, 4 waves (wave w: rows w*16..+16), cols 0..256 both phases.
// phase 1: agg1 tile = relu(blockdiag(aggX@W1)+b1) stored fp16 in LDS.
// phase 2: h2 = agg1@W2 from LDS A-frags; logits + transposed h2t store fused.
__global__ __launch_bounds__(256) void k_gemm_fused(
    const _Float16* __restrict__ aggX,  // [N,4,128]
    const _Float16* __restrict__ W1t,   // [256,128] (Wt[c][k])
    const float* __restrict__ b1,       // [256]
    const _Float16* __restrict__ W2t,   // [256,256] (Wt[c][k])
    const float* __restrict__ att_s, const float* __restrict__ att_d,
    __half* __restrict__ h2t,           // [N,64,4] halves
    float* __restrict__ asrc, float* __restrict__ adst, int N)
{
  __shared__ _Float16 h1[64][264];      // 33KB; stride 528B = 33x16B (aligned, ~2-way banks)
  const int w = threadIdx.x >> 6, l = threadIdx.x & 63;
  const int lr = l & 15, lk = l >> 4;
  const int row0 = blockIdx.x*64 + w*16;
  const int rowa = min(row0 + lr, N-1);

  // ---- phase 1 ----
  {
    v4f acc[16] = {};
    for (int ks = 0; ks < 4; ks++){
      const int k = ks*32 + lk*8;
      v8h a[4];
      #pragma unroll
      for (int h = 0; h < 4; h++)
        a[h] = *(const v8h*)(aggX + (size_t)rowa*512 + h*128 + k);
      #pragma unroll
      for (int ct = 0; ct < 16; ct++){
        const v8h b = *(const v8h*)(W1t + (size_t)(ct*16+lr)*128 + k);
        acc[ct] = __builtin_amdgcn_mfma_f32_16x16x32_f16(a[ct>>2], b, acc[ct], 0,0,0);
      }
    }
    #pragma unroll
    for (int ct = 0; ct < 16; ct++){
      const int col = ct*16 + lr;
      const float bv = b1[col];
      #pragma unroll
      for (int j = 0; j < 4; j++)
        h1[w*16 + lk*4 + j][col] = (_Float16)fmaxf(acc[ct][j] + bv, 0.f);
    }
  }
  __syncthreads();

  // ---- phase 2 ----
  v4f acc[16] = {};
  for (int ks = 0; ks < 8; ks++){
    const int k = ks*32 + lk*8;
    const v8h a = *(const v8h*)(&h1[w*16 + lr][k]);
    #pragma unroll
    for (int ct = 0; ct < 16; ct++){
      const v8h b = *(const v8h*)(W2t + (size_t)(ct*16+lr)*256 + k);
      acc[ct] = __builtin_amdgcn_mfma_f32_16x16x32_f16(a, b, acc[ct], 0,0,0);
    }
  }
  // attention coefficients: head = ct>>2, ch = (ct&3)*16+lr
  float AS[16], AD[16];
  #pragma unroll
  for (int ct = 0; ct < 16; ct++){
    const int h = ct >> 2, idx = (ct & 3)*16 + lr;
    AS[ct] = att_s[h*64 + idx];
    AD[ct] = att_d[h*64 + idx];
  }
  #pragma unroll
  for (int j = 0; j < 4; j++){
    const int row = row0 + lk*4 + j;
    const bool ok = row < N;
    float vs[4] = {0.f,0.f,0.f,0.f}, vd[4] = {0.f,0.f,0.f,0.f};
    #pragma unroll
    for (int ct = 0; ct < 16; ct++){
      vs[ct>>2] += acc[ct][j] * AS[ct];
      vd[ct>>2] += acc[ct][j] * AD[ct];
    }
    if (ok){
      #pragma unroll
      for (int ctm = 0; ctm < 4; ctm++){
        const int ch = ctm*16 + lr;
        *(__half2*)(h2t + (size_t)row*256 + ch*4 + 0) =
            __floats2half2_rn(acc[ctm][j],   acc[ctm+4][j]);
        *(__half2*)(h2t + (size_t)row*256 + ch*4 + 2) =
            __floats2half2_rn(acc[ctm+8][j], acc[ctm+12][j]);
      }
    }
    #pragma unroll
    for (int h = 0; h < 4; h++){
      float s = vs[h], d = vd[h];
      #pragma unroll
      for (int off = 1; off < 16; off <<= 1){
        s += __shfl_xor(s, off, 16);
        d += __shfl_xor(d, off, 16);
      }
      if (lr == 0 && ok){
        asrc[(size_t)row*4 + h] = s;
        adst[(size_t)row*4 + h] = d;
      }
    }
  }
}

// ---------------- layer-2 aggregation: inline weights + 4x unrolled ---------
__global__ __launch_bounds__(256) void k_node_agg2(
    const int* __restrict__ rowptr, const int* __restrict__ csr,
    const float* __restrict__ asrc, const float* __restrict__ adst,
    const __half* __restrict__ h2t, const float* __restrict__ bias,
    float* __restrict__ outp, int N)
{
  const int n = blockIdx.x*4 + (threadIdx.x >> 6);
  const int l = threadIdx.x & 63;              // output channel
  if (n >= N) return;
  const int start = rowptr[n];
  const int deg = rowptr[n+1] - start;
  const float4 ad = *(const float4*)(adst + (size_t)n*4);

  float a0=0.f, a1=0.f, a2=0.f, a3=0.f;
  float4 ds = make_float4(0.f,0.f,0.f,0.f);
  int j = 0;
  for (; j + 4 <= deg; j += 4){
    const int p0 = start + j;
    const int s0 = csr[p0+0], s1 = csr[p0+1], s2 = csr[p0+2], s3 = csr[p0+3];
    const float4 q0 = *(const float4*)(asrc + (size_t)s0*4);   // L2 hit
    const float4 q1 = *(const float4*)(asrc + (size_t)s1*4);
    const float4 q2 = *(const float4*)(asrc + (size_t)s2*4);
    const float4 q3 = *(const float4*)(asrc + (size_t)s3*4);
    const uint2 u0 = *(const uint2*)(h2t + (size_t)s0*256 + l*4);
    const uint2 u1 = *(const uint2*)(h2t + (size_t)s1*256 + l*4);
    const uint2 u2 = *(const uint2*)(h2t + (size_t)s2*256 + l*4);
    const uint2 u3 = *(const uint2*)(h2t + (size_t)s3*256 + l*4);
    float4 w0, w1, w2, w3;
    w0.x = __expf(lrelu(q0.x+ad.x)); w0.y = __expf(lrelu(q0.y+ad.y));
    w0.z = __expf(lrelu(q0.z+ad.z)); w0.w = __expf(lrelu(q0.w+ad.w));
    w1.x = __expf(lrelu(q1.x+ad.x)); w1.y = __expf(lrelu(q1.y+ad.y));
    w1.z = __expf(lrelu(q1.z+ad.z)); w1.w = __expf(lrelu(q1.w+ad.w));
    w2.x = __expf(lrelu(q2.x+ad.x)); w2.y = __expf(lrelu(q2.y+ad.y));
    w2.z = __expf(lrelu(q2.z+ad.z)); w2.w = __expf(lrelu(q2.w+ad.w));
    w3.x = __expf(lrelu(q3.x+ad.x)); w3.y = __expf(lrelu(q3.y+ad.y));
    w3.z = __expf(lrelu(q3.z+ad.z)); w3.w = __expf(lrelu(q3.w+ad.w));
    const float2 g0 = __half22float2(*reinterpret_cast<const __half2*>(&u0.x));
    const float2 g1 = __half22float2(*reinterpret_cast<const __half2*>(&u0.y));
    const float2 h0 = __half22float2(*reinterpret_cast<const __half2*>(&u1.x));
    const float2 h1 = __half22float2(*reinterpret_cast<const __half2*>(&u1.y));
    const float2 i0 = __half22float2(*reinterpret_cast<const __half2*>(&u2.x));
    const float2 i1 = __half22float2(*reinterpret_cast<const __half2*>(&u2.y));
    const float2 k0 = __half22float2(*reinterpret_cast<const __half2*>(&u3.x));
    const float2 k1 = __half22float2(*reinterpret_cast<const __half2*>(&u3.y));
    a0 += w0.x*g0.x + w1.x*h0.x + w2.x*i0.x + w3.x*k0.x;
    a1 += w0.y*g0.y + w1.y*h0.y + w2.y*i0.y + w3.y*k0.y;
    a2 += w0.z*g1.x + w1.z*h1.x + w2.z*i1.x + w3.z*k1.x;
    a3 += w0.w*g1.y + w1.w*h1.y + w2.w*i1.y + w3.w*k1.y;
    ds.x += w0.x+w1.x+w2.x+w3.x;
    ds.y += w0.y+w1.y+w2.y+w3.y;
    ds.z += w0.z+w1.z+w2.z+w3.z;
    ds.w += w0.w+w1.w+w2.w+w3.w;
  }
  for (; j < deg; j++){
    const int s = csr[start + j];
    const float4 q = *(const float4*)(asrc + (size_t)s*4);
    const uint2 u = *(const uint2*)(h2t + (size_t)s*256 + l*4);
    float4 w4;
    w4.x = __expf(lrelu(q.x+ad.x)); w4.y = __expf(lrelu(q.y+ad.y));
    w4.z = __expf(lrelu(q.z+ad.z)); w4.w = __expf(lrelu(q.w+ad.w));
    const float2 f01 = __half22float2(*reinterpret_cast<const __half2*>(&u.x));
    const float2 f23 = __half22float2(*reinterpret_cast<const __half2*>(&u.y));
    a0 += w4.x*f01.x; a1 += w4.y*f01.y; a2 += w4.z*f23.x; a3 += w4.w*f23.y;
    ds.x += w4.x; ds.y += w4.y; ds.z += w4.z; ds.w += w4.w;
  }
  const float val = 0.25f*(a0/ds.x + a1/ds.y + a2/ds.z + a3/ds.w) + bias[l];
  outp[(size_t)n*64 + l] = fmaxf(val, 0.f);
}

// ---------------- FF head: agg2 -> relu(@ff1) -> @ff2 -------
__global__ __launch_bounds__(256) void k_ff(
    const float* __restrict__ agg2,
    const float* __restrict__ w1, const float* __restrict__ b1,
    const float* __restrict__ w2, const float* __restrict__ b2f,
    float* __restrict__ out, int N)
{
  __shared__ float W1s[64*32];
  __shared__ float B1s[32];
  __shared__ float W2s[64];
  __shared__ float B2s[2];
  const int t = threadIdx.x;
  for (int i=t; i<64*32; i+=256) W1s[i] = w1[i];
  if (t < 32) B1s[t] = b1[t];
  if (t < 64) W2s[t] = w2[t];
  if (t < 2)  B2s[t] = b2f[t];
  __syncthreads();

  const int n = blockIdx.x*256 + t;
  if (n >= N) return;

  float t1[32];
  #pragma unroll
  for (int j=0;j<32;j++) t1[j] = B1s[j];
  #pragma unroll
  for (int c=0;c<64;c++){
    const float fc = agg2[(long)n*64 + c];
    #pragma unroll
    for (int j=0;j<32;j++) t1[j] += fc * W1s[c*32 + j];
  }
  float o0 = B2s[0], o1 = B2s[1];
  #pragma unroll
  for (int j=0;j<32;j++){
    const float v = t1[j] > 0.f ? t1[j] : 0.f;
    o0 += v * W2s[j*2 + 0];
    o1 += v * W2s[j*2 + 1];
  }
  out[(long)n*2 + 0] = o0;
  out[(long)n*2 + 1] = o1;
}

extern "C" void kernel_launch(void* const* d_in, const int* in_sizes, int n_in,
                              void* d_out, int out_size, void* d_ws, size_t ws_size,
                              hipStream_t stream)
{
  const float* x      = (const float*)d_in[0];
  const int*   ei     = (const int*)  d_in[1];
  const float* W1     = (const float*)d_in[3];
  const float* att_s1 = (const float*)d_in[4];
  const float* att_d1 = (const float*)d_in[5];
  const float* b1     = (const float*)d_in[6];
  const float* W2     = (const float*)d_in[7];
  const float* att_s2 = (const float*)d_in[8];
  const float* att_d2 = (const float*)d_in[9];
  const float* b2     = (const float*)d_in[10];
  const float* ff1w   = (const float*)d_in[11];
  const float* ff1b   = (const float*)d_in[12];
  const float* ff2w   = (const float*)d_in[13];
  const float* ff2b   = (const float*)d_in[14];
  float* out = (float*)d_out;

  const int N = in_sizes[0] / 128;
  const int E = in_sizes[1] / 2;
  const int tot = E + N;

  // ---- workspace ----
  // R0: aggX [N*512 halves] (layer-1); agg2 f32 [N*64] at +N*512B (after aggX dead)
  char* p = (char*)d_ws;
  __half* aggX = (__half*)p;
  float*  agg2 = (float*)(p + (size_t)N*512);
  p += (size_t)N*1024;
  // R1 (old agg1 region, N*1024B): xh [N*128 halves] at 0; h2t [N*256 halves] at +N*256B
  __half* xh  = (__half*)p;
  __half* h2t = (__half*)(p + (size_t)N*256);
  p += (size_t)N*1024;
  float* asrc = (float*)p;  p += (size_t)N*4*4;
  float* adst = (float*)p;  p += (size_t)N*4*4;
  float* Ps   = (float*)p;  p += 512*4;
  float* Pd   = (float*)p;  p += 512*4;
  _Float16* W1t = (_Float16*)p; p += 256*128*2;
  _Float16* W2t = (_Float16*)p; p += 256*256*2;
  int* deg    = (int*)p;    p += (size_t)N*4;
  int* rowptr = (int*)p;    p += (size_t)(N+1)*4;
  int* cursor = (int*)p;    p += (size_t)N*4;
  int* bsum   = (int*)p;    p += SB*4;
  int* csr    = (int*)p;    p += (size_t)tot*4;

  const int gE  = (tot + 255) / 256;
  const int gN4 = (N + 3) / 4;
  const int g64 = (N + 63) / 64;

  // ---- CSR build (shared by both layers) ----
  k_zero <<<(N+255)/256,256,0,stream>>>(deg, N);
  k_count<<<gE,256,0,stream>>>(ei, E, N, deg);
  k_scan1<<<SB,256,0,stream>>>(deg, bsum, N);
  k_scan2<<<1,256,0,stream>>>(bsum);
  k_scan3<<<SB,256,0,stream>>>(deg, bsum, rowptr, cursor, N);
  k_fill <<<gE,256,0,stream>>>(ei, E, N, cursor, csr);

  // ---- weight prep (fp16 transposed copies) ----
  k_cvt_wt<<<128,256,0,stream>>>(W1, W1t, 128, 256);
  k_cvt_wt<<<256,256,0,stream>>>(W2, W2t, 256, 256);

  // ---- layer 1: aggregate-then-transform ----
  k_cvt_x<<<1024,256,0,stream>>>(x, xh, (long)N*64);
  k_prep<<<1,256,0,stream>>>(W1, att_s1, att_d1, Ps, Pd);
  k_att1<<<g64,256,0,stream>>>(x, Ps, Pd, asrc, adst, N);
  k_agg_x<<<gN4,256,0,stream>>>(rowptr, csr, asrc, adst, xh, aggX, N);

  // ---- fused gemm1+gemm2 (+ layer-2 logits + transposed fp16 h2t) ----
  k_gemm_fused<<<g64,256,0,stream>>>((const _Float16*)aggX, W1t, b1, W2t,
                                     att_s2, att_d2, h2t, asrc, adst, N);

  // ---- layer-2 aggregation + FF head ----
  k_node_agg2<<<gN4,256,0,stream>>>(rowptr, csr, asrc, adst, h2t, b2, agg2, N);
  k_ff<<<(N+255)/256,256,0,stream>>>(agg2, ff1w, ff1b, ff2w, ff2b, out, N);
}

// Round 14
// 389.193 us; speedup vs baseline: 1.6297x; 1.0046x over previous
//
#include <hip/hip_runtime.h>
#include <hip/hip_fp16.h>

typedef _Float16 v8h __attribute__((ext_vector_type(8)));
typedef float    v4f __attribute__((ext_vector_type(4)));

__device__ __forceinline__ float lrelu(float x){ return x >= 0.f ? x : 0.2f*x; }

#define SB 256  // scan blocks

// ---------------- zero degree counters ----------------
__global__ __launch_bounds__(256) void k_zero(int* __restrict__ p, int n)
{
  int i = blockIdx.x*256 + threadIdx.x;
  if (i < n) p[i] = 0;
}

// ---------------- count in-degree per destination ----------------
__global__ __launch_bounds__(256) void k_count(const int* __restrict__ ei,
                                               int E, int N, int* __restrict__ deg)
{
  const int e = blockIdx.x*256 + threadIdx.x;
  if (e >= E + N) return;
  const int d = (e < E) ? ei[E + e] : (e - E);
  atomicAdd(&deg[d], 1);
}

// ---------------- parallel scan phase 1: per-block chunk sums ----------------
__global__ __launch_bounds__(256) void k_scan1(const int* __restrict__ deg,
                                               int* __restrict__ bsum, int N)
{
  __shared__ int sh[256];
  const int chunk = (N + SB - 1) / SB;
  const int lo = blockIdx.x * chunk;
  const int hi = min(lo + chunk, N);
  int s = 0;
  for (int i = lo + threadIdx.x; i < hi; i += 256) s += deg[i];
  sh[threadIdx.x] = s;
  __syncthreads();
  #pragma unroll
  for (int off = 128; off; off >>= 1){
    if (threadIdx.x < off) sh[threadIdx.x] += sh[threadIdx.x + off];
    __syncthreads();
  }
  if (threadIdx.x == 0) bsum[blockIdx.x] = sh[0];
}

// ---------------- parallel scan phase 2: exclusive scan of 256 partials -----
__global__ __launch_bounds__(256) void k_scan2(int* __restrict__ bsum)
{
  __shared__ int sh[256];
  const int v = bsum[threadIdx.x];
  sh[threadIdx.x] = v;
  __syncthreads();
  for (int off = 1; off < 256; off <<= 1){
    int t = 0;
    if (threadIdx.x >= off) t = sh[threadIdx.x - off];
    __syncthreads();
    sh[threadIdx.x] += t;
    __syncthreads();
  }
  bsum[threadIdx.x] = sh[threadIdx.x] - v;  // exclusive
}

// ---------------- parallel scan phase 3: chunk-local scan + base -------------
__global__ __launch_bounds__(256) void k_scan3(const int* __restrict__ deg,
                                               const int* __restrict__ bsum,
                                               int* __restrict__ rowptr,
                                               int* __restrict__ cursor, int N)
{
  __shared__ int sh[256];
  const int chunk = (N + SB - 1) / SB;
  const int lo = blockIdx.x * chunk;
  const int hi = min(lo + chunk, N);
  int base = bsum[blockIdx.x];
  for (int start = lo; start < hi; start += 256){
    const int i = start + threadIdx.x;
    const int v = (i < hi) ? deg[i] : 0;
    sh[threadIdx.x] = v;
    __syncthreads();
    for (int off = 1; off < 256; off <<= 1){
      int t = 0;
      if (threadIdx.x >= off) t = sh[threadIdx.x - off];
      __syncthreads();
      sh[threadIdx.x] += t;
      __syncthreads();
    }
    if (i < hi){
      const int excl = base + sh[threadIdx.x] - v;
      rowptr[i] = excl;
      cursor[i] = excl;
    }
    base += sh[255];
    __syncthreads();
  }
  if (blockIdx.x == SB-1 && threadIdx.x == 0) rowptr[N] = base;
}

// ---------------- fill CSR src lists ----------------
__global__ __launch_bounds__(256) void k_fill(const int* __restrict__ ei,
                                              int E, int N, int* __restrict__ cursor,
                                              int* __restrict__ csr)
{
  const int e = blockIdx.x*256 + threadIdx.x;
  if (e >= E + N) return;
  int s, d;
  if (e < E){ s = ei[e]; d = ei[E + e]; } else { s = d = e - E; }
  const int pos = atomicAdd(&cursor[d], 1);
  csr[pos] = s;
}

// ---------------- x -> fp16 copy (gather payload shrink) ----------------
__global__ __launch_bounds__(256) void k_cvt_x(const float* __restrict__ x,
                                               __half* __restrict__ xh, long n2)
{
  long i  = (long)blockIdx.x*256 + threadIdx.x;
  long st = (long)gridDim.x*256;
  for (; i < n2; i += st){
    const float2 v = *(const float2*)(x + 2*i);
    *(__half2*)(xh + 2*i) = __floats2half2_rn(v.x, v.y);
  }
}

// ---------------- W [K,C] f32 -> Wt [C,K] fp16 (transpose + convert) --------
__global__ __launch_bounds__(256) void k_cvt_wt(const float* __restrict__ W,
                                                _Float16* __restrict__ Wt,
                                                int K, int C)
{
  const int idx = blockIdx.x*256 + threadIdx.x;
  if (idx >= K*C) return;
  const int c = idx / K, k = idx % K;     // writes coalesced along k
  Wt[(size_t)c*K + k] = (_Float16)W[(size_t)k*C + c];
}

// ---------------- Ps/Pd = per-head W1 @ att vectors: [128,4] ----------------
__global__ __launch_bounds__(256) void k_prep(
    const float* __restrict__ W1, const float* __restrict__ as1,
    const float* __restrict__ ad1, float* __restrict__ Ps, float* __restrict__ Pd)
{
  const int t = threadIdx.x;
  for (int idx = t; idx < 512; idx += 256){
    const int k = idx >> 2, h = idx & 3;
    float ss = 0.f, dd = 0.f;
    for (int c = 0; c < 64; c++){
      const float wv = W1[k*256 + h*64 + c];
      ss += wv * as1[h*64 + c];
      dd += wv * ad1[h*64 + c];
    }
    Ps[k*4 + h] = ss;
    Pd[k*4 + h] = dd;
  }
}

// ---------------- layer-1 logits: asrc/adst = x @ Ps/Pd  [N,4] --------------
__global__ __launch_bounds__(256) void k_att1(
    const float* __restrict__ x, const float* __restrict__ Ps,
    const float* __restrict__ Pd, float* __restrict__ asrc,
    float* __restrict__ adst, int N)
{
  __shared__ float PsL[512], PdL[512];
  __shared__ float red[4][64][8];
  const int t = threadIdx.x;
  PsL[t] = Ps[t]; PsL[t+256] = Ps[t+256];
  PdL[t] = Pd[t]; PdL[t+256] = Pd[t+256];
  __syncthreads();
  const int r = t & 63, g = t >> 6;
  const int row = blockIdx.x*64 + r;
  const int rg = min(row, N-1);
  const float* xr = x + (size_t)rg*128;
  float4 pa = make_float4(0.f,0.f,0.f,0.f);
  float4 pb = make_float4(0.f,0.f,0.f,0.f);
  for (int kk = g*32; kk < g*32 + 32; kk++){
    const float xv = xr[kk];
    const float4 s4 = *(const float4*)(PsL + kk*4);
    const float4 d4 = *(const float4*)(PdL + kk*4);
    pa.x += xv*s4.x; pa.y += xv*s4.y; pa.z += xv*s4.z; pa.w += xv*s4.w;
    pb.x += xv*d4.x; pb.y += xv*d4.y; pb.z += xv*d4.z; pb.w += xv*d4.w;
  }
  *(float4*)(&red[g][r][0]) = pa;
  *(float4*)(&red[g][r][4]) = pb;
  __syncthreads();
  if (t < 64 && blockIdx.x*64 + t < N){
    float4 sa = make_float4(0.f,0.f,0.f,0.f);
    float4 sb = make_float4(0.f,0.f,0.f,0.f);
    #pragma unroll
    for (int gg = 0; gg < 4; gg++){
      const float4 qa = *(const float4*)(&red[gg][t][0]);
      const float4 qb = *(const float4*)(&red[gg][t][4]);
      sa.x += qa.x; sa.y += qa.y; sa.z += qa.z; sa.w += qa.w;
      sb.x += qb.x; sb.y += qb.y; sb.z += qb.z; sb.w += qb.w;
    }
    *(float4*)(asrc + (size_t)(blockIdx.x*64 + t)*4) = sa;
    *(float4*)(adst + (size_t)(blockIdx.x*64 + t)*4) = sb;
  }
}

// ---------------- layer-1 aggregate: inline weights + 4x unrolled gather ----
__global__ __launch_bounds__(256) void k_agg_x(
    const int* __restrict__ rowptr, const int* __restrict__ csr,
    const float* __restrict__ asrc, const float* __restrict__ adst,
    const __half* __restrict__ xh,
    __half* __restrict__ aggX, int N)
{
  const int n = blockIdx.x*4 + (threadIdx.x >> 6);
  const int l = threadIdx.x & 63;
  if (n >= N) return;
  const int start = rowptr[n];
  const int deg = rowptr[n+1] - start;
  const float4 ad = *(const float4*)(adst + (size_t)n*4);

  float a0x=0.f,a0y=0.f, a1x=0.f,a1y=0.f, a2x=0.f,a2y=0.f, a3x=0.f,a3y=0.f;
  float4 ds = make_float4(0.f,0.f,0.f,0.f);
  int j = 0;
  for (; j + 4 <= deg; j += 4){
    const int p0 = start + j;
    const int s0 = csr[p0+0], s1 = csr[p0+1], s2 = csr[p0+2], s3 = csr[p0+3];
    const float4 q0 = *(const float4*)(asrc + (size_t)s0*4);   // L2 hit
    const float4 q1 = *(const float4*)(asrc + (size_t)s1*4);
    const float4 q2 = *(const float4*)(asrc + (size_t)s2*4);
    const float4 q3 = *(const float4*)(asrc + (size_t)s3*4);
    const __half2 v0 = *(const __half2*)(xh + (size_t)s0*128 + 2*l);
    const __half2 v1 = *(const __half2*)(xh + (size_t)s1*128 + 2*l);
    const __half2 v2 = *(const __half2*)(xh + (size_t)s2*128 + 2*l);
    const __half2 v3 = *(const __half2*)(xh + (size_t)s3*128 + 2*l);
    float4 w0, w1, w2, w3;
    w0.x = __expf(lrelu(q0.x+ad.x)); w0.y = __expf(lrelu(q0.y+ad.y));
    w0.z = __expf(lrelu(q0.z+ad.z)); w0.w = __expf(lrelu(q0.w+ad.w));
    w1.x = __expf(lrelu(q1.x+ad.x)); w1.y = __expf(lrelu(q1.y+ad.y));
    w1.z = __expf(lrelu(q1.z+ad.z)); w1.w = __expf(lrelu(q1.w+ad.w));
    w2.x = __expf(lrelu(q2.x+ad.x)); w2.y = __expf(lrelu(q2.y+ad.y));
    w2.z = __expf(lrelu(q2.z+ad.z)); w2.w = __expf(lrelu(q2.w+ad.w));
    w3.x = __expf(lrelu(q3.x+ad.x)); w3.y = __expf(lrelu(q3.y+ad.y));
    w3.z = __expf(lrelu(q3.z+ad.z)); w3.w = __expf(lrelu(q3.w+ad.w));
    const float2 f0 = __half22float2(v0);
    const float2 f1 = __half22float2(v1);
    const float2 f2 = __half22float2(v2);
    const float2 f3 = __half22float2(v3);
    a0x += w0.x*f0.x + w1.x*f1.x + w2.x*f2.x + w3.x*f3.x;
    a0y += w0.x*f0.y + w1.x*f1.y + w2.x*f2.y + w3.x*f3.y;
    a1x += w0.y*f0.x + w1.y*f1.x + w2.y*f2.x + w3.y*f3.x;
    a1y += w0.y*f0.y + w1.y*f1.y + w2.y*f2.y + w3.y*f3.y;
    a2x += w0.z*f0.x + w1.z*f1.x + w2.z*f2.x + w3.z*f3.x;
    a2y += w0.z*f0.y + w1.z*f1.y + w2.z*f2.y + w3.z*f3.y;
    a3x += w0.w*f0.x + w1.w*f1.x + w2.w*f2.x + w3.w*f3.x;
    a3y += w0.w*f0.y + w1.w*f1.y + w2.w*f2.y + w3.w*f3.y;
    ds.x += w0.x+w1.x+w2.x+w3.x;
    ds.y += w0.y+w1.y+w2.y+w3.y;
    ds.z += w0.z+w1.z+w2.z+w3.z;
    ds.w += w0.w+w1.w+w2.w+w3.w;
  }
  for (; j < deg; j++){
    const int s = csr[start + j];
    const float4 q = *(const float4*)(asrc + (size_t)s*4);
    const float2 f = __half22float2(*(const __half2*)(xh + (size_t)s*128 + 2*l));
    float4 w4;
    w4.x = __expf(lrelu(q.x+ad.x)); w4.y = __expf(lrelu(q.y+ad.y));
    w4.z = __expf(lrelu(q.z+ad.z)); w4.w = __expf(lrelu(q.w+ad.w));
    a0x += w4.x*f.x; a0y += w4.x*f.y;
    a1x += w4.y*f.x; a1y += w4.y*f.y;
    a2x += w4.z*f.x; a2y += w4.z*f.y;
    a3x += w4.w*f.x; a3y += w4.w*f.y;
    ds.x += w4.x; ds.y += w4.y; ds.z += w4.z; ds.w += w4.w;
  }
  const float i0 = 1.f/ds.x, i1 = 1.f/ds.y, i2 = 1.f/ds.z, i3 = 1.f/ds.w;
  __half* base = aggX + (size_t)n*512 + 2*l;
  *(__half2*)(base +   0) = __floats2half2_rn(a0x*i0, a0y*i0);
  *(__half2*)(base + 128) = __floats2half2_rn(a1x*i1, a1y*i1);
  *(__half2*)(base + 256) = __floats2half2_rn(a2x*i2, a2y*i2);
  *(__half2*)(base + 384) = __floats2half2_rn(a3x*i3, a3y*i3);
}

// ---------------- FUSED MFMA, 8 waves: wave (wr,wc) = rows wr*16 x cols wc*128
// phase 1: h1 quadrant = relu(blockdiag(aggX@W1)+b1) -> LDS fp16.
// phase 2: h2 = h1@W2 (LDS A-frags, full k); logits + transposed h2t fused.
__global__ __launch_bounds__(512) void k_gemm_fused(
    const _Float16* __restrict__ aggX,  // [N,4,128]
    const _Float16* __restrict__ W1t,   // [256,128] (Wt[c][k])
    const float* __restrict__ b1,       // [256]
    const _Float16* __restrict__ W2t,   // [256,256] (Wt[c][k])
    const float* __restrict__ att_s, const float* __restrict__ att_d,
    __half* __restrict__ h2t,           // [N,64,4] halves
    float* __restrict__ asrc, float* __restrict__ adst, int N)
{
  __shared__ _Float16 h1[64][264];      // 33KB
  const int wv = threadIdx.x >> 6, l = threadIdx.x & 63;
  const int wr = wv & 3, wc = wv >> 2;  // row group / col half
  const int lr = l & 15, lk = l >> 4;
  const int row0 = blockIdx.x*64 + wr*16;
  const int rowa = min(row0 + lr, N-1);

  // ---- phase 1: cols wc*128 .. +128 (heads 2wc, 2wc+1) ----
  {
    v4f acc[8] = {};
    for (int ks = 0; ks < 4; ks++){
      const int k = ks*32 + lk*8;
      const v8h a0 = *(const v8h*)(aggX + (size_t)rowa*512 + (2*wc  )*128 + k);
      const v8h a1 = *(const v8h*)(aggX + (size_t)rowa*512 + (2*wc+1)*128 + k);
      #pragma unroll
      for (int ct = 0; ct < 8; ct++){
        const int col = wc*128 + ct*16 + lr;
        const v8h b = *(const v8h*)(W1t + (size_t)col*128 + k);
        acc[ct] = __builtin_amdgcn_mfma_f32_16x16x32_f16(ct < 4 ? a0 : a1, b, acc[ct], 0,0,0);
      }
    }
    #pragma unroll
    for (int ct = 0; ct < 8; ct++){
      const int col = wc*128 + ct*16 + lr;
      const float bv = b1[col];
      #pragma unroll
      for (int j = 0; j < 4; j++)
        h1[wr*16 + lk*4 + j][col] = (_Float16)fmaxf(acc[ct][j] + bv, 0.f);
    }
  }
  __syncthreads();

  // ---- phase 2: cols wc*128 .. +128, full k=256 from LDS ----
  v4f acc[8] = {};
  for (int ks = 0; ks < 8; ks++){
    const int k = ks*32 + lk*8;
    const v8h a = *(const v8h*)(&h1[wr*16 + lr][k]);
    #pragma unroll
    for (int ct = 0; ct < 8; ct++){
      const int col = wc*128 + ct*16 + lr;
      const v8h b = *(const v8h*)(W2t + (size_t)col*256 + k);
      acc[ct] = __builtin_amdgcn_mfma_f32_16x16x32_f16(a, b, acc[ct], 0,0,0);
    }
  }
  // attention coefficients: head = 2wc + (ct>>2), ch = (ct&3)*16 + lr
  float AS[8], AD[8];
  #pragma unroll
  for (int ct = 0; ct < 8; ct++){
    const int h = 2*wc + (ct >> 2), idx = (ct & 3)*16 + lr;
    AS[ct] = att_s[h*64 + idx];
    AD[ct] = att_d[h*64 + idx];
  }
  #pragma unroll
  for (int j = 0; j < 4; j++){
    const int row = row0 + lk*4 + j;
    const bool ok = row < N;
    float vs0=0.f, vd0=0.f, vs1=0.f, vd1=0.f;
    #pragma unroll
    for (int ct = 0; ct < 8; ct++){
      const float v = acc[ct][j];
      if (ct < 4){ vs0 += v*AS[ct]; vd0 += v*AD[ct]; }
      else       { vs1 += v*AS[ct]; vd1 += v*AD[ct]; }
    }
    if (ok){
      #pragma unroll
      for (int ctm = 0; ctm < 4; ctm++){
        const int ch = ctm*16 + lr;
        *(__half2*)(h2t + (size_t)row*256 + ch*4 + 2*wc) =
            __floats2half2_rn(acc[ctm][j], acc[ctm+4][j]);
      }
    }
    #pragma unroll
    for (int off = 1; off < 16; off <<= 1){
      vs0 += __shfl_xor(vs0, off, 16);
      vd0 += __shfl_xor(vd0, off, 16);
      vs1 += __shfl_xor(vs1, off, 16);
      vd1 += __shfl_xor(vd1, off, 16);
    }
    if (lr == 0 && ok){
      asrc[(size_t)row*4 + 2*wc    ] = vs0;
      adst[(size_t)row*4 + 2*wc    ] = vd0;
      asrc[(size_t)row*4 + 2*wc + 1] = vs1;
      adst[(size_t)row*4 + 2*wc + 1] = vd1;
    }
  }
}

// ---------------- layer-2 aggregation: inline weights + 4x unrolled ---------
__global__ __launch_bounds__(256) void k_node_agg2(
    const int* __restrict__ rowptr, const int* __restrict__ csr,
    const float* __restrict__ asrc, const float* __restrict__ adst,
    const __half* __restrict__ h2t, const float* __restrict__ bias,
    float* __restrict__ outp, int N)
{
  const int n = blockIdx.x*4 + (threadIdx.x >> 6);
  const int l = threadIdx.x & 63;              // output channel
  if (n >= N) return;
  const int start = rowptr[n];
  const int deg = rowptr[n+1] - start;
  const float4 ad = *(const float4*)(adst + (size_t)n*4);

  float a0=0.f, a1=0.f, a2=0.f, a3=0.f;
  float4 ds = make_float4(0.f,0.f,0.f,0.f);
  int j = 0;
  for (; j + 4 <= deg; j += 4){
    const int p0 = start + j;
    const int s0 = csr[p0+0], s1 = csr[p0+1], s2 = csr[p0+2], s3 = csr[p0+3];
    const float4 q0 = *(const float4*)(asrc + (size_t)s0*4);   // L2 hit
    const float4 q1 = *(const float4*)(asrc + (size_t)s1*4);
    const float4 q2 = *(const float4*)(asrc + (size_t)s2*4);
    const float4 q3 = *(const float4*)(asrc + (size_t)s3*4);
    const uint2 u0 = *(const uint2*)(h2t + (size_t)s0*256 + l*4);
    const uint2 u1 = *(const uint2*)(h2t + (size_t)s1*256 + l*4);
    const uint2 u2 = *(const uint2*)(h2t + (size_t)s2*256 + l*4);
    const uint2 u3 = *(const uint2*)(h2t + (size_t)s3*256 + l*4);
    float4 w0, w1, w2, w3;
    w0.x = __expf(lrelu(q0.x+ad.x)); w0.y = __expf(lrelu(q0.y+ad.y));
    w0.z = __expf(lrelu(q0.z+ad.z)); w0.w = __expf(lrelu(q0.w+ad.w));
    w1.x = __expf(lrelu(q1.x+ad.x)); w1.y = __expf(lrelu(q1.y+ad.y));
    w1.z = __expf(lrelu(q1.z+ad.z)); w1.w = __expf(lrelu(q1.w+ad.w));
    w2.x = __expf(lrelu(q2.x+ad.x)); w2.y = __expf(lrelu(q2.y+ad.y));
    w2.z = __expf(lrelu(q2.z+ad.z)); w2.w = __expf(lrelu(q2.w+ad.w));
    w3.x = __expf(lrelu(q3.x+ad.x)); w3.y = __expf(lrelu(q3.y+ad.y));
    w3.z = __expf(lrelu(q3.z+ad.z)); w3.w = __expf(lrelu(q3.w+ad.w));
    const float2 g0 = __half22float2(*reinterpret_cast<const __half2*>(&u0.x));
    const float2 g1 = __half22float2(*reinterpret_cast<const __half2*>(&u0.y));
    const float2 h0 = __half22float2(*reinterpret_cast<const __half2*>(&u1.x));
    const float2 h1 = __half22float2(*reinterpret_cast<const __half2*>(&u1.y));
    const float2 i0 = __half22float2(*reinterpret_cast<const __half2*>(&u2.x));
    const float2 i1 = __half22float2(*reinterpret_cast<const __half2*>(&u2.y));
    const float2 k0 = __half22float2(*reinterpret_cast<const __half2*>(&u3.x));
    const float2 k1 = __half22float2(*reinterpret_cast<const __half2*>(&u3.y));
    a0 += w0.x*g0.x + w1.x*h0.x + w2.x*i0.x + w3.x*k0.x;
    a1 += w0.y*g0.y + w1.y*h0.y + w2.y*i0.y + w3.y*k0.y;
    a2 += w0.z*g1.x + w1.z*h1.x + w2.z*i1.x + w3.z*k1.x;
    a3 += w0.w*g1.y + w1.w*h1.y + w2.w*i1.y + w3.w*k1.y;
    ds.x += w0.x+w1.x+w2.x+w3.x;
    ds.y += w0.y+w1.y+w2.y+w3.y;
    ds.z += w0.z+w1.z+w2.z+w3.z;
    ds.w += w0.w+w1.w+w2.w+w3.w;
  }
  for (; j < deg; j++){
    const int s = csr[start + j];
    const float4 q = *(const float4*)(asrc + (size_t)s*4);
    const uint2 u = *(const uint2*)(h2t + (size_t)s*256 + l*4);
    float4 w4;
    w4.x = __expf(lrelu(q.x+ad.x)); w4.y = __expf(lrelu(q.y+ad.y));
    w4.z = __expf(lrelu(q.z+ad.z)); w4.w = __expf(lrelu(q.w+ad.w));
    const float2 f01 = __half22float2(*reinterpret_cast<const __half2*>(&u.x));
    const float2 f23 = __half22float2(*reinterpret_cast<const __half2*>(&u.y));
    a0 += w4.x*f01.x; a1 += w4.y*f01.y; a2 += w4.z*f23.x; a3 += w4.w*f23.y;
    ds.x += w4.x; ds.y += w4.y; ds.z += w4.z; ds.w += w4.w;
  }
  const float val = 0.25f*(a0/ds.x + a1/ds.y + a2/ds.z + a3/ds.w) + bias[l];
  outp[(size_t)n*64 + l] = fmaxf(val, 0.f);
}

// ---------------- FF head: agg2 -> relu(@ff1) -> @ff2 -------
__global__ __launch_bounds__(256) void k_ff(
    const float* __restrict__ agg2,
    const float* __restrict__ w1, const float* __restrict__ b1,
    const float* __restrict__ w2, const float* __restrict__ b2f,
    float* __restrict__ out, int N)
{
  __shared__ float W1s[64*32];
  __shared__ float B1s[32];
  __shared__ float W2s[64];
  __shared__ float B2s[2];
  const int t = threadIdx.x;
  for (int i=t; i<64*32; i+=256) W1s[i] = w1[i];
  if (t < 32) B1s[t] = b1[t];
  if (t < 64) W2s[t] = w2[t];
  if (t < 2)  B2s[t] = b2f[t];
  __syncthreads();

  const int n = blockIdx.x*256 + t;
  if (n >= N) return;

  float t1[32];
  #pragma unroll
  for (int j=0;j<32;j++) t1[j] = B1s[j];
  #pragma unroll
  for (int c=0;c<64;c++){
    const float fc = agg2[(long)n*64 + c];
    #pragma unroll
    for (int j=0;j<32;j++) t1[j] += fc * W1s[c*32 + j];
  }
  float o0 = B2s[0], o1 = B2s[1];
  #pragma unroll
  for (int j=0;j<32;j++){
    const float v = t1[j] > 0.f ? t1[j] : 0.f;
    o0 += v * W2s[j*2 + 0];
    o1 += v * W2s[j*2 + 1];
  }
  out[(long)n*2 + 0] = o0;
  out[(long)n*2 + 1] = o1;
}

extern "C" void kernel_launch(void* const* d_in, const int* in_sizes, int n_in,
                              void* d_out, int out_size, void* d_ws, size_t ws_size,
                              hipStream_t stream)
{
  const float* x      = (const float*)d_in[0];
  const int*   ei     = (const int*)  d_in[1];
  const float* W1     = (const float*)d_in[3];
  const float* att_s1 = (const float*)d_in[4];
  const float* att_d1 = (const float*)d_in[5];
  const float* b1     = (const float*)d_in[6];
  const float* W2     = (const float*)d_in[7];
  const float* att_s2 = (const float*)d_in[8];
  const float* att_d2 = (const float*)d_in[9];
  const float* b2     = (const float*)d_in[10];
  const float* ff1w   = (const float*)d_in[11];
  const float* ff1b   = (const float*)d_in[12];
  const float* ff2w   = (const float*)d_in[13];
  const float* ff2b   = (const float*)d_in[14];
  float* out = (float*)d_out;

  const int N = in_sizes[0] / 128;
  const int E = in_sizes[1] / 2;
  const int tot = E + N;

  // ---- workspace ----
  char* p = (char*)d_ws;
  __half* aggX = (__half*)p;
  float*  agg2 = (float*)(p + (size_t)N*512);
  p += (size_t)N*1024;
  __half* xh  = (__half*)p;
  __half* h2t = (__half*)(p + (size_t)N*256);
  p += (size_t)N*1024;
  float* asrc = (float*)p;  p += (size_t)N*4*4;
  float* adst = (float*)p;  p += (size_t)N*4*4;
  float* Ps   = (float*)p;  p += 512*4;
  float* Pd   = (float*)p;  p += 512*4;
  _Float16* W1t = (_Float16*)p; p += 256*128*2;
  _Float16* W2t = (_Float16*)p; p += 256*256*2;
  int* deg    = (int*)p;    p += (size_t)N*4;
  int* rowptr = (int*)p;    p += (size_t)(N+1)*4;
  int* cursor = (int*)p;    p += (size_t)N*4;
  int* bsum   = (int*)p;    p += SB*4;
  int* csr    = (int*)p;    p += (size_t)tot*4;

  const int gE  = (tot + 255) / 256;
  const int gN4 = (N + 3) / 4;
  const int g64 = (N + 63) / 64;

  // ---- CSR build (shared by both layers) ----
  k_zero <<<(N+255)/256,256,0,stream>>>(deg, N);
  k_count<<<gE,256,0,stream>>>(ei, E, N, deg);
  k_scan1<<<SB,256,0,stream>>>(deg, bsum, N);
  k_scan2<<<1,256,0,stream>>>(bsum);
  k_scan3<<<SB,256,0,stream>>>(deg, bsum, rowptr, cursor, N);
  k_fill <<<gE,256,0,stream>>>(ei, E, N, cursor, csr);

  // ---- weight prep (fp16 transposed copies) ----
  k_cvt_wt<<<128,256,0,stream>>>(W1, W1t, 128, 256);
  k_cvt_wt<<<256,256,0,stream>>>(W2, W2t, 256, 256);

  // ---- layer 1: aggregate-then-transform ----
  k_cvt_x<<<1024,256,0,stream>>>(x, xh, (long)N*64);
  k_prep<<<1,256,0,stream>>>(W1, att_s1, att_d1, Ps, Pd);
  k_att1<<<g64,256,0,stream>>>(x, Ps, Pd, asrc, adst, N);
  k_agg_x<<<gN4,256,0,stream>>>(rowptr, csr, asrc, adst, xh, aggX, N);

  // ---- fused gemm1+gemm2 (8-wave, per-wave col split) ----
  k_gemm_fused<<<g64,512,0,stream>>>((const _Float16*)aggX, W1t, b1, W2t,
                                     att_s2, att_d2, h2t, asrc, adst, N);

  // ---- layer-2 aggregation + FF head ----
  k_node_agg2<<<gN4,256,0,stream>>>(rowptr, csr, asrc, adst, h2t, b2, agg2, N);
  k_ff<<<(N+255)/256,256,0,stream>>>(agg2, ff1w, ff1b, ff2w, ff2b, out, N);
}

// Round 15
// 307.233 us; speedup vs baseline: 2.0645x; 1.2668x over previous
//
#include <hip/hip_runtime.h>
#include <hip/hip_fp16.h>

typedef _Float16 v8h __attribute__((ext_vector_type(8)));
typedef float    v4f __attribute__((ext_vector_type(4)));

__device__ __forceinline__ float lrelu(float x){ return x >= 0.f ? x : 0.2f*x; }

#define SB 256  // scan blocks

// ---------------- zero degree counters ----------------
__global__ __launch_bounds__(256) void k_zero(int* __restrict__ p, int n)
{
  int i = blockIdx.x*256 + threadIdx.x;
  if (i < n) p[i] = 0;
}

// ---------------- count in-degree per destination ----------------
__global__ __launch_bounds__(256) void k_count(const int* __restrict__ ei,
                                               int E, int N, int* __restrict__ deg)
{
  const int e = blockIdx.x*256 + threadIdx.x;
  if (e >= E + N) return;
  const int d = (e < E) ? ei[E + e] : (e - E);
  atomicAdd(&deg[d], 1);
}

// ---------------- parallel scan phase 1 ----------------
__global__ __launch_bounds__(256) void k_scan1(const int* __restrict__ deg,
                                               int* __restrict__ bsum, int N)
{
  __shared__ int sh[256];
  const int chunk = (N + SB - 1) / SB;
  const int lo = blockIdx.x * chunk;
  const int hi = min(lo + chunk, N);
  int s = 0;
  for (int i = lo + threadIdx.x; i < hi; i += 256) s += deg[i];
  sh[threadIdx.x] = s;
  __syncthreads();
  #pragma unroll
  for (int off = 128; off; off >>= 1){
    if (threadIdx.x < off) sh[threadIdx.x] += sh[threadIdx.x + off];
    __syncthreads();
  }
  if (threadIdx.x == 0) bsum[blockIdx.x] = sh[0];
}

// ---------------- parallel scan phase 2 ----------------
__global__ __launch_bounds__(256) void k_scan2(int* __restrict__ bsum)
{
  __shared__ int sh[256];
  const int v = bsum[threadIdx.x];
  sh[threadIdx.x] = v;
  __syncthreads();
  for (int off = 1; off < 256; off <<= 1){
    int t = 0;
    if (threadIdx.x >= off) t = sh[threadIdx.x - off];
    __syncthreads();
    sh[threadIdx.x] += t;
    __syncthreads();
  }
  bsum[threadIdx.x] = sh[threadIdx.x] - v;  // exclusive
}

// ---------------- parallel scan phase 3 ----------------
__global__ __launch_bounds__(256) void k_scan3(const int* __restrict__ deg,
                                               const int* __restrict__ bsum,
                                               int* __restrict__ rowptr,
                                               int* __restrict__ cursor, int N)
{
  __shared__ int sh[256];
  const int chunk = (N + SB - 1) / SB;
  const int lo = blockIdx.x * chunk;
  const int hi = min(lo + chunk, N);
  int base = bsum[blockIdx.x];
  for (int start = lo; start < hi; start += 256){
    const int i = start + threadIdx.x;
    const int v = (i < hi) ? deg[i] : 0;
    sh[threadIdx.x] = v;
    __syncthreads();
    for (int off = 1; off < 256; off <<= 1){
      int t = 0;
      if (threadIdx.x >= off) t = sh[threadIdx.x - off];
      __syncthreads();
      sh[threadIdx.x] += t;
      __syncthreads();
    }
    if (i < hi){
      const int excl = base + sh[threadIdx.x] - v;
      rowptr[i] = excl;
      cursor[i] = excl;
    }
    base += sh[255];
    __syncthreads();
  }
  if (blockIdx.x == SB-1 && threadIdx.x == 0) rowptr[N] = base;
}

// ---------------- fill CSR src lists ----------------
__global__ __launch_bounds__(256) void k_fill(const int* __restrict__ ei,
                                              int E, int N, int* __restrict__ cursor,
                                              int* __restrict__ csr)
{
  const int e = blockIdx.x*256 + threadIdx.x;
  if (e >= E + N) return;
  int s, d;
  if (e < E){ s = ei[e]; d = ei[E + e]; } else { s = d = e - E; }
  const int pos = atomicAdd(&cursor[d], 1);
  csr[pos] = s;
}

// ---------------- x -> fp16 copy ----------------
__global__ __launch_bounds__(256) void k_cvt_x(const float* __restrict__ x,
                                               __half* __restrict__ xh, long n2)
{
  long i  = (long)blockIdx.x*256 + threadIdx.x;
  long st = (long)gridDim.x*256;
  for (; i < n2; i += st){
    const float2 v = *(const float2*)(x + 2*i);
    *(__half2*)(xh + 2*i) = __floats2half2_rn(v.x, v.y);
  }
}

// ---------------- W1 [128,256] -> fragment-packed fp16 [16][4][64][8] -------
// Wp1[tct][ks][lane][e] = W1[ks*32+(lane>>4)*8+e][tct*16+(lane&15)]
__global__ __launch_bounds__(256) void k_pack_w1(const float* __restrict__ W,
                                                 _Float16* __restrict__ Wp)
{
  const int idx = blockIdx.x*256 + threadIdx.x;   // 32768 total
  const int e = idx & 7, lane = (idx >> 3) & 63;
  const int ks = (idx >> 9) & 3, tct = idx >> 11;
  Wp[idx] = (_Float16)W[(size_t)(ks*32 + (lane>>4)*8 + e)*256 + tct*16 + (lane&15)];
}

// ---------------- W2 [256,256] -> fragment-packed fp16 [16][8][64][8] -------
__global__ __launch_bounds__(256) void k_pack_w2(const float* __restrict__ W,
                                                 _Float16* __restrict__ Wp)
{
  const int idx = blockIdx.x*256 + threadIdx.x;   // 65536 total
  const int e = idx & 7, lane = (idx >> 3) & 63;
  const int ks = (idx >> 9) & 7, tct = idx >> 12;
  Wp[idx] = (_Float16)W[(size_t)(ks*32 + (lane>>4)*8 + e)*256 + tct*16 + (lane&15)];
}

// ---------------- Ps/Pd = per-head W1 @ att vectors: [128,4] ----------------
__global__ __launch_bounds__(256) void k_prep(
    const float* __restrict__ W1, const float* __restrict__ as1,
    const float* __restrict__ ad1, float* __restrict__ Ps, float* __restrict__ Pd)
{
  const int t = threadIdx.x;
  for (int idx = t; idx < 512; idx += 256){
    const int k = idx >> 2, h = idx & 3;
    float ss = 0.f, dd = 0.f;
    for (int c = 0; c < 64; c++){
      const float wv = W1[k*256 + h*64 + c];
      ss += wv * as1[h*64 + c];
      dd += wv * ad1[h*64 + c];
    }
    Ps[k*4 + h] = ss;
    Pd[k*4 + h] = dd;
  }
}

// ---------------- layer-1 logits: asrc/adst = x @ Ps/Pd  [N,4] --------------
__global__ __launch_bounds__(256) void k_att1(
    const float* __restrict__ x, const float* __restrict__ Ps,
    const float* __restrict__ Pd, float* __restrict__ asrc,
    float* __restrict__ adst, int N)
{
  __shared__ float PsL[512], PdL[512];
  __shared__ float red[4][64][8];
  const int t = threadIdx.x;
  PsL[t] = Ps[t]; PsL[t+256] = Ps[t+256];
  PdL[t] = Pd[t]; PdL[t+256] = Pd[t+256];
  __syncthreads();
  const int r = t & 63, g = t >> 6;
  const int row = blockIdx.x*64 + r;
  const int rg = min(row, N-1);
  const float* xr = x + (size_t)rg*128;
  float4 pa = make_float4(0.f,0.f,0.f,0.f);
  float4 pb = make_float4(0.f,0.f,0.f,0.f);
  for (int kk = g*32; kk < g*32 + 32; kk++){
    const float xv = xr[kk];
    const float4 s4 = *(const float4*)(PsL + kk*4);
    const float4 d4 = *(const float4*)(PdL + kk*4);
    pa.x += xv*s4.x; pa.y += xv*s4.y; pa.z += xv*s4.z; pa.w += xv*s4.w;
    pb.x += xv*d4.x; pb.y += xv*d4.y; pb.z += xv*d4.z; pb.w += xv*d4.w;
  }
  *(float4*)(&red[g][r][0]) = pa;
  *(float4*)(&red[g][r][4]) = pb;
  __syncthreads();
  if (t < 64 && blockIdx.x*64 + t < N){
    float4 sa = make_float4(0.f,0.f,0.f,0.f);
    float4 sb = make_float4(0.f,0.f,0.f,0.f);
    #pragma unroll
    for (int gg = 0; gg < 4; gg++){
      const float4 qa = *(const float4*)(&red[gg][t][0]);
      const float4 qb = *(const float4*)(&red[gg][t][4]);
      sa.x += qa.x; sa.y += qa.y; sa.z += qa.z; sa.w += qa.w;
      sb.x += qb.x; sb.y += qb.y; sb.z += qb.z; sb.w += qb.w;
    }
    *(float4*)(asrc + (size_t)(blockIdx.x*64 + t)*4) = sa;
    *(float4*)(adst + (size_t)(blockIdx.x*64 + t)*4) = sb;
  }
}

// ---------------- layer-1 aggregate: dedup'd weights + packed aggX store ----
// lane (jj=l&15, hh=l>>4) computes ONE exp per 16-edge chunk -> LDS; payload
// loop reads broadcast (s,w) and gathers xh. Output written MFMA-fragment-
// packed: aggXp[nb][h][ks][lane][e] = aggX[nb*16+(lane&15)][h][ks*32+(lane>>4)*8+e]
__global__ __launch_bounds__(256) void k_agg_x(
    const int* __restrict__ rowptr, const int* __restrict__ csr,
    const float* __restrict__ asrc, const float* __restrict__ adst,
    const __half* __restrict__ xh,
    __half* __restrict__ aggXp, int N)
{
  __shared__ float wbuf[4][16][4];
  __shared__ int   sbuf[4][16];
  const int wid = threadIdx.x >> 6;
  const int n = blockIdx.x*4 + wid;
  const int l = threadIdx.x & 63;
  if (n >= N) return;
  const int start = rowptr[n];
  const int deg = rowptr[n+1] - start;
  const float4 ad = *(const float4*)(adst + (size_t)n*4);
  const int jj = l & 15, hh = l >> 4;
  const float adh = hh==0?ad.x : hh==1?ad.y : hh==2?ad.z : ad.w;

  float a0x=0.f,a0y=0.f, a1x=0.f,a1y=0.f, a2x=0.f,a2y=0.f, a3x=0.f,a3y=0.f;
  float4 ds = make_float4(0.f,0.f,0.f,0.f);
  for (int c = 0; c < deg; c += 16){
    const int cnt = min(16, deg - c);
    const int sE = csr[start + c + min(jj, cnt-1)];
    const float q = asrc[(size_t)sE*4 + hh];
    const float wE = (jj < cnt) ? __expf(lrelu(q + adh)) : 0.f;
    wbuf[wid][jj][hh] = wE;
    if (hh == 0) sbuf[wid][jj] = sE;
    __builtin_amdgcn_wave_barrier();
    int j = 0;
    for (; j + 4 <= cnt; j += 4){
      const int t0 = sbuf[wid][j+0], t1 = sbuf[wid][j+1];
      const int t2 = sbuf[wid][j+2], t3 = sbuf[wid][j+3];
      const float4 wA = *(const float4*)(&wbuf[wid][j+0][0]);
      const float4 wB = *(const float4*)(&wbuf[wid][j+1][0]);
      const float4 wC = *(const float4*)(&wbuf[wid][j+2][0]);
      const float4 wD = *(const float4*)(&wbuf[wid][j+3][0]);
      const float2 f0 = __half22float2(*(const __half2*)(xh + (size_t)t0*128 + 2*l));
      const float2 f1 = __half22float2(*(const __half2*)(xh + (size_t)t1*128 + 2*l));
      const float2 f2 = __half22float2(*(const __half2*)(xh + (size_t)t2*128 + 2*l));
      const float2 f3 = __half22float2(*(const __half2*)(xh + (size_t)t3*128 + 2*l));
      a0x += wA.x*f0.x + wB.x*f1.x + wC.x*f2.x + wD.x*f3.x;
      a0y += wA.x*f0.y + wB.x*f1.y + wC.x*f2.y + wD.x*f3.y;
      a1x += wA.y*f0.x + wB.y*f1.x + wC.y*f2.x + wD.y*f3.x;
      a1y += wA.y*f0.y + wB.y*f1.y + wC.y*f2.y + wD.y*f3.y;
      a2x += wA.z*f0.x + wB.z*f1.x + wC.z*f2.x + wD.z*f3.x;
      a2y += wA.z*f0.y + wB.z*f1.y + wC.z*f2.y + wD.z*f3.y;
      a3x += wA.w*f0.x + wB.w*f1.x + wC.w*f2.x + wD.w*f3.x;
      a3y += wA.w*f0.y + wB.w*f1.y + wC.w*f2.y + wD.w*f3.y;
      ds.x += wA.x+wB.x+wC.x+wD.x;
      ds.y += wA.y+wB.y+wC.y+wD.y;
      ds.z += wA.z+wB.z+wC.z+wD.z;
      ds.w += wA.w+wB.w+wC.w+wD.w;
    }
    for (; j < cnt; j++){
      const int t0 = sbuf[wid][j];
      const float4 wA = *(const float4*)(&wbuf[wid][j][0]);
      const float2 f0 = __half22float2(*(const __half2*)(xh + (size_t)t0*128 + 2*l));
      a0x += wA.x*f0.x; a0y += wA.x*f0.y;
      a1x += wA.y*f0.x; a1y += wA.y*f0.y;
      a2x += wA.z*f0.x; a2y += wA.z*f0.y;
      a3x += wA.w*f0.x; a3y += wA.w*f0.y;
      ds.x += wA.x; ds.y += wA.y; ds.z += wA.z; ds.w += wA.w;
    }
    __builtin_amdgcn_wave_barrier();
  }
  const float i0 = 1.f/ds.x, i1 = 1.f/ds.y, i2 = 1.f/ds.z, i3 = 1.f/ds.w;
  // packed store: node n holds k = 2l, 2l+1 for each head
  const int nb = n >> 4, r = n & 15;
  const int ksA = l >> 4;
  const int laneA = r + (((2*l) >> 3) & 3) * 16;
  const int e0 = (2*l) & 7;
  const size_t base = (((size_t)nb*4)*4 + ksA)*64*8 + (size_t)laneA*8 + e0;
  // head h adds h*4*64*8 = h*2048
  *(__half2*)(aggXp + base +    0) = __floats2half2_rn(a0x*i0, a0y*i0);
  *(__half2*)(aggXp + base + 2048) = __floats2half2_rn(a1x*i1, a1y*i1);
  *(__half2*)(aggXp + base + 4096) = __floats2half2_rn(a2x*i2, a2y*i2);
  *(__half2*)(aggXp + base + 6144) = __floats2half2_rn(a3x*i3, a3y*i3);
}

// ---------------- FUSED MFMA, 8 waves, all operand loads coalesced ----------
__global__ __launch_bounds__(512) void k_gemm_fused(
    const _Float16* __restrict__ aggXp, // [nb][4][4][64][8]
    const _Float16* __restrict__ Wp1,   // [16][4][64][8]
    const float* __restrict__ b1,
    const _Float16* __restrict__ Wp2,   // [16][8][64][8]
    const float* __restrict__ att_s, const float* __restrict__ att_d,
    __half* __restrict__ h2t,           // [N,64,4] halves
    float* __restrict__ asrc, float* __restrict__ adst, int N)
{
  __shared__ _Float16 h1[64][264];
  const int wv = threadIdx.x >> 6, l = threadIdx.x & 63;
  const int wr = wv & 3, wc = wv >> 2;
  const int lr = l & 15, lk = l >> 4;
  const int row0 = blockIdx.x*64 + wr*16;
  const int nb = blockIdx.x*4 + wr;

  // ---- phase 1: cols wc*128..+128 (heads 2wc, 2wc+1), coalesced A and B ----
  {
    v4f acc[8] = {};
    for (int ks = 0; ks < 4; ks++){
      const v8h a0 = *(const v8h*)(aggXp + ((((size_t)nb*4 + 2*wc  )*4 + ks)*64 + l)*8);
      const v8h a1 = *(const v8h*)(aggXp + ((((size_t)nb*4 + 2*wc+1)*4 + ks)*64 + l)*8);
      #pragma unroll
      for (int ct = 0; ct < 8; ct++){
        const int tct = wc*8 + ct;
        const v8h b = *(const v8h*)(Wp1 + (((size_t)tct*4 + ks)*64 + l)*8);
        acc[ct] = __builtin_amdgcn_mfma_f32_16x16x32_f16(ct < 4 ? a0 : a1, b, acc[ct], 0,0,0);
      }
    }
    #pragma unroll
    for (int ct = 0; ct < 8; ct++){
      const int col = wc*128 + ct*16 + lr;
      const float bv = b1[col];
      #pragma unroll
      for (int j = 0; j < 4; j++)
        h1[wr*16 + lk*4 + j][col] = (_Float16)fmaxf(acc[ct][j] + bv, 0.f);
    }
  }
  __syncthreads();

  // ---- phase 2: cols wc*128..+128, full k=256 from LDS; coalesced B ----
  v4f acc[8] = {};
  for (int ks = 0; ks < 8; ks++){
    const v8h a = *(const v8h*)(&h1[wr*16 + lr][ks*32 + lk*8]);
    #pragma unroll
    for (int ct = 0; ct < 8; ct++){
      const int tct = wc*8 + ct;
      const v8h b = *(const v8h*)(Wp2 + (((size_t)tct*8 + ks)*64 + l)*8);
      acc[ct] = __builtin_amdgcn_mfma_f32_16x16x32_f16(a, b, acc[ct], 0,0,0);
    }
  }
  float AS[8], AD[8];
  #pragma unroll
  for (int ct = 0; ct < 8; ct++){
    const int h = 2*wc + (ct >> 2), idx = (ct & 3)*16 + lr;
    AS[ct] = att_s[h*64 + idx];
    AD[ct] = att_d[h*64 + idx];
  }
  #pragma unroll
  for (int j = 0; j < 4; j++){
    const int row = row0 + lk*4 + j;
    const bool ok = row < N;
    float vs0=0.f, vd0=0.f, vs1=0.f, vd1=0.f;
    #pragma unroll
    for (int ct = 0; ct < 8; ct++){
      const float v = acc[ct][j];
      if (ct < 4){ vs0 += v*AS[ct]; vd0 += v*AD[ct]; }
      else       { vs1 += v*AS[ct]; vd1 += v*AD[ct]; }
    }
    if (ok){
      #pragma unroll
      for (int ctm = 0; ctm < 4; ctm++){
        const int ch = ctm*16 + lr;
        *(__half2*)(h2t + (size_t)row*256 + ch*4 + 2*wc) =
            __floats2half2_rn(acc[ctm][j], acc[ctm+4][j]);
      }
    }
    #pragma unroll
    for (int off = 1; off < 16; off <<= 1){
      vs0 += __shfl_xor(vs0, off, 16);
      vd0 += __shfl_xor(vd0, off, 16);
      vs1 += __shfl_xor(vs1, off, 16);
      vd1 += __shfl_xor(vd1, off, 16);
    }
    if (lr == 0 && ok){
      asrc[(size_t)row*4 + 2*wc    ] = vs0;
      adst[(size_t)row*4 + 2*wc    ] = vd0;
      asrc[(size_t)row*4 + 2*wc + 1] = vs1;
      adst[(size_t)row*4 + 2*wc + 1] = vd1;
    }
  }
}

// ---------------- layer-2 aggregation: dedup'd weights + 4x unrolled --------
__global__ __launch_bounds__(256) void k_node_agg2(
    const int* __restrict__ rowptr, const int* __restrict__ csr,
    const float* __restrict__ asrc, const float* __restrict__ adst,
    const __half* __restrict__ h2t, const float* __restrict__ bias,
    float* __restrict__ outp, int N)
{
  __shared__ float wbuf[4][16][4];
  __shared__ int   sbuf[4][16];
  const int wid = threadIdx.x >> 6;
  const int n = blockIdx.x*4 + wid;
  const int l = threadIdx.x & 63;              // output channel
  if (n >= N) return;
  const int start = rowptr[n];
  const int deg = rowptr[n+1] - start;
  const float4 ad = *(const float4*)(adst + (size_t)n*4);
  const int jj = l & 15, hh = l >> 4;
  const float adh = hh==0?ad.x : hh==1?ad.y : hh==2?ad.z : ad.w;

  float a0=0.f, a1=0.f, a2=0.f, a3=0.f;
  float4 ds = make_float4(0.f,0.f,0.f,0.f);
  for (int c = 0; c < deg; c += 16){
    const int cnt = min(16, deg - c);
    const int sE = csr[start + c + min(jj, cnt-1)];
    const float q = asrc[(size_t)sE*4 + hh];
    const float wE = (jj < cnt) ? __expf(lrelu(q + adh)) : 0.f;
    wbuf[wid][jj][hh] = wE;
    if (hh == 0) sbuf[wid][jj] = sE;
    __builtin_amdgcn_wave_barrier();
    int j = 0;
    for (; j + 4 <= cnt; j += 4){
      const int t0 = sbuf[wid][j+0], t1 = sbuf[wid][j+1];
      const int t2 = sbuf[wid][j+2], t3 = sbuf[wid][j+3];
      const float4 wA = *(const float4*)(&wbuf[wid][j+0][0]);
      const float4 wB = *(const float4*)(&wbuf[wid][j+1][0]);
      const float4 wC = *(const float4*)(&wbuf[wid][j+2][0]);
      const float4 wD = *(const float4*)(&wbuf[wid][j+3][0]);
      const uint2 u0 = *(const uint2*)(h2t + (size_t)t0*256 + l*4);
      const uint2 u1 = *(const uint2*)(h2t + (size_t)t1*256 + l*4);
      const uint2 u2 = *(const uint2*)(h2t + (size_t)t2*256 + l*4);
      const uint2 u3 = *(const uint2*)(h2t + (size_t)t3*256 + l*4);
      const float2 g0 = __half22float2(*reinterpret_cast<const __half2*>(&u0.x));
      const float2 g1 = __half22float2(*reinterpret_cast<const __half2*>(&u0.y));
      const float2 h0 = __half22float2(*reinterpret_cast<const __half2*>(&u1.x));
      const float2 h1 = __half22float2(*reinterpret_cast<const __half2*>(&u1.y));
      const float2 i0 = __half22float2(*reinterpret_cast<const __half2*>(&u2.x));
      const float2 i1 = __half22float2(*reinterpret_cast<const __half2*>(&u2.y));
      const float2 k0 = __half22float2(*reinterpret_cast<const __half2*>(&u3.x));
      const float2 k1 = __half22float2(*reinterpret_cast<const __half2*>(&u3.y));
      a0 += wA.x*g0.x + wB.x*h0.x + wC.x*i0.x + wD.x*k0.x;
      a1 += wA.y*g0.y + wB.y*h0.y + wC.y*i0.y + wD.y*k0.y;
      a2 += wA.z*g1.x + wB.z*h1.x + wC.z*i1.x + wD.z*k1.x;
      a3 += wA.w*g1.y + wB.w*h1.y + wC.w*i1.y + wD.w*k1.y;
      ds.x += wA.x+wB.x+wC.x+wD.x;
      ds.y += wA.y+wB.y+wC.y+wD.y;
      ds.z += wA.z+wB.z+wC.z+wD.z;
      ds.w += wA.w+wB.w+wC.w+wD.w;
    }
    for (; j < cnt; j++){
      const int t0 = sbuf[wid][j];
      const float4 wA = *(const float4*)(&wbuf[wid][j][0]);
      const uint2 u = *(const uint2*)(h2t + (size_t)t0*256 + l*4);
      const float2 f01 = __half22float2(*reinterpret_cast<const __half2*>(&u.x));
      const float2 f23 = __half22float2(*reinterpret_cast<const __half2*>(&u.y));
      a0 += wA.x*f01.x; a1 += wA.y*f01.y; a2 += wA.z*f23.x; a3 += wA.w*f23.y;
      ds.x += wA.x; ds.y += wA.y; ds.z += wA.z; ds.w += wA.w;
    }
    __builtin_amdgcn_wave_barrier();
  }
  const float val = 0.25f*(a0/ds.x + a1/ds.y + a2/ds.z + a3/ds.w) + bias[l];
  outp[(size_t)n*64 + l] = fmaxf(val, 0.f);
}

// ---------------- FF head: agg2 -> relu(@ff1) -> @ff2 -------
__global__ __launch_bounds__(256) void k_ff(
    const float* __restrict__ agg2,
    const float* __restrict__ w1, const float* __restrict__ b1,
    const float* __restrict__ w2, const float* __restrict__ b2f,
    float* __restrict__ out, int N)
{
  __shared__ float W1s[64*32];
  __shared__ float B1s[32];
  __shared__ float W2s[64];
  __shared__ float B2s[2];
  const int t = threadIdx.x;
  for (int i=t; i<64*32; i+=256) W1s[i] = w1[i];
  if (t < 32) B1s[t] = b1[t];
  if (t < 64) W2s[t] = w2[t];
  if (t < 2)  B2s[t] = b2f[t];
  __syncthreads();

  const int n = blockIdx.x*256 + t;
  if (n >= N) return;

  float t1[32];
  #pragma unroll
  for (int j=0;j<32;j++) t1[j] = B1s[j];
  #pragma unroll
  for (int c=0;c<64;c++){
    const float fc = agg2[(long)n*64 + c];
    #pragma unroll
    for (int j=0;j<32;j++) t1[j] += fc * W1s[c*32 + j];
  }
  float o0 = B2s[0], o1 = B2s[1];
  #pragma unroll
  for (int j=0;j<32;j++){
    const float v = t1[j] > 0.f ? t1[j] : 0.f;
    o0 += v * W2s[j*2 + 0];
    o1 += v * W2s[j*2 + 1];
  }
  out[(long)n*2 + 0] = o0;
  out[(long)n*2 + 1] = o1;
}

extern "C" void kernel_launch(void* const* d_in, const int* in_sizes, int n_in,
                              void* d_out, int out_size, void* d_ws, size_t ws_size,
                              hipStream_t stream)
{
  const float* x      = (const float*)d_in[0];
  const int*   ei     = (const int*)  d_in[1];
  const float* W1     = (const float*)d_in[3];
  const float* att_s1 = (const float*)d_in[4];
  const float* att_d1 = (const float*)d_in[5];
  const float* b1     = (const float*)d_in[6];
  const float* W2     = (const float*)d_in[7];
  const float* att_s2 = (const float*)d_in[8];
  const float* att_d2 = (const float*)d_in[9];
  const float* b2     = (const float*)d_in[10];
  const float* ff1w   = (const float*)d_in[11];
  const float* ff1b   = (const float*)d_in[12];
  const float* ff2w   = (const float*)d_in[13];
  const float* ff2b   = (const float*)d_in[14];
  float* out = (float*)d_out;

  const int N = in_sizes[0] / 128;
  const int E = in_sizes[1] / 2;
  const int tot = E + N;
  const int g64 = (N + 63) / 64;
  const size_t NP = (size_t)g64 * 64;   // padded rows for packed aggX

  // ---- workspace ----
  char* p = (char*)d_ws;
  __half* aggXp = (__half*)p;                        // [NP,512] halves packed
  p += NP*1024;
  float* agg2 = (float*)p;  p += (size_t)N*64*4;     // [N,64]
  __half* xh  = (__half*)p; p += (size_t)N*128*2;    // [N,128]
  __half* h2t = (__half*)p; p += (size_t)N*256*2;    // [N,256]
  float* asrc = (float*)p;  p += (size_t)N*4*4;
  float* adst = (float*)p;  p += (size_t)N*4*4;
  float* Ps   = (float*)p;  p += 512*4;
  float* Pd   = (float*)p;  p += 512*4;
  _Float16* Wp1 = (_Float16*)p; p += 32768*2;        // [16][4][64][8]
  _Float16* Wp2 = (_Float16*)p; p += 65536*2;        // [16][8][64][8]
  int* deg    = (int*)p;    p += (size_t)N*4;
  int* rowptr = (int*)p;    p += (size_t)(N+1)*4;
  int* cursor = (int*)p;    p += (size_t)N*4;
  int* bsum   = (int*)p;    p += SB*4;
  int* csr    = (int*)p;    p += (size_t)tot*4;

  const int gE  = (tot + 255) / 256;
  const int gN4 = (N + 3) / 4;

  // ---- CSR build ----
  k_zero <<<(N+255)/256,256,0,stream>>>(deg, N);
  k_count<<<gE,256,0,stream>>>(ei, E, N, deg);
  k_scan1<<<SB,256,0,stream>>>(deg, bsum, N);
  k_scan2<<<1,256,0,stream>>>(bsum);
  k_scan3<<<SB,256,0,stream>>>(deg, bsum, rowptr, cursor, N);
  k_fill <<<gE,256,0,stream>>>(ei, E, N, cursor, csr);

  // ---- weight prep (fragment-packed fp16) ----
  k_pack_w1<<<128,256,0,stream>>>(W1, Wp1);
  k_pack_w2<<<256,256,0,stream>>>(W2, Wp2);

  // ---- layer 1 ----
  k_cvt_x<<<1024,256,0,stream>>>(x, xh, (long)N*64);
  k_prep<<<1,256,0,stream>>>(W1, att_s1, att_d1, Ps, Pd);
  k_att1<<<g64,256,0,stream>>>(x, Ps, Pd, asrc, adst, N);
  k_agg_x<<<gN4,256,0,stream>>>(rowptr, csr, asrc, adst, xh, (__half*)aggXp, N);

  // ---- fused gemm1+gemm2 ----
  k_gemm_fused<<<g64,512,0,stream>>>((const _Float16*)aggXp, Wp1, b1, Wp2,
                                     att_s2, att_d2, h2t, asrc, adst, N);

  // ---- layer-2 aggregation + FF head ----
  k_node_agg2<<<gN4,256,0,stream>>>(rowptr, csr, asrc, adst, h2t, b2, agg2, N);
  k_ff<<<(N+255)/256,256,0,stream>>>(agg2, ff1w, ff1b, ff2w, ff2b, out, N);
}